// Round 12
// baseline (985.481 us; speedup 1.0000x reference)
//
#include <hip/hip_runtime.h>
#include <math.h>

#define NTOK 577
#define NB 8
#define NC 1024
#define NH 16
#define HD 64
#define M_ROWS (NB*NTOK)               // 4616
#define SZ ((size_t)NB*NH*NTOK*HD)     // 4726784 elements
#define WSZ ((size_t)3*NC*NC)          // 3145728
#define PSZ ((size_t)NC*NC)            // 1048576
#define VTW 608                        // padded key width for VT (19*32)
#define VTSZ ((size_t)NB*NH*HD*VTW)    // 4980736
#define HSTR ((size_t)NTOK*HD)         // 36928 head stride in A-layout
#define LP 36                          // padded LDS row (32 data + 4 pad)
#define KP 66                          // K-tile LDS row pad (64 data + 2)
#define VP 36                          // VT-tile LDS row pad (32 data + 4)

typedef __attribute__((ext_vector_type(8)))  short bf16x8_t;
typedef __attribute__((ext_vector_type(8)))  unsigned short u16x8_t;
typedef __attribute__((ext_vector_type(16))) float f32x16_t;

union U4 { unsigned short s[8]; unsigned int u[4]; bf16x8_t v; };

__device__ inline unsigned short f2bf(float x){
    unsigned int u = __float_as_uint(x);
    u = (u + 0x7FFFu + ((u>>16)&1u)) >> 16;
    return (unsigned short)u;
}
__device__ inline float bf2f(unsigned short h){
    return __uint_as_float(((unsigned int)h)<<16);
}
__device__ inline unsigned int cvt_pk(float a, float b){
    unsigned int r;
    asm volatile("v_cvt_pk_bf16_f32 %0, %1, %2" : "=v"(r) : "v"(a), "v"(b));
    return r;
}

// ---------------------------------------------------------------------------
// split fp32 rows -> bf16 hi/lo [nrows][1024]. mode 0: row-major src.
// mode 1: X [N,B,C] gather (row m=b*577+n -> src row n*8+b).
// ---------------------------------------------------------------------------
__global__ __launch_bounds__(256) void split_rows(const float* __restrict__ src,
        unsigned short* __restrict__ dh, unsigned short* __restrict__ dl, int mode)
{
    int row = blockIdx.x, t = threadIdx.x;
    const float* s;
    if (mode == 0) s = src + (size_t)row*NC + 4*t;
    else {
        int b = row / NTOK, n = row % NTOK;
        s = src + ((size_t)n*NB + b)*NC + 4*t;
    }
    float4 v = *(const float4*)s;
    ushort4 hv, lv;
    hv.x = f2bf(v.x); lv.x = f2bf(v.x - bf2f(hv.x));
    hv.y = f2bf(v.y); lv.y = f2bf(v.y - bf2f(hv.y));
    hv.z = f2bf(v.z); lv.z = f2bf(v.z - bf2f(hv.z));
    hv.w = f2bf(v.w); lv.w = f2bf(v.w - bf2f(hv.w));
    *(ushort4*)(dh + (size_t)row*NC + 4*t) = hv;
    *(ushort4*)(dl + (size_t)row*NC + 4*t) = lv;
}

// ---------------------------------------------------------------------------
// Coalesced transpose: src hi-bf16 [BH][577][64] -> dst [BH][64][608], pads=0.
// ---------------------------------------------------------------------------
__global__ __launch_bounds__(256) void transp64(const unsigned short* __restrict__ src,
                                                unsigned short* __restrict__ dst)
{
    __shared__ unsigned short t[64][72];
    int bh = blockIdx.y;
    int n0 = blockIdx.x * 64;
    int tid = threadIdx.x;
    int r  = tid >> 2;
    int c0 = (tid & 3) * 16;
    int n = n0 + r;
    if (n < NTOK){
        const unsigned short* s = src + ((size_t)bh*NTOK + n)*HD + c0;
        *(u16x8_t*)&t[r][c0]   = *(const u16x8_t*)s;
        *(u16x8_t*)&t[r][c0+8] = *(const u16x8_t*)(s + 8);
    } else {
        u16x8_t z = (u16x8_t)0;
        *(u16x8_t*)&t[r][c0]   = z;
        *(u16x8_t*)&t[r][c0+8] = z;
    }
    __syncthreads();
    if (n0 + c0 < VTW){
        int d = r;
        U4 o0, o1;
        #pragma unroll
        for (int j = 0; j < 8; j++){ o0.s[j] = t[c0+j][d]; o1.s[j] = t[c0+8+j][d]; }
        unsigned short* dp = dst + ((size_t)bh*HD + d)*VTW + n0 + c0;
        *(u16x8_t*)dp       = (u16x8_t)o0.v;
        *(u16x8_t*)(dp + 8) = (u16x8_t)o1.v;
    }
}

#define MFMA12(a0h,a1h,b0h,b1h,a0l,a1l,b0l,b1l) \
    acc[0][0] = __builtin_amdgcn_mfma_f32_32x32x16_bf16(a0h, b0h, acc[0][0], 0,0,0); \
    acc[0][1] = __builtin_amdgcn_mfma_f32_32x32x16_bf16(a0h, b1h, acc[0][1], 0,0,0); \
    acc[1][0] = __builtin_amdgcn_mfma_f32_32x32x16_bf16(a1h, b0h, acc[1][0], 0,0,0); \
    acc[1][1] = __builtin_amdgcn_mfma_f32_32x32x16_bf16(a1h, b1h, acc[1][1], 0,0,0); \
    acc[0][0] = __builtin_amdgcn_mfma_f32_32x32x16_bf16(a0h, b0l, acc[0][0], 0,0,0); \
    acc[0][1] = __builtin_amdgcn_mfma_f32_32x32x16_bf16(a0h, b1l, acc[0][1], 0,0,0); \
    acc[1][0] = __builtin_amdgcn_mfma_f32_32x32x16_bf16(a1h, b0l, acc[1][0], 0,0,0); \
    acc[1][1] = __builtin_amdgcn_mfma_f32_32x32x16_bf16(a1h, b1l, acc[1][1], 0,0,0); \
    acc[0][0] = __builtin_amdgcn_mfma_f32_32x32x16_bf16(a0l, b0h, acc[0][0], 0,0,0); \
    acc[0][1] = __builtin_amdgcn_mfma_f32_32x32x16_bf16(a0l, b1h, acc[0][1], 0,0,0); \
    acc[1][0] = __builtin_amdgcn_mfma_f32_32x32x16_bf16(a1l, b0h, acc[1][0], 0,0,0); \
    acc[1][1] = __builtin_amdgcn_mfma_f32_32x32x16_bf16(a1l, b1h, acc[1][1], 0,0,0);

// ---------------------------------------------------------------------------
// qkv GEMM, LDS-staged (128x128 tile, BK=32, padded LDS rows, 4 waves 2x2).
// ---------------------------------------------------------------------------
__global__ __launch_bounds__(256) void gemm_qkv_mfma(
    const unsigned short* __restrict__ Ah, const unsigned short* __restrict__ Al,
    const unsigned short* __restrict__ Bh, const unsigned short* __restrict__ Bl,
    const float* __restrict__ bias,
    unsigned short* __restrict__ qh, unsigned short* __restrict__ ql,
    unsigned short* __restrict__ kh, unsigned short* __restrict__ kl,
    unsigned short* __restrict__ vh, unsigned short* __restrict__ vl)
{
    __shared__ unsigned short ahs[128][LP], als[128][LP];
    __shared__ unsigned short bhs[128][LP], bls[128][LP];
    int t = threadIdx.x;
    int l = t & 63, w = t >> 6;
    int lq = l & 31, hi = l >> 5;
    int wr = w >> 1, wc = w & 1;
    int col0 = blockIdx.x*128, row0 = blockIdx.y*128;

    int srow[2], scol[2], sa[2];
    #pragma unroll
    for (int i = 0; i < 2; i++){
        int idx = i*256 + t;
        srow[i] = idx >> 2;
        scol[i] = (idx & 3) * 8;
        int ar = row0 + srow[i]; if (ar >= M_ROWS) ar = M_ROWS-1;
        sa[i] = ar;
    }

    f32x16_t acc[2][2];
    #pragma unroll
    for (int i = 0; i < 16; i++){
        acc[0][0][i]=0.f; acc[0][1][i]=0.f; acc[1][0][i]=0.f; acc[1][1][i]=0.f;
    }

    for (int k0 = 0; k0 < NC; k0 += 32){
        if (k0) __syncthreads();
        #pragma unroll
        for (int i = 0; i < 2; i++){
            size_t ao = (size_t)sa[i]*NC + k0 + scol[i];
            size_t bo = (size_t)(col0 + srow[i])*NC + k0 + scol[i];
            u16x8_t va  = *(const u16x8_t*)(Ah + ao);
            u16x8_t va2 = *(const u16x8_t*)(Al + ao);
            u16x8_t vb  = *(const u16x8_t*)(Bh + bo);
            u16x8_t vb2 = *(const u16x8_t*)(Bl + bo);
            *(u16x8_t*)&ahs[srow[i]][scol[i]] = va;
            *(u16x8_t*)&als[srow[i]][scol[i]] = va2;
            *(u16x8_t*)&bhs[srow[i]][scol[i]] = vb;
            *(u16x8_t*)&bls[srow[i]][scol[i]] = vb2;
        }
        __syncthreads();
        #pragma unroll
        for (int kk = 0; kk < 2; kk++){
            int co = kk*16 + 8*hi;
            bf16x8_t a0h = *(const bf16x8_t*)&ahs[wr*64+lq][co];
            bf16x8_t a1h = *(const bf16x8_t*)&ahs[wr*64+32+lq][co];
            bf16x8_t b0h = *(const bf16x8_t*)&bhs[wc*64+lq][co];
            bf16x8_t b1h = *(const bf16x8_t*)&bhs[wc*64+32+lq][co];
            bf16x8_t a0l = *(const bf16x8_t*)&als[wr*64+lq][co];
            bf16x8_t a1l = *(const bf16x8_t*)&als[wr*64+32+lq][co];
            bf16x8_t b0l = *(const bf16x8_t*)&bls[wc*64+lq][co];
            bf16x8_t b1l = *(const bf16x8_t*)&bls[wc*64+32+lq][co];
            MFMA12(a0h,a1h,b0h,b1h,a0l,a1l,b0l,b1l)
        }
    }

    int colW = col0 + wc*64, rowW = row0 + wr*64;
    #pragma unroll
    for (int fn = 0; fn < 2; fn++){
        int colb = colW + fn*32 + lq;
        float bb = bias[colb];
        int tt = colb >> 10, h = (colb >> 6) & 15, d = colb & 63;
        unsigned short* dsth = (tt == 0) ? qh : (tt == 1 ? kh : vh);
        unsigned short* dstl = (tt == 0) ? ql : (tt == 1 ? kl : vl);
        #pragma unroll
        for (int fm = 0; fm < 2; fm++){
            #pragma unroll
            for (int r = 0; r < 16; r++){
                int orow = rowW + fm*32 + (r&3) + 8*(r>>2) + 4*hi;
                if (orow < M_ROWS){
                    float val = acc[fm][fn][r] + bb;
                    int b = orow / NTOK, n = orow % NTOK;
                    unsigned short hv = f2bf(val);
                    unsigned short lv = f2bf(val - bf2f(hv));
                    size_t idx = ((size_t)(b*NH + h)*NTOK + n)*HD + d;
                    dsth[idx] = hv; dstl[idx] = lv;
                }
            }
        }
    }
}

// ---------------------------------------------------------------------------
// proj GEMM, LDS-staged (64x128 tile, BK=32). A split bf16 in HEAD layout.
// ---------------------------------------------------------------------------
__global__ __launch_bounds__(256) void gemm_proj_mfma(
    const unsigned short* __restrict__ Ah, const unsigned short* __restrict__ Al,
    const unsigned short* __restrict__ Bh, const unsigned short* __restrict__ Bl,
    const float* __restrict__ bias, float alpha, float* __restrict__ out)
{
    __shared__ unsigned short ahs[64][LP], als[64][LP];
    __shared__ unsigned short bhs[128][LP], bls[128][LP];
    int t = threadIdx.x;
    int l = t & 63, w = t >> 6;
    int lq = l & 31, hi = l >> 5;
    int wr = w >> 1, wc = w & 1;
    int col0 = blockIdx.x*128, row0 = blockIdx.y*64;

    int sarow = t >> 2, sacol = (t & 3) * 8;
    int ar = row0 + sarow; if (ar >= M_ROWS) ar = M_ROWS-1;
    size_t abase = (size_t)(ar / NTOK)*NH*HSTR + (size_t)(ar % NTOK)*HD;
    int sbrow[2], sbcol[2];
    #pragma unroll
    for (int i = 0; i < 2; i++){
        int idx = i*256 + t;
        sbrow[i] = idx >> 2;
        sbcol[i] = (idx & 3) * 8;
    }

    f32x16_t acc[2];
    #pragma unroll
    for (int i = 0; i < 16; i++){ acc[0][i]=0.f; acc[1][i]=0.f; }

    for (int k0 = 0; k0 < NC; k0 += 32){
        if (k0) __syncthreads();
        {
            int kk = k0 + sacol;
            size_t ao = abase + (size_t)(kk >> 6)*HSTR + (kk & 63);
            u16x8_t va  = *(const u16x8_t*)(Ah + ao);
            u16x8_t va2 = *(const u16x8_t*)(Al + ao);
            *(u16x8_t*)&ahs[sarow][sacol] = va;
            *(u16x8_t*)&als[sarow][sacol] = va2;
            #pragma unroll
            for (int i = 0; i < 2; i++){
                size_t bo = (size_t)(col0 + sbrow[i])*NC + k0 + sbcol[i];
                u16x8_t vb  = *(const u16x8_t*)(Bh + bo);
                u16x8_t vb2 = *(const u16x8_t*)(Bl + bo);
                *(u16x8_t*)&bhs[sbrow[i]][sbcol[i]] = vb;
                *(u16x8_t*)&bls[sbrow[i]][sbcol[i]] = vb2;
            }
        }
        __syncthreads();
        #pragma unroll
        for (int kk = 0; kk < 2; kk++){
            int co = kk*16 + 8*hi;
            bf16x8_t a0h = *(const bf16x8_t*)&ahs[wr*32+lq][co];
            bf16x8_t a0l = *(const bf16x8_t*)&als[wr*32+lq][co];
            bf16x8_t b0h = *(const bf16x8_t*)&bhs[wc*64+lq][co];
            bf16x8_t b1h = *(const bf16x8_t*)&bhs[wc*64+32+lq][co];
            bf16x8_t b0l = *(const bf16x8_t*)&bls[wc*64+lq][co];
            bf16x8_t b1l = *(const bf16x8_t*)&bls[wc*64+32+lq][co];
            acc[0] = __builtin_amdgcn_mfma_f32_32x32x16_bf16(a0h, b0h, acc[0], 0,0,0);
            acc[1] = __builtin_amdgcn_mfma_f32_32x32x16_bf16(a0h, b1h, acc[1], 0,0,0);
            acc[0] = __builtin_amdgcn_mfma_f32_32x32x16_bf16(a0h, b0l, acc[0], 0,0,0);
            acc[1] = __builtin_amdgcn_mfma_f32_32x32x16_bf16(a0h, b1l, acc[1], 0,0,0);
            acc[0] = __builtin_amdgcn_mfma_f32_32x32x16_bf16(a0l, b0h, acc[0], 0,0,0);
            acc[1] = __builtin_amdgcn_mfma_f32_32x32x16_bf16(a0l, b1h, acc[1], 0,0,0);
        }
    }

    #pragma unroll
    for (int fn = 0; fn < 2; fn++){
        int colb = col0 + wc*64 + fn*32 + lq;
        float bb = bias[colb];
        #pragma unroll
        for (int r = 0; r < 16; r++){
            int orow = row0 + wr*32 + (r&3) + 8*(r>>2) + 4*hi;
            if (orow < M_ROWS){
                int b = orow / NTOK, n = orow % NTOK;
                out[((size_t)n*NB + b)*NC + colb] = alpha*acc[fn][r] + bb;
            }
        }
    }
}

// ---------------------------------------------------------------------------
// Flash inner body with block-shared LDS staging of K (hi/lo) and VT.
// All 4 waves of the block process the same (b,h) -> stage once, read 4x.
// VAR=0: online softmax + 1/l (x_ori). VAR=1: static max + fused output-l2n.
// VAR=2: static max + 1/l.
// ---------------------------------------------------------------------------
template<int VAR>
__device__ __forceinline__ void flash_body(
    const unsigned short* Qh, const unsigned short* Ql,
    const unsigned short* Kh, const unsigned short* Kl,
    const unsigned short* VT,
    unsigned short* Ohi, unsigned short* Olo,
    float scale, int acc, int bh, int qt, int tid,
    unsigned short (*skh)[KP], unsigned short (*skl)[KP],
    unsigned short (*svt)[VP])
{
    int lane = tid & 63;
    int hi = lane >> 5, lq = lane & 31;
    const size_t base = (size_t)bh * NTOK * HD;
    const size_t vtb  = (size_t)bh * HD * VTW;

    // staging coords: K tile 32x64 (2 bufs), VT tile 64x32
    int karow = tid >> 3, kacol = (tid & 7) * 8;
    int varow = tid >> 2, vacol = (tid & 3) * 8;

    int qrow = qt*32 + lq;
    int qr = qrow < NTOK ? qrow : NTOK-1;
    const size_t qoff = base + (size_t)qr*HD + 8*hi;
    bf16x8_t qfh[4], qfl[4];
    #pragma unroll
    for (int c = 0; c < 4; c++){
        qfh[c] = *(const bf16x8_t*)(Qh + qoff + 16*c);
        qfl[c] = *(const bf16x8_t*)(Ql + qoff + 16*c);
    }

    f32x16_t od0, od1;
    #pragma unroll
    for (int r = 0; r < 16; r++){ od0[r]=0.f; od1[r]=0.f; }
    float m_ = -1e30f, l_ = 0.f;

    for (int kt = 0; kt < 19; kt++){
        // issue stage loads early (latency hides under the barrier)
        int gk = kt*32 + karow;
        if (gk >= NTOK) gk = NTOK-1;
        size_t ko = base + (size_t)gk*HD + kacol;
        u16x8_t ska = *(const u16x8_t*)(Kh + ko);
        u16x8_t skb = *(const u16x8_t*)(Kl + ko);
        u16x8_t sva = *(const u16x8_t*)(VT + vtb + (size_t)varow*VTW + kt*32 + vacol);
        __syncthreads();                    // prev iteration reads done
        *(u16x8_t*)&skh[karow][kacol] = ska;
        *(u16x8_t*)&skl[karow][kacol] = skb;
        *(u16x8_t*)&svt[varow][vacol] = sva;
        __syncthreads();                    // stores visible

        bf16x8_t kfh[4], kfl[4];
        #pragma unroll
        for (int c = 0; c < 4; c++){
            kfh[c] = *(const bf16x8_t*)&skh[lq][16*c + 8*hi];
            kfl[c] = *(const bf16x8_t*)&skl[lq][16*c + 8*hi];
        }
        f32x16_t sf;
        #pragma unroll
        for (int r = 0; r < 16; r++) sf[r] = 0.f;
        __builtin_amdgcn_s_setprio(1);
        #pragma unroll
        for (int c = 0; c < 4; c++){
            sf = __builtin_amdgcn_mfma_f32_32x32x16_bf16(kfh[c], qfh[c], sf, 0,0,0);
            sf = __builtin_amdgcn_mfma_f32_32x32x16_bf16(kfh[c], qfl[c], sf, 0,0,0);
            sf = __builtin_amdgcn_mfma_f32_32x32x16_bf16(kfl[c], qfh[c], sf, 0,0,0);
        }
        __builtin_amdgcn_s_setprio(0);

        float p[16];
        if (VAR == 0){
            float tm = -1e30f;
            if (kt == 18){
                #pragma unroll
                for (int r = 0; r < 16; r++){
                    int key = 576 + (r&3) + 8*(r>>2) + 4*hi;
                    p[r] = (key < NTOK) ? sf[r]*scale : -1e30f;
                    tm = fmaxf(tm, p[r]);
                }
            } else {
                #pragma unroll
                for (int r = 0; r < 16; r++){ p[r] = sf[r]*scale; tm = fmaxf(tm, p[r]); }
            }
            tm = fmaxf(tm, __shfl_xor(tm, 32));
            float mn = fmaxf(m_, tm);
            float corr = __expf(m_ - mn);
            float ps = 0.f;
            #pragma unroll
            for (int r = 0; r < 16; r++){ p[r] = __expf(p[r] - mn); ps += p[r]; }
            ps += __shfl_xor(ps, 32);
            l_ = l_*corr + ps;
            m_ = mn;
            #pragma unroll
            for (int r = 0; r < 16; r++){
                int crow = (r&3) + 8*(r>>2) + 4*hi;
                float cR = __shfl(corr, crow);
                od0[r] *= cR; od1[r] *= cR;
            }
        } else {
            // static max == scale (row max is the diagonal, exactly scale)
            if (kt == 18){
                #pragma unroll
                for (int r = 0; r < 16; r++){
                    int key = 576 + (r&3) + 8*(r>>2) + 4*hi;
                    p[r] = (key < NTOK) ? __expf(sf[r]*scale - scale) : 0.f;
                }
            } else {
                #pragma unroll
                for (int r = 0; r < 16; r++) p[r] = __expf(sf[r]*scale - scale);
            }
            if (VAR == 2){
                #pragma unroll
                for (int r = 0; r < 16; r++) l_ += p[r];
            }
        }

        U4 pa[2];
        #pragma unroll
        for (int ks = 0; ks < 2; ks++){
            unsigned int X0 = cvt_pk(p[8*ks+0], p[8*ks+1]);
            unsigned int X1 = cvt_pk(p[8*ks+2], p[8*ks+3]);
            unsigned int X2 = cvt_pk(p[8*ks+4], p[8*ks+5]);
            unsigned int X3 = cvt_pk(p[8*ks+6], p[8*ks+7]);
            unsigned int Y0 = (unsigned int)__shfl_xor((int)X2, 32);
            unsigned int Y1 = (unsigned int)__shfl_xor((int)X3, 32);
            unsigned int Y2 = (unsigned int)__shfl_xor((int)X0, 32);
            unsigned int Y3 = (unsigned int)__shfl_xor((int)X1, 32);
            pa[ks].u[0] = hi ? Y0 : X0;
            pa[ks].u[1] = hi ? Y1 : X1;
            pa[ks].u[2] = hi ? X2 : Y2;
            pa[ks].u[3] = hi ? X3 : Y3;
        }
        bf16x8_t vf00 = *(const bf16x8_t*)&svt[lq][8*hi];
        bf16x8_t vf01 = *(const bf16x8_t*)&svt[lq][16 + 8*hi];
        bf16x8_t vf10 = *(const bf16x8_t*)&svt[32+lq][8*hi];
        bf16x8_t vf11 = *(const bf16x8_t*)&svt[32+lq][16 + 8*hi];
        __builtin_amdgcn_s_setprio(1);
        od0 = __builtin_amdgcn_mfma_f32_32x32x16_bf16(pa[0].v, vf00, od0, 0,0,0);
        od0 = __builtin_amdgcn_mfma_f32_32x32x16_bf16(pa[1].v, vf01, od0, 0,0,0);
        od1 = __builtin_amdgcn_mfma_f32_32x32x16_bf16(pa[0].v, vf10, od1, 0,0,0);
        od1 = __builtin_amdgcn_mfma_f32_32x32x16_bf16(pa[1].v, vf11, od1, 0,0,0);
        __builtin_amdgcn_s_setprio(0);
    }

    if (VAR == 1){
        // fused l2n: z = od/||od|| per row (1/l cancels inside the norm)
        #pragma unroll
        for (int r = 0; r < 16; r++){
            float s = od0[r]*od0[r] + od1[r]*od1[r];
            #pragma unroll
            for (int o = 1; o < 32; o <<= 1) s += __shfl_xor(s, o);
            int crow = (r&3) + 8*(r>>2) + 4*hi;
            int qg = qt*32 + crow;
            if (qg < NTOK){
                float inv = 1.f / fmaxf(sqrtf(s), 1e-12f);
                size_t o0 = base + (size_t)qg*HD + lq;
                float a0 = od0[r]*inv, a1 = od1[r]*inv;
                unsigned short h0 = f2bf(a0), h1 = f2bf(a1);
                Ohi[o0] = h0;    Olo[o0]    = f2bf(a0 - bf2f(h0));
                Ohi[o0+32] = h1; Olo[o0+32] = f2bf(a1 - bf2f(h1));
            }
        }
        return;
    }

    if (VAR == 2) l_ = l_ + __shfl_xor(l_, 32);
    float linv = 1.f / l_;
    #pragma unroll
    for (int r = 0; r < 16; r++){
        int crow = (r&3) + 8*(r>>2) + 4*hi;
        int qg = qt*32 + crow;
        float li = __shfl(linv, crow);
        if (qg < NTOK){
            size_t o0 = base + (size_t)qg*HD + lq;
            float a0 = od0[r]*li, a1 = od1[r]*li;
            if (acc){
                a0 += bf2f(Ohi[o0])    + bf2f(Olo[o0]);
                a1 += bf2f(Ohi[o0+32]) + bf2f(Olo[o0+32]);
            }
            unsigned short h0 = f2bf(a0), h1 = f2bf(a1);
            Ohi[o0] = h0;    Olo[o0]    = f2bf(a0 - bf2f(h0));
            Ohi[o0+32] = h1; Olo[o0+32] = f2bf(a1 - bf2f(h1));
        }
    }
}

__global__ __launch_bounds__(256) void flash2(
    const unsigned short* __restrict__ Qh, const unsigned short* __restrict__ Ql,
    const unsigned short* __restrict__ Kh, const unsigned short* __restrict__ Kl,
    const unsigned short* __restrict__ VT,
    unsigned short* __restrict__ Ohi, unsigned short* __restrict__ Olo,
    const float* __restrict__ itemp, float cscale, int acc)
{
    __shared__ unsigned short skh[32][KP], skl[32][KP], svt[64][VP];
    int w = threadIdx.x >> 6;
    int bid = blockIdx.x;
    int bh = (bid & 7) * 16 + (bid >> 3) / 5;
    int qt = ((bid >> 3) % 5) * 4 + w;
    if (qt > 18) qt = 18;                 // dup wave writes identical bytes
    float scale = itemp ? itemp[bh >> 4] : cscale;
    flash_body<0>(Qh, Ql, Kh, Kl, VT, Ohi, Olo, scale, acc, bh, qt,
                  threadIdx.x, skh, skl, svt);
}

// Batched: 3 independent self-attentions (Q=K), slice = blockIdx.y.
template<int VAR>
__global__ __launch_bounds__(256) void flash2b(
    const unsigned short* __restrict__ q0h, const unsigned short* __restrict__ q0l,
    const unsigned short* __restrict__ q1h, const unsigned short* __restrict__ q1l,
    const unsigned short* __restrict__ q2h, const unsigned short* __restrict__ q2l,
    const unsigned short* __restrict__ vt0, const unsigned short* __restrict__ vt1,
    const unsigned short* __restrict__ vt2,
    unsigned short* __restrict__ o0h, unsigned short* __restrict__ o0l,
    unsigned short* __restrict__ o1h, unsigned short* __restrict__ o1l,
    unsigned short* __restrict__ o2h, unsigned short* __restrict__ o2l,
    const float* __restrict__ itemp)
{
    __shared__ unsigned short skh[32][KP], skl[32][KP], svt[64][VP];
    int w = threadIdx.x >> 6;
    int bid = blockIdx.x;
    int bh = (bid & 7) * 16 + (bid >> 3) / 5;
    int qt = ((bid >> 3) % 5) * 4 + w;
    if (qt > 18) qt = 18;
    int i = blockIdx.y;
    const unsigned short *Qh, *Ql, *VT;
    unsigned short *Oh, *Ol;
    if (i == 0){ Qh=q0h; Ql=q0l; VT=vt0; Oh=o0h; Ol=o0l; }
    else if (i == 1){ Qh=q1h; Ql=q1l; VT=vt1; Oh=o1h; Ol=o1l; }
    else { Qh=q2h; Ql=q2l; VT=vt2; Oh=o2h; Ol=o2l; }
    flash_body<VAR>(Qh, Ql, Qh, Ql, VT, Oh, Ol, itemp[bh >> 4], 0, bh, qt,
                    threadIdx.x, skh, skl, svt);
}

// ---------------------------------------------------------------------------
// sum of 3 split-bf16 buffers -> split-bf16 (fp32 adds, fixed order)
// ---------------------------------------------------------------------------
__global__ __launch_bounds__(256) void sum3(
    const unsigned short* __restrict__ ah, const unsigned short* __restrict__ al,
    const unsigned short* __restrict__ bh, const unsigned short* __restrict__ bl,
    const unsigned short* __restrict__ ch, const unsigned short* __restrict__ cl,
    unsigned short* __restrict__ oh, unsigned short* __restrict__ ol)
{
    size_t idx = ((size_t)blockIdx.x*256 + threadIdx.x)*4;
    ushort4 vah = *(const ushort4*)(ah+idx), val = *(const ushort4*)(al+idx);
    ushort4 vbh = *(const ushort4*)(bh+idx), vbl = *(const ushort4*)(bl+idx);
    ushort4 vch = *(const ushort4*)(ch+idx), vcl = *(const ushort4*)(cl+idx);
    ushort4 rh, rl;
    #define S3(f) { \
        float s = bf2f(vah.f)+bf2f(val.f)+bf2f(vbh.f)+bf2f(vbl.f)+bf2f(vch.f)+bf2f(vcl.f); \
        rh.f = f2bf(s); rl.f = f2bf(s - bf2f(rh.f)); }
    S3(x) S3(y) S3(z) S3(w)
    #undef S3
    *(ushort4*)(oh+idx) = rh;
    *(ushort4*)(ol+idx) = rl;
}

// ---------------------------------------------------------------------------
__global__ __launch_bounds__(256) void row_norm(const float* __restrict__ X,
                                                float* __restrict__ rn)
{
    int id = blockIdx.x;
    int b = id / NTOK, n = id % NTOK;
    const float* src = X + ((size_t)n*NB + b)*NC;
    int tid = threadIdx.x;
    float s = 0.f;
    for (int i = tid; i < NC; i += 256) { float t = src[i]; s += t*t; }
    #pragma unroll
    for (int o = 1; o < 64; o <<= 1) s += __shfl_xor(s, o);
    __shared__ float red[4];
    if ((tid & 63) == 0) red[tid >> 6] = s;
    __syncthreads();
    if (tid == 0) rn[id] = sqrtf(red[0] + red[1] + red[2] + red[3]);
}

__global__ __launch_bounds__(256) void calc_invtemp(const float* __restrict__ rn,
                                                    float* __restrict__ it)
{
    int b = blockIdx.x;
    int tid = threadIdx.x;
    float s = 0.f;
    for (int i = tid; i < NTOK; i += 256) s += rn[b*NTOK + i];
    #pragma unroll
    for (int o = 1; o < 64; o <<= 1) s += __shfl_xor(s, o);
    __shared__ float red[4];
    if ((tid & 63) == 0) red[tid >> 6] = s;
    __syncthreads();
    if (tid == 0) it[b] = (red[0]+red[1]+red[2]+red[3]) / (float)NTOK * 0.125f;
}

// ---------------------------------------------------------------------------
__global__ __launch_bounds__(256) void l2n_s2s(const unsigned short* __restrict__ ih,
        const unsigned short* __restrict__ il,
        unsigned short* __restrict__ oh, unsigned short* __restrict__ ol)
{
    size_t row = (size_t)blockIdx.x*4 + (threadIdx.x >> 6);
    int lane = threadIdx.x & 63;
    size_t ii = row*HD + lane;
    float x = bf2f(ih[ii]) + bf2f(il[ii]);
    float s = x*x;
    #pragma unroll
    for (int o = 1; o < 64; o <<= 1) s += __shfl_xor(s, o);
    float xn = x / fmaxf(sqrtf(s), 1e-12f);
    unsigned short hv = f2bf(xn);
    oh[ii] = hv;
    ol[ii] = f2bf(xn - bf2f(hv));
}

// ---------------------------------------------------------------------------
extern "C" void kernel_launch(void* const* d_in, const int* in_sizes, int n_in,
                              void* d_out, int out_size, void* d_ws, size_t ws_size,
                              hipStream_t stream)
{
    const float* x      = (const float*)d_in[0];
    const float* qkv_w  = (const float*)d_in[1];
    const float* qkv_b  = (const float*)d_in[2];
    const float* proj_w = (const float*)d_in[3];
    const float* proj_b = (const float*)d_in[4];
    float* out = (float*)d_out;            // [0,SZ)=x_gem, [SZ,2SZ)=x_ori

    unsigned short* w16 = (unsigned short*)d_ws;
    #define SL(i) (w16 + (size_t)(i)*SZ)          // 8 bf16 slots
    unsigned short* WQh = w16 + 8*SZ;             // WQ, dead after qkv
    unsigned short* WQl = WQh + WSZ;
    unsigned short* VT1 = WQh;                    // aliases WQ
    size_t p = 8*SZ + 2*WSZ;
    unsigned short* VTv = w16 + p;  p += VTSZ;
    unsigned short* VT2 = w16 + p;  p += VTSZ;    // batched-only
    unsigned short* VT3 = w16 + p;  p += VTSZ;    // batched-only
    unsigned short* WPh = w16 + p;  p += PSZ;
    unsigned short* WPl = w16 + p;  p += PSZ;
    unsigned short* E0  = w16 + p;  p += SZ;      // batched-only extra pair
    unsigned short* E1  = w16 + p;  p += SZ;
    float* rn = (float*)(w16 + p);
    float* it = rn + M_ROWS;
    size_t need = (p + 2*(M_ROWS + 8)) * sizeof(unsigned short);
    int batched = (ws_size >= need);

    unsigned short* S0 = (unsigned short*)d_out;  // x_gem bytes (scratch pair)
    unsigned short* S1 = S0 + SZ;

    dim3 blk(256);
    dim3 gq(24,37), gp(8,73), gfl(640), gflb(640,3), gt(10,128);

    // common prologue
    row_norm<<<dim3(M_ROWS), blk, 0, stream>>>(x, rn);
    calc_invtemp<<<dim3(NB), blk, 0, stream>>>(rn, it);
    split_rows<<<dim3(M_ROWS), blk, 0, stream>>>(x, SL(6), SL(7), 1);
    split_rows<<<dim3(3*NC),  blk, 0, stream>>>(qkv_w, WQh, WQl, 0);
    gemm_qkv_mfma<<<gq, blk, 0, stream>>>(SL(6), SL(7), WQh, WQl, qkv_b,
        SL(0), SL(1), SL(2), SL(3), SL(4), SL(5));
    transp64<<<gt, blk, 0, stream>>>(SL(4), VTv);
    // x_ori = proj(softmax(q k^T/8) v)
    flash2<<<gfl, blk, 0, stream>>>(SL(0),SL(1),SL(2),SL(3), VTv,
        SL(6),SL(7), nullptr, 0.125f, 0);
    split_rows<<<dim3(NC), blk, 0, stream>>>(proj_w, WPh, WPl, 0);
    gemm_proj_mfma<<<gp, blk, 0, stream>>>(SL(6),SL(7), WPh,WPl, proj_b, 1.f,
        out + SZ);

    if (batched){
        // xs_i = l2n in-place on v(4,5), k(2,3), q(0,1); then transposes
        l2n_s2s<<<dim3(18464), blk, 0, stream>>>(SL(4),SL(5), SL(4),SL(5));
        l2n_s2s<<<dim3(18464), blk, 0, stream>>>(SL(2),SL(3), SL(2),SL(3));
        l2n_s2s<<<dim3(18464), blk, 0, stream>>>(SL(0),SL(1), SL(0),SL(1));
        transp64<<<gt, blk, 0, stream>>>(SL(4), VT1);
        transp64<<<gt, blk, 0, stream>>>(SL(2), VT2);
        transp64<<<gt, blk, 0, stream>>>(SL(0), VT3);
        // z_i = l2n(ys_i) fused in epilogue (VAR=1): outputs (6,7), S, E
        flash2b<1><<<gflb, blk, 0, stream>>>(
            SL(4),SL(5), SL(2),SL(3), SL(0),SL(1),
            VT1, VT2, VT3,
            SL(6),SL(7), S0,S1, E0,E1, it);
        // final attentions concurrently (VAR=2, V = original v via VTv)
        flash2b<2><<<gflb, blk, 0, stream>>>(
            SL(6),SL(7), S0,S1, E0,E1,
            VTv, VTv, VTv,
            SL(4),SL(5), SL(2),SL(3), SL(0),SL(1), it);
        sum3<<<dim3(4616), blk, 0, stream>>>(
            SL(4),SL(5), SL(2),SL(3), SL(0),SL(1), SL(4),SL(5));
        gemm_proj_mfma<<<gp, blk, 0, stream>>>(SL(4),SL(5), WPh,WPl, proj_b,
            1.f/3.f, out);
    } else {
        // proven serial fallback (online softmax throughout)
        unsigned short* VTx = WQh;
        l2n_s2s<<<dim3(18464), blk, 0, stream>>>(SL(4),SL(5), SL(6),SL(7));
        transp64<<<gt, blk, 0, stream>>>(SL(6), VTx);
        flash2<<<gfl, blk, 0, stream>>>(SL(6),SL(7),SL(6),SL(7), VTx,
            SL(4),SL(5), it, 0.f, 0);
        l2n_s2s<<<dim3(18464), blk, 0, stream>>>(SL(4),SL(5), SL(6),SL(7));
        l2n_s2s<<<dim3(18464), blk, 0, stream>>>(SL(2),SL(3), SL(2),SL(3));
        transp64<<<gt, blk, 0, stream>>>(SL(2), VTx);
        flash2<<<gfl, blk, 0, stream>>>(SL(2),SL(3),SL(2),SL(3), VTx,
            SL(4),SL(5), it, 0.f, 0);
        l2n_s2s<<<dim3(18464), blk, 0, stream>>>(SL(4),SL(5), SL(2),SL(3));
        l2n_s2s<<<dim3(18464), blk, 0, stream>>>(SL(0),SL(1), SL(0),SL(1));
        transp64<<<gt, blk, 0, stream>>>(SL(0), VTx);
        flash2<<<gfl, blk, 0, stream>>>(SL(0),SL(1),SL(0),SL(1), VTx,
            SL(4),SL(5), it, 0.f, 0);
        l2n_s2s<<<dim3(18464), blk, 0, stream>>>(SL(4),SL(5), SL(0),SL(1));
        flash2<<<gfl, blk, 0, stream>>>(SL(6),SL(7),SL(6),SL(7), VTv,
            SL(4),SL(5), it, 0.f, 0);
        flash2<<<gfl, blk, 0, stream>>>(SL(2),SL(3),SL(2),SL(3), VTv,
            SL(4),SL(5), it, 0.f, 1);
        flash2<<<gfl, blk, 0, stream>>>(SL(0),SL(1),SL(0),SL(1), VTv,
            SL(4),SL(5), it, 0.f, 1);
        gemm_proj_mfma<<<gp, blk, 0, stream>>>(SL(4),SL(5), WPh,WPl, proj_b,
            1.f/3.f, out);
    }
    #undef SL
}

// Round 13
// 732.937 us; speedup vs baseline: 1.3446x; 1.3446x over previous
//
#include <hip/hip_runtime.h>
#include <math.h>

#define NTOK 577
#define NB 8
#define NC 1024
#define NH 16
#define HD 64
#define M_ROWS (NB*NTOK)               // 4616
#define SZ ((size_t)NB*NH*NTOK*HD)     // 4726784 elements
#define WSZ ((size_t)3*NC*NC)          // 3145728
#define PSZ ((size_t)NC*NC)            // 1048576
#define VTW 608                        // padded key width for VT (19*32)
#define VTSZ ((size_t)NB*NH*HD*VTW)    // 4980736
#define HSTR ((size_t)NTOK*HD)         // 36928 head stride in A-layout
#define LP 36                          // padded LDS row (32 data + 4 pad)

typedef __attribute__((ext_vector_type(8)))  short bf16x8_t;
typedef __attribute__((ext_vector_type(8)))  unsigned short u16x8_t;
typedef __attribute__((ext_vector_type(16))) float f32x16_t;

union U4 { unsigned short s[8]; unsigned int u[4]; bf16x8_t v; };

__device__ inline unsigned short f2bf(float x){
    unsigned int u = __float_as_uint(x);
    u = (u + 0x7FFFu + ((u>>16)&1u)) >> 16;
    return (unsigned short)u;
}
__device__ inline float bf2f(unsigned short h){
    return __uint_as_float(((unsigned int)h)<<16);
}
__device__ inline unsigned int cvt_pk(float a, float b){
    unsigned int r;
    asm volatile("v_cvt_pk_bf16_f32 %0, %1, %2" : "=v"(r) : "v"(a), "v"(b));
    return r;
}

// ---------------------------------------------------------------------------
// split fp32 rows -> bf16 hi/lo [nrows][1024]. mode 0: row-major src.
// mode 1: X [N,B,C] gather (row m=b*577+n -> src row n*8+b).
// ---------------------------------------------------------------------------
__global__ __launch_bounds__(256) void split_rows(const float* __restrict__ src,
        unsigned short* __restrict__ dh, unsigned short* __restrict__ dl, int mode)
{
    int row = blockIdx.x, t = threadIdx.x;
    const float* s;
    if (mode == 0) s = src + (size_t)row*NC + 4*t;
    else {
        int b = row / NTOK, n = row % NTOK;
        s = src + ((size_t)n*NB + b)*NC + 4*t;
    }
    float4 v = *(const float4*)s;
    ushort4 hv, lv;
    hv.x = f2bf(v.x); lv.x = f2bf(v.x - bf2f(hv.x));
    hv.y = f2bf(v.y); lv.y = f2bf(v.y - bf2f(hv.y));
    hv.z = f2bf(v.z); lv.z = f2bf(v.z - bf2f(hv.z));
    hv.w = f2bf(v.w); lv.w = f2bf(v.w - bf2f(hv.w));
    *(ushort4*)(dh + (size_t)row*NC + 4*t) = hv;
    *(ushort4*)(dl + (size_t)row*NC + 4*t) = lv;
}

// ---------------------------------------------------------------------------
// Coalesced transpose: src hi-bf16 [BH][577][64] -> dst [BH][64][608], pads=0.
// ---------------------------------------------------------------------------
__global__ __launch_bounds__(256) void transp64(const unsigned short* __restrict__ src,
                                                unsigned short* __restrict__ dst)
{
    __shared__ unsigned short t[64][72];
    int bh = blockIdx.y;
    int n0 = blockIdx.x * 64;
    int tid = threadIdx.x;
    int r  = tid >> 2;
    int c0 = (tid & 3) * 16;
    int n = n0 + r;
    if (n < NTOK){
        const unsigned short* s = src + ((size_t)bh*NTOK + n)*HD + c0;
        *(u16x8_t*)&t[r][c0]   = *(const u16x8_t*)s;
        *(u16x8_t*)&t[r][c0+8] = *(const u16x8_t*)(s + 8);
    } else {
        u16x8_t z = (u16x8_t)0;
        *(u16x8_t*)&t[r][c0]   = z;
        *(u16x8_t*)&t[r][c0+8] = z;
    }
    __syncthreads();
    if (n0 + c0 < VTW){
        int d = r;
        U4 o0, o1;
        #pragma unroll
        for (int j = 0; j < 8; j++){ o0.s[j] = t[c0+j][d]; o1.s[j] = t[c0+8+j][d]; }
        unsigned short* dp = dst + ((size_t)bh*HD + d)*VTW + n0 + c0;
        *(u16x8_t*)dp       = (u16x8_t)o0.v;
        *(u16x8_t*)(dp + 8) = (u16x8_t)o1.v;
    }
}

#define MFMA12(a0h,a1h,b0h,b1h,a0l,a1l,b0l,b1l) \
    acc[0][0] = __builtin_amdgcn_mfma_f32_32x32x16_bf16(a0h, b0h, acc[0][0], 0,0,0); \
    acc[0][1] = __builtin_amdgcn_mfma_f32_32x32x16_bf16(a0h, b1h, acc[0][1], 0,0,0); \
    acc[1][0] = __builtin_amdgcn_mfma_f32_32x32x16_bf16(a1h, b0h, acc[1][0], 0,0,0); \
    acc[1][1] = __builtin_amdgcn_mfma_f32_32x32x16_bf16(a1h, b1h, acc[1][1], 0,0,0); \
    acc[0][0] = __builtin_amdgcn_mfma_f32_32x32x16_bf16(a0h, b0l, acc[0][0], 0,0,0); \
    acc[0][1] = __builtin_amdgcn_mfma_f32_32x32x16_bf16(a0h, b1l, acc[0][1], 0,0,0); \
    acc[1][0] = __builtin_amdgcn_mfma_f32_32x32x16_bf16(a1h, b0l, acc[1][0], 0,0,0); \
    acc[1][1] = __builtin_amdgcn_mfma_f32_32x32x16_bf16(a1h, b1l, acc[1][1], 0,0,0); \
    acc[0][0] = __builtin_amdgcn_mfma_f32_32x32x16_bf16(a0l, b0h, acc[0][0], 0,0,0); \
    acc[0][1] = __builtin_amdgcn_mfma_f32_32x32x16_bf16(a0l, b1h, acc[0][1], 0,0,0); \
    acc[1][0] = __builtin_amdgcn_mfma_f32_32x32x16_bf16(a1l, b0h, acc[1][0], 0,0,0); \
    acc[1][1] = __builtin_amdgcn_mfma_f32_32x32x16_bf16(a1l, b1h, acc[1][1], 0,0,0);

// ---------------------------------------------------------------------------
// qkv GEMM, LDS-staged (128x128 tile, BK=32, padded LDS rows, 4 waves 2x2).
// ---------------------------------------------------------------------------
__global__ __launch_bounds__(256) void gemm_qkv_mfma(
    const unsigned short* __restrict__ Ah, const unsigned short* __restrict__ Al,
    const unsigned short* __restrict__ Bh, const unsigned short* __restrict__ Bl,
    const float* __restrict__ bias,
    unsigned short* __restrict__ qh, unsigned short* __restrict__ ql,
    unsigned short* __restrict__ kh, unsigned short* __restrict__ kl,
    unsigned short* __restrict__ vh, unsigned short* __restrict__ vl)
{
    __shared__ unsigned short ahs[128][LP], als[128][LP];
    __shared__ unsigned short bhs[128][LP], bls[128][LP];
    int t = threadIdx.x;
    int l = t & 63, w = t >> 6;
    int lq = l & 31, hi = l >> 5;
    int wr = w >> 1, wc = w & 1;
    int col0 = blockIdx.x*128, row0 = blockIdx.y*128;

    int srow[2], scol[2], sa[2];
    #pragma unroll
    for (int i = 0; i < 2; i++){
        int idx = i*256 + t;
        srow[i] = idx >> 2;
        scol[i] = (idx & 3) * 8;
        int ar = row0 + srow[i]; if (ar >= M_ROWS) ar = M_ROWS-1;
        sa[i] = ar;
    }

    f32x16_t acc[2][2];
    #pragma unroll
    for (int i = 0; i < 16; i++){
        acc[0][0][i]=0.f; acc[0][1][i]=0.f; acc[1][0][i]=0.f; acc[1][1][i]=0.f;
    }

    for (int k0 = 0; k0 < NC; k0 += 32){
        if (k0) __syncthreads();
        #pragma unroll
        for (int i = 0; i < 2; i++){
            size_t ao = (size_t)sa[i]*NC + k0 + scol[i];
            size_t bo = (size_t)(col0 + srow[i])*NC + k0 + scol[i];
            u16x8_t va  = *(const u16x8_t*)(Ah + ao);
            u16x8_t va2 = *(const u16x8_t*)(Al + ao);
            u16x8_t vb  = *(const u16x8_t*)(Bh + bo);
            u16x8_t vb2 = *(const u16x8_t*)(Bl + bo);
            *(u16x8_t*)&ahs[srow[i]][scol[i]] = va;
            *(u16x8_t*)&als[srow[i]][scol[i]] = va2;
            *(u16x8_t*)&bhs[srow[i]][scol[i]] = vb;
            *(u16x8_t*)&bls[srow[i]][scol[i]] = vb2;
        }
        __syncthreads();
        #pragma unroll
        for (int kk = 0; kk < 2; kk++){
            int co = kk*16 + 8*hi;
            bf16x8_t a0h = *(const bf16x8_t*)&ahs[wr*64+lq][co];
            bf16x8_t a1h = *(const bf16x8_t*)&ahs[wr*64+32+lq][co];
            bf16x8_t b0h = *(const bf16x8_t*)&bhs[wc*64+lq][co];
            bf16x8_t b1h = *(const bf16x8_t*)&bhs[wc*64+32+lq][co];
            bf16x8_t a0l = *(const bf16x8_t*)&als[wr*64+lq][co];
            bf16x8_t a1l = *(const bf16x8_t*)&als[wr*64+32+lq][co];
            bf16x8_t b0l = *(const bf16x8_t*)&bls[wc*64+lq][co];
            bf16x8_t b1l = *(const bf16x8_t*)&bls[wc*64+32+lq][co];
            MFMA12(a0h,a1h,b0h,b1h,a0l,a1l,b0l,b1l)
        }
    }

    int colW = col0 + wc*64, rowW = row0 + wr*64;
    #pragma unroll
    for (int fn = 0; fn < 2; fn++){
        int colb = colW + fn*32 + lq;
        float bb = bias[colb];
        int tt = colb >> 10, h = (colb >> 6) & 15, d = colb & 63;
        unsigned short* dsth = (tt == 0) ? qh : (tt == 1 ? kh : vh);
        unsigned short* dstl = (tt == 0) ? ql : (tt == 1 ? kl : vl);
        #pragma unroll
        for (int fm = 0; fm < 2; fm++){
            #pragma unroll
            for (int r = 0; r < 16; r++){
                int orow = rowW + fm*32 + (r&3) + 8*(r>>2) + 4*hi;
                if (orow < M_ROWS){
                    float val = acc[fm][fn][r] + bb;
                    int b = orow / NTOK, n = orow % NTOK;
                    unsigned short hv = f2bf(val);
                    unsigned short lv = f2bf(val - bf2f(hv));
                    size_t idx = ((size_t)(b*NH + h)*NTOK + n)*HD + d;
                    dsth[idx] = hv; dstl[idx] = lv;
                }
            }
        }
    }
}

// ---------------------------------------------------------------------------
// proj GEMM, LDS-staged (64x128 tile, BK=32). A split bf16 in HEAD layout.
// ---------------------------------------------------------------------------
__global__ __launch_bounds__(256) void gemm_proj_mfma(
    const unsigned short* __restrict__ Ah, const unsigned short* __restrict__ Al,
    const unsigned short* __restrict__ Bh, const unsigned short* __restrict__ Bl,
    const float* __restrict__ bias, float alpha, float* __restrict__ out)
{
    __shared__ unsigned short ahs[64][LP], als[64][LP];
    __shared__ unsigned short bhs[128][LP], bls[128][LP];
    int t = threadIdx.x;
    int l = t & 63, w = t >> 6;
    int lq = l & 31, hi = l >> 5;
    int wr = w >> 1, wc = w & 1;
    int col0 = blockIdx.x*128, row0 = blockIdx.y*64;

    int sarow = t >> 2, sacol = (t & 3) * 8;
    int ar = row0 + sarow; if (ar >= M_ROWS) ar = M_ROWS-1;
    size_t abase = (size_t)(ar / NTOK)*NH*HSTR + (size_t)(ar % NTOK)*HD;
    int sbrow[2], sbcol[2];
    #pragma unroll
    for (int i = 0; i < 2; i++){
        int idx = i*256 + t;
        sbrow[i] = idx >> 2;
        sbcol[i] = (idx & 3) * 8;
    }

    f32x16_t acc[2];
    #pragma unroll
    for (int i = 0; i < 16; i++){ acc[0][i]=0.f; acc[1][i]=0.f; }

    for (int k0 = 0; k0 < NC; k0 += 32){
        if (k0) __syncthreads();
        {
            int kk = k0 + sacol;
            size_t ao = abase + (size_t)(kk >> 6)*HSTR + (kk & 63);
            u16x8_t va  = *(const u16x8_t*)(Ah + ao);
            u16x8_t va2 = *(const u16x8_t*)(Al + ao);
            *(u16x8_t*)&ahs[sarow][sacol] = va;
            *(u16x8_t*)&als[sarow][sacol] = va2;
            #pragma unroll
            for (int i = 0; i < 2; i++){
                size_t bo = (size_t)(col0 + sbrow[i])*NC + k0 + sbcol[i];
                u16x8_t vb  = *(const u16x8_t*)(Bh + bo);
                u16x8_t vb2 = *(const u16x8_t*)(Bl + bo);
                *(u16x8_t*)&bhs[sbrow[i]][sbcol[i]] = vb;
                *(u16x8_t*)&bls[sbrow[i]][sbcol[i]] = vb2;
            }
        }
        __syncthreads();
        #pragma unroll
        for (int kk = 0; kk < 2; kk++){
            int co = kk*16 + 8*hi;
            bf16x8_t a0h = *(const bf16x8_t*)&ahs[wr*32+lq][co];
            bf16x8_t a0l = *(const bf16x8_t*)&als[wr*32+lq][co];
            bf16x8_t b0h = *(const bf16x8_t*)&bhs[wc*64+lq][co];
            bf16x8_t b1h = *(const bf16x8_t*)&bhs[wc*64+32+lq][co];
            bf16x8_t b0l = *(const bf16x8_t*)&bls[wc*64+lq][co];
            bf16x8_t b1l = *(const bf16x8_t*)&bls[wc*64+32+lq][co];
            acc[0] = __builtin_amdgcn_mfma_f32_32x32x16_bf16(a0h, b0h, acc[0], 0,0,0);
            acc[1] = __builtin_amdgcn_mfma_f32_32x32x16_bf16(a0h, b1h, acc[1], 0,0,0);
            acc[0] = __builtin_amdgcn_mfma_f32_32x32x16_bf16(a0h, b0l, acc[0], 0,0,0);
            acc[1] = __builtin_amdgcn_mfma_f32_32x32x16_bf16(a0h, b1l, acc[1], 0,0,0);
            acc[0] = __builtin_amdgcn_mfma_f32_32x32x16_bf16(a0l, b0h, acc[0], 0,0,0);
            acc[1] = __builtin_amdgcn_mfma_f32_32x32x16_bf16(a0l, b1h, acc[1], 0,0,0);
        }
    }

    #pragma unroll
    for (int fn = 0; fn < 2; fn++){
        int colb = col0 + wc*64 + fn*32 + lq;
        float bb = bias[colb];
        #pragma unroll
        for (int r = 0; r < 16; r++){
            int orow = row0 + wr*32 + (r&3) + 8*(r>>2) + 4*hi;
            if (orow < M_ROWS){
                int b = orow / NTOK, n = orow % NTOK;
                out[((size_t)n*NB + b)*NC + colb] = alpha*acc[fn][r] + bb;
            }
        }
    }
}

// ---------------------------------------------------------------------------
// Flash inner body, no LDS (R11-proven math), 2-deep kt register pipeline:
// prefetch next kt's {K hi/lo, VT} registers while computing current kt.
// VAR=0: online softmax + 1/l (x_ori). VAR=1: static max + fused output-l2n.
// VAR=2: static max + 1/l.
// ---------------------------------------------------------------------------
#define LOADKV(Pkh, Pkl, Pv, KT) { \
    int krow_ = (KT)*32 + lq; \
    int kr_ = krow_ < NTOK ? krow_ : NTOK-1; \
    const size_t ko_ = base + (size_t)kr_*HD + 8*hi; \
    _Pragma("unroll") \
    for (int c = 0; c < 4; c++){ \
        Pkh[c] = *(const bf16x8_t*)(Kh + ko_ + 16*c); \
        Pkl[c] = *(const bf16x8_t*)(Kl + ko_ + 16*c); \
    } \
    const size_t v0_ = vtb + (size_t)lq*VTW + (KT)*32 + 8*hi; \
    const size_t v1_ = vtb + (size_t)(32+lq)*VTW + (KT)*32 + 8*hi; \
    Pv[0] = *(const bf16x8_t*)(VT + v0_); \
    Pv[1] = *(const bf16x8_t*)(VT + v0_ + 16); \
    Pv[2] = *(const bf16x8_t*)(VT + v1_); \
    Pv[3] = *(const bf16x8_t*)(VT + v1_ + 16); \
}

#define COMPUTE(Pkh, Pkl, Pv, KT) { \
    f32x16_t sf; \
    _Pragma("unroll") \
    for (int r = 0; r < 16; r++) sf[r] = 0.f; \
    __builtin_amdgcn_s_setprio(1); \
    _Pragma("unroll") \
    for (int c = 0; c < 4; c++){ \
        sf = __builtin_amdgcn_mfma_f32_32x32x16_bf16(Pkh[c], qfh[c], sf, 0,0,0); \
        sf = __builtin_amdgcn_mfma_f32_32x32x16_bf16(Pkh[c], qfl[c], sf, 0,0,0); \
        sf = __builtin_amdgcn_mfma_f32_32x32x16_bf16(Pkl[c], qfh[c], sf, 0,0,0); \
    } \
    __builtin_amdgcn_s_setprio(0); \
    float p[16]; \
    if (VAR == 0){ \
        float tm = -1e30f; \
        if ((KT) == 18){ \
            _Pragma("unroll") \
            for (int r = 0; r < 16; r++){ \
                int key = 576 + (r&3) + 8*(r>>2) + 4*hi; \
                p[r] = (key < NTOK) ? sf[r]*scale : -1e30f; \
                tm = fmaxf(tm, p[r]); \
            } \
        } else { \
            _Pragma("unroll") \
            for (int r = 0; r < 16; r++){ p[r] = sf[r]*scale; tm = fmaxf(tm, p[r]); } \
        } \
        tm = fmaxf(tm, __shfl_xor(tm, 32)); \
        float mn = fmaxf(m_, tm); \
        float corr = __expf(m_ - mn); \
        float ps = 0.f; \
        _Pragma("unroll") \
        for (int r = 0; r < 16; r++){ p[r] = __expf(p[r] - mn); ps += p[r]; } \
        ps += __shfl_xor(ps, 32); \
        l_ = l_*corr + ps; \
        m_ = mn; \
        _Pragma("unroll") \
        for (int r = 0; r < 16; r++){ \
            int crow = (r&3) + 8*(r>>2) + 4*hi; \
            float cR = __shfl(corr, crow); \
            od0[r] *= cR; od1[r] *= cR; \
        } \
    } else { \
        if ((KT) == 18){ \
            _Pragma("unroll") \
            for (int r = 0; r < 16; r++){ \
                int key = 576 + (r&3) + 8*(r>>2) + 4*hi; \
                p[r] = (key < NTOK) ? __expf(sf[r]*scale - scale) : 0.f; \
            } \
        } else { \
            _Pragma("unroll") \
            for (int r = 0; r < 16; r++) p[r] = __expf(sf[r]*scale - scale); \
        } \
        if (VAR == 2){ \
            _Pragma("unroll") \
            for (int r = 0; r < 16; r++) l_ += p[r]; \
        } \
    } \
    U4 pa[2]; \
    _Pragma("unroll") \
    for (int ks = 0; ks < 2; ks++){ \
        unsigned int X0 = cvt_pk(p[8*ks+0], p[8*ks+1]); \
        unsigned int X1 = cvt_pk(p[8*ks+2], p[8*ks+3]); \
        unsigned int X2 = cvt_pk(p[8*ks+4], p[8*ks+5]); \
        unsigned int X3 = cvt_pk(p[8*ks+6], p[8*ks+7]); \
        unsigned int Y0 = (unsigned int)__shfl_xor((int)X2, 32); \
        unsigned int Y1 = (unsigned int)__shfl_xor((int)X3, 32); \
        unsigned int Y2 = (unsigned int)__shfl_xor((int)X0, 32); \
        unsigned int Y3 = (unsigned int)__shfl_xor((int)X1, 32); \
        pa[ks].u[0] = hi ? Y0 : X0; \
        pa[ks].u[1] = hi ? Y1 : X1; \
        pa[ks].u[2] = hi ? X2 : Y2; \
        pa[ks].u[3] = hi ? X3 : Y3; \
    } \
    __builtin_amdgcn_s_setprio(1); \
    od0 = __builtin_amdgcn_mfma_f32_32x32x16_bf16(pa[0].v, Pv[0], od0, 0,0,0); \
    od0 = __builtin_amdgcn_mfma_f32_32x32x16_bf16(pa[1].v, Pv[1], od0, 0,0,0); \
    od1 = __builtin_amdgcn_mfma_f32_32x32x16_bf16(pa[0].v, Pv[2], od1, 0,0,0); \
    od1 = __builtin_amdgcn_mfma_f32_32x32x16_bf16(pa[1].v, Pv[3], od1, 0,0,0); \
    __builtin_amdgcn_s_setprio(0); \
}

template<int VAR>
__device__ __forceinline__ void flash_body(
    const unsigned short* Qh, const unsigned short* Ql,
    const unsigned short* Kh, const unsigned short* Kl,
    const unsigned short* VT,
    unsigned short* Ohi, unsigned short* Olo,
    float scale, int acc, int bh, int qt, int lane)
{
    int hi = lane >> 5, lq = lane & 31;
    const size_t base = (size_t)bh * NTOK * HD;
    const size_t vtb  = (size_t)bh * HD * VTW;

    int qrow = qt*32 + lq;
    int qr = qrow < NTOK ? qrow : NTOK-1;
    const size_t qoff = base + (size_t)qr*HD + 8*hi;
    bf16x8_t qfh[4], qfl[4];
    #pragma unroll
    for (int c = 0; c < 4; c++){
        qfh[c] = *(const bf16x8_t*)(Qh + qoff + 16*c);
        qfl[c] = *(const bf16x8_t*)(Ql + qoff + 16*c);
    }

    f32x16_t od0, od1;
    #pragma unroll
    for (int r = 0; r < 16; r++){ od0[r]=0.f; od1[r]=0.f; }
    float m_ = -1e30f, l_ = 0.f;

    // 2-deep register pipeline over kt = 0..18
    bf16x8_t Xkh[4], Xkl[4], Xv[4];
    bf16x8_t Ykh[4], Ykl[4], Yv[4];
    LOADKV(Xkh, Xkl, Xv, 0)
    for (int kt = 0; kt < 18; kt += 2){
        LOADKV(Ykh, Ykl, Yv, kt+1)
        COMPUTE(Xkh, Xkl, Xv, kt)
        if (kt + 2 < 19) LOADKV(Xkh, Xkl, Xv, kt+2)
        COMPUTE(Ykh, Ykl, Yv, kt+1)
    }
    COMPUTE(Xkh, Xkl, Xv, 18)

    if (VAR == 1){
        // fused l2n: z = od/||od|| per row (1/l cancels inside the norm)
        #pragma unroll
        for (int r = 0; r < 16; r++){
            float s = od0[r]*od0[r] + od1[r]*od1[r];
            #pragma unroll
            for (int o = 1; o < 32; o <<= 1) s += __shfl_xor(s, o);
            int crow = (r&3) + 8*(r>>2) + 4*hi;
            int qg = qt*32 + crow;
            if (qg < NTOK){
                float inv = 1.f / fmaxf(sqrtf(s), 1e-12f);
                size_t o0 = base + (size_t)qg*HD + lq;
                float a0 = od0[r]*inv, a1 = od1[r]*inv;
                unsigned short h0 = f2bf(a0), h1 = f2bf(a1);
                Ohi[o0] = h0;    Olo[o0]    = f2bf(a0 - bf2f(h0));
                Ohi[o0+32] = h1; Olo[o0+32] = f2bf(a1 - bf2f(h1));
            }
        }
        return;
    }

    if (VAR == 2) l_ = l_ + __shfl_xor(l_, 32);
    float linv = 1.f / l_;
    #pragma unroll
    for (int r = 0; r < 16; r++){
        int crow = (r&3) + 8*(r>>2) + 4*hi;
        int qg = qt*32 + crow;
        float li = __shfl(linv, crow);
        if (qg < NTOK){
            size_t o0 = base + (size_t)qg*HD + lq;
            float a0 = od0[r]*li, a1 = od1[r]*li;
            if (acc){
                a0 += bf2f(Ohi[o0])    + bf2f(Olo[o0]);
                a1 += bf2f(Ohi[o0+32]) + bf2f(Olo[o0+32]);
            }
            unsigned short h0 = f2bf(a0), h1 = f2bf(a1);
            Ohi[o0] = h0;    Olo[o0]    = f2bf(a0 - bf2f(h0));
            Ohi[o0+32] = h1; Olo[o0+32] = f2bf(a1 - bf2f(h1));
        }
    }
}

__global__ __launch_bounds__(256) void flash2(
    const unsigned short* __restrict__ Qh, const unsigned short* __restrict__ Ql,
    const unsigned short* __restrict__ Kh, const unsigned short* __restrict__ Kl,
    const unsigned short* __restrict__ VT,
    unsigned short* __restrict__ Ohi, unsigned short* __restrict__ Olo,
    const float* __restrict__ itemp, float cscale, int acc)
{
    int w = threadIdx.x >> 6, lane = threadIdx.x & 63;
    int bid = blockIdx.x;
    int bh = (bid & 7) * 16 + (bid >> 3) / 5;
    int qt = ((bid >> 3) % 5) * 4 + w;
    if (qt >= 19) return;
    float scale = itemp ? itemp[bh >> 4] : cscale;
    flash_body<0>(Qh, Ql, Kh, Kl, VT, Ohi, Olo, scale, acc, bh, qt, lane);
}

// Batched: 3 independent self-attentions (Q=K), slice = blockIdx.y.
template<int VAR>
__global__ __launch_bounds__(256) void flash2b(
    const unsigned short* __restrict__ q0h, const unsigned short* __restrict__ q0l,
    const unsigned short* __restrict__ q1h, const unsigned short* __restrict__ q1l,
    const unsigned short* __restrict__ q2h, const unsigned short* __restrict__ q2l,
    const unsigned short* __restrict__ vt0, const unsigned short* __restrict__ vt1,
    const unsigned short* __restrict__ vt2,
    unsigned short* __restrict__ o0h, unsigned short* __restrict__ o0l,
    unsigned short* __restrict__ o1h, unsigned short* __restrict__ o1l,
    unsigned short* __restrict__ o2h, unsigned short* __restrict__ o2l,
    const float* __restrict__ itemp)
{
    int w = threadIdx.x >> 6, lane = threadIdx.x & 63;
    int bid = blockIdx.x;
    int bh = (bid & 7) * 16 + (bid >> 3) / 5;
    int qt = ((bid >> 3) % 5) * 4 + w;
    if (qt >= 19) return;
    int i = blockIdx.y;
    const unsigned short *Qh, *Ql, *VT;
    unsigned short *Oh, *Ol;
    if (i == 0){ Qh=q0h; Ql=q0l; VT=vt0; Oh=o0h; Ol=o0l; }
    else if (i == 1){ Qh=q1h; Ql=q1l; VT=vt1; Oh=o1h; Ol=o1l; }
    else { Qh=q2h; Ql=q2l; VT=vt2; Oh=o2h; Ol=o2l; }
    flash_body<VAR>(Qh, Ql, Qh, Ql, VT, Oh, Ol, itemp[bh >> 4], 0, bh, qt, lane);
}

// ---------------------------------------------------------------------------
// sum of 3 split-bf16 buffers -> split-bf16 (fp32 adds, fixed order)
// ---------------------------------------------------------------------------
__global__ __launch_bounds__(256) void sum3(
    const unsigned short* __restrict__ ah, const unsigned short* __restrict__ al,
    const unsigned short* __restrict__ bh, const unsigned short* __restrict__ bl,
    const unsigned short* __restrict__ ch, const unsigned short* __restrict__ cl,
    unsigned short* __restrict__ oh, unsigned short* __restrict__ ol)
{
    size_t idx = ((size_t)blockIdx.x*256 + threadIdx.x)*4;
    ushort4 vah = *(const ushort4*)(ah+idx), val = *(const ushort4*)(al+idx);
    ushort4 vbh = *(const ushort4*)(bh+idx), vbl = *(const ushort4*)(bl+idx);
    ushort4 vch = *(const ushort4*)(ch+idx), vcl = *(const ushort4*)(cl+idx);
    ushort4 rh, rl;
    #define S3(f) { \
        float s = bf2f(vah.f)+bf2f(val.f)+bf2f(vbh.f)+bf2f(vbl.f)+bf2f(vch.f)+bf2f(vcl.f); \
        rh.f = f2bf(s); rl.f = f2bf(s - bf2f(rh.f)); }
    S3(x) S3(y) S3(z) S3(w)
    #undef S3
    *(ushort4*)(oh+idx) = rh;
    *(ushort4*)(ol+idx) = rl;
}

// ---------------------------------------------------------------------------
__global__ __launch_bounds__(256) void row_norm(const float* __restrict__ X,
                                                float* __restrict__ rn)
{
    int id = blockIdx.x;
    int b = id / NTOK, n = id % NTOK;
    const float* src = X + ((size_t)n*NB + b)*NC;
    int tid = threadIdx.x;
    float s = 0.f;
    for (int i = tid; i < NC; i += 256) { float t = src[i]; s += t*t; }
    #pragma unroll
    for (int o = 1; o < 64; o <<= 1) s += __shfl_xor(s, o);
    __shared__ float red[4];
    if ((tid & 63) == 0) red[tid >> 6] = s;
    __syncthreads();
    if (tid == 0) rn[id] = sqrtf(red[0] + red[1] + red[2] + red[3]);
}

__global__ __launch_bounds__(256) void calc_invtemp(const float* __restrict__ rn,
                                                    float* __restrict__ it)
{
    int b = blockIdx.x;
    int tid = threadIdx.x;
    float s = 0.f;
    for (int i = tid; i < NTOK; i += 256) s += rn[b*NTOK + i];
    #pragma unroll
    for (int o = 1; o < 64; o <<= 1) s += __shfl_xor(s, o);
    __shared__ float red[4];
    if ((tid & 63) == 0) red[tid >> 6] = s;
    __syncthreads();
    if (tid == 0) it[b] = (red[0]+red[1]+red[2]+red[3]) / (float)NTOK * 0.125f;
}

// ---------------------------------------------------------------------------
__global__ __launch_bounds__(256) void l2n_s2s(const unsigned short* __restrict__ ih,
        const unsigned short* __restrict__ il,
        unsigned short* __restrict__ oh, unsigned short* __restrict__ ol)
{
    size_t row = (size_t)blockIdx.x*4 + (threadIdx.x >> 6);
    int lane = threadIdx.x & 63;
    size_t ii = row*HD + lane;
    float x = bf2f(ih[ii]) + bf2f(il[ii]);
    float s = x*x;
    #pragma unroll
    for (int o = 1; o < 64; o <<= 1) s += __shfl_xor(s, o);
    float xn = x / fmaxf(sqrtf(s), 1e-12f);
    unsigned short hv = f2bf(xn);
    oh[ii] = hv;
    ol[ii] = f2bf(xn - bf2f(hv));
}

// ---------------------------------------------------------------------------
extern "C" void kernel_launch(void* const* d_in, const int* in_sizes, int n_in,
                              void* d_out, int out_size, void* d_ws, size_t ws_size,
                              hipStream_t stream)
{
    const float* x      = (const float*)d_in[0];
    const float* qkv_w  = (const float*)d_in[1];
    const float* qkv_b  = (const float*)d_in[2];
    const float* proj_w = (const float*)d_in[3];
    const float* proj_b = (const float*)d_in[4];
    float* out = (float*)d_out;            // [0,SZ)=x_gem, [SZ,2SZ)=x_ori

    unsigned short* w16 = (unsigned short*)d_ws;
    #define SL(i) (w16 + (size_t)(i)*SZ)          // 8 bf16 slots
    unsigned short* WQh = w16 + 8*SZ;             // WQ, dead after qkv
    unsigned short* WQl = WQh + WSZ;
    unsigned short* VT1 = WQh;                    // aliases WQ
    size_t p = 8*SZ + 2*WSZ;
    unsigned short* VTv = w16 + p;  p += VTSZ;
    unsigned short* VT2 = w16 + p;  p += VTSZ;    // batched-only
    unsigned short* VT3 = w16 + p;  p += VTSZ;    // batched-only
    unsigned short* WPh = w16 + p;  p += PSZ;
    unsigned short* WPl = w16 + p;  p += PSZ;
    unsigned short* E0  = w16 + p;  p += SZ;      // batched-only extra pair
    unsigned short* E1  = w16 + p;  p += SZ;
    float* rn = (float*)(w16 + p);
    float* it = rn + M_ROWS;
    size_t need = (p + 2*(M_ROWS + 8)) * sizeof(unsigned short);
    int batched = (ws_size >= need);

    unsigned short* S0 = (unsigned short*)d_out;  // x_gem bytes (scratch pair)
    unsigned short* S1 = S0 + SZ;

    dim3 blk(256);
    dim3 gq(24,37), gp(8,73), gfl(640), gflb(640,3), gt(10,128);

    // common prologue
    row_norm<<<dim3(M_ROWS), blk, 0, stream>>>(x, rn);
    calc_invtemp<<<dim3(NB), blk, 0, stream>>>(rn, it);
    split_rows<<<dim3(M_ROWS), blk, 0, stream>>>(x, SL(6), SL(7), 1);
    split_rows<<<dim3(3*NC),  blk, 0, stream>>>(qkv_w, WQh, WQl, 0);
    gemm_qkv_mfma<<<gq, blk, 0, stream>>>(SL(6), SL(7), WQh, WQl, qkv_b,
        SL(0), SL(1), SL(2), SL(3), SL(4), SL(5));
    transp64<<<gt, blk, 0, stream>>>(SL(4), VTv);
    // x_ori = proj(softmax(q k^T/8) v)
    flash2<<<gfl, blk, 0, stream>>>(SL(0),SL(1),SL(2),SL(3), VTv,
        SL(6),SL(7), nullptr, 0.125f, 0);
    split_rows<<<dim3(NC), blk, 0, stream>>>(proj_w, WPh, WPl, 0);
    gemm_proj_mfma<<<gp, blk, 0, stream>>>(SL(6),SL(7), WPh,WPl, proj_b, 1.f,
        out + SZ);

    if (batched){
        // xs_i = l2n in-place on v(4,5), k(2,3), q(0,1); then transposes
        l2n_s2s<<<dim3(18464), blk, 0, stream>>>(SL(4),SL(5), SL(4),SL(5));
        l2n_s2s<<<dim3(18464), blk, 0, stream>>>(SL(2),SL(3), SL(2),SL(3));
        l2n_s2s<<<dim3(18464), blk, 0, stream>>>(SL(0),SL(1), SL(0),SL(1));
        transp64<<<gt, blk, 0, stream>>>(SL(4), VT1);
        transp64<<<gt, blk, 0, stream>>>(SL(2), VT2);
        transp64<<<gt, blk, 0, stream>>>(SL(0), VT3);
        // z_i = l2n(ys_i) fused in epilogue (VAR=1): outputs (6,7), S, E
        flash2b<1><<<gflb, blk, 0, stream>>>(
            SL(4),SL(5), SL(2),SL(3), SL(0),SL(1),
            VT1, VT2, VT3,
            SL(6),SL(7), S0,S1, E0,E1, it);
        // final attentions concurrently (VAR=2, V = original v via VTv)
        flash2b<2><<<gflb, blk, 0, stream>>>(
            SL(6),SL(7), S0,S1, E0,E1,
            VTv, VTv, VTv,
            SL(4),SL(5), SL(2),SL(3), SL(0),SL(1), it);
        sum3<<<dim3(4616), blk, 0, stream>>>(
            SL(4),SL(5), SL(2),SL(3), SL(0),SL(1), SL(4),SL(5));
        gemm_proj_mfma<<<gp, blk, 0, stream>>>(SL(4),SL(5), WPh,WPl, proj_b,
            1.f/3.f, out);
    } else {
        // proven serial fallback (online softmax throughout)
        unsigned short* VTx = WQh;
        l2n_s2s<<<dim3(18464), blk, 0, stream>>>(SL(4),SL(5), SL(6),SL(7));
        transp64<<<gt, blk, 0, stream>>>(SL(6), VTx);
        flash2<<<gfl, blk, 0, stream>>>(SL(6),SL(7),SL(6),SL(7), VTx,
            SL(4),SL(5), it, 0.f, 0);
        l2n_s2s<<<dim3(18464), blk, 0, stream>>>(SL(4),SL(5), SL(6),SL(7));
        l2n_s2s<<<dim3(18464), blk, 0, stream>>>(SL(2),SL(3), SL(2),SL(3));
        transp64<<<gt, blk, 0, stream>>>(SL(2), VTx);
        flash2<<<gfl, blk, 0, stream>>>(SL(2),SL(3),SL(2),SL(3), VTx,
            SL(4),SL(5), it, 0.f, 0);
        l2n_s2s<<<dim3(18464), blk, 0, stream>>>(SL(4),SL(5), SL(2),SL(3));
        l2n_s2s<<<dim3(18464), blk, 0, stream>>>(SL(0),SL(1), SL(0),SL(1));
        transp64<<<gt, blk, 0, stream>>>(SL(0), VTx);
        flash2<<<gfl, blk, 0, stream>>>(SL(0),SL(1),SL(0),SL(1), VTx,
            SL(4),SL(5), it, 0.f, 0);
        l2n_s2s<<<dim3(18464), blk, 0, stream>>>(SL(4),SL(5), SL(0),SL(1));
        flash2<<<gfl, blk, 0, stream>>>(SL(6),SL(7),SL(6),SL(7), VTv,
            SL(4),SL(5), it, 0.f, 0);
        flash2<<<gfl, blk, 0, stream>>>(SL(2),SL(3),SL(2),SL(3), VTv,
            SL(4),SL(5), it, 0.f, 1);
        flash2<<<gfl, blk, 0, stream>>>(SL(0),SL(1),SL(0),SL(1), VTv,
            SL(4),SL(5), it, 0.f, 1);
        gemm_proj_mfma<<<gp, blk, 0, stream>>>(SL(4),SL(5), WPh,WPl, proj_b,
            1.f/3.f, out);
    }
    #undef SL
}

// Round 14
// 729.564 us; speedup vs baseline: 1.3508x; 1.0046x over previous
//
#include <hip/hip_runtime.h>
#include <math.h>

#define NTOK 577
#define NB 8
#define NC 1024
#define NH 16
#define HD 64
#define M_ROWS (NB*NTOK)               // 4616
#define SZ ((size_t)NB*NH*NTOK*HD)     // 4726784 elements
#define WSZ ((size_t)3*NC*NC)          // 3145728
#define PSZ ((size_t)NC*NC)            // 1048576
#define VTW 608                        // padded key width for VT (19*32)
#define VTSZ ((size_t)NB*NH*HD*VTW)    // 4980736
#define HSTR ((size_t)NTOK*HD)         // 36928 head stride in A-layout
#define LP 36                          // padded LDS row (32 data + 4 pad)

typedef __attribute__((ext_vector_type(8)))  short bf16x8_t;
typedef __attribute__((ext_vector_type(8)))  unsigned short u16x8_t;
typedef __attribute__((ext_vector_type(16))) float f32x16_t;

union U4 { unsigned short s[8]; unsigned int u[4]; bf16x8_t v; };

__device__ inline unsigned short f2bf(float x){
    unsigned int u = __float_as_uint(x);
    u = (u + 0x7FFFu + ((u>>16)&1u)) >> 16;
    return (unsigned short)u;
}
__device__ inline float bf2f(unsigned short h){
    return __uint_as_float(((unsigned int)h)<<16);
}
__device__ inline unsigned int cvt_pk(float a, float b){
    unsigned int r;
    asm volatile("v_cvt_pk_bf16_f32 %0, %1, %2" : "=v"(r) : "v"(a), "v"(b));
    return r;
}

// ---------------------------------------------------------------------------
// split fp32 rows -> bf16 hi/lo [nrows][1024]. mode 0: row-major src.
// mode 1: X [N,B,C] gather (row m=b*577+n -> src row n*8+b).
// ---------------------------------------------------------------------------
__global__ __launch_bounds__(256) void split_rows(const float* __restrict__ src,
        unsigned short* __restrict__ dh, unsigned short* __restrict__ dl, int mode)
{
    int row = blockIdx.x, t = threadIdx.x;
    const float* s;
    if (mode == 0) s = src + (size_t)row*NC + 4*t;
    else {
        int b = row / NTOK, n = row % NTOK;
        s = src + ((size_t)n*NB + b)*NC + 4*t;
    }
    float4 v = *(const float4*)s;
    ushort4 hv, lv;
    hv.x = f2bf(v.x); lv.x = f2bf(v.x - bf2f(hv.x));
    hv.y = f2bf(v.y); lv.y = f2bf(v.y - bf2f(hv.y));
    hv.z = f2bf(v.z); lv.z = f2bf(v.z - bf2f(hv.z));
    hv.w = f2bf(v.w); lv.w = f2bf(v.w - bf2f(hv.w));
    *(ushort4*)(dh + (size_t)row*NC + 4*t) = hv;
    *(ushort4*)(dl + (size_t)row*NC + 4*t) = lv;
}

// ---------------------------------------------------------------------------
// Coalesced transpose: src hi-bf16 [BH][577][64] -> dst [BH][64][608], pads=0.
// ---------------------------------------------------------------------------
__global__ __launch_bounds__(256) void transp64(const unsigned short* __restrict__ src,
                                                unsigned short* __restrict__ dst)
{
    __shared__ unsigned short t[64][72];
    int bh = blockIdx.y;
    int n0 = blockIdx.x * 64;
    int tid = threadIdx.x;
    int r  = tid >> 2;
    int c0 = (tid & 3) * 16;
    int n = n0 + r;
    if (n < NTOK){
        const unsigned short* s = src + ((size_t)bh*NTOK + n)*HD + c0;
        *(u16x8_t*)&t[r][c0]   = *(const u16x8_t*)s;
        *(u16x8_t*)&t[r][c0+8] = *(const u16x8_t*)(s + 8);
    } else {
        u16x8_t z = (u16x8_t)0;
        *(u16x8_t*)&t[r][c0]   = z;
        *(u16x8_t*)&t[r][c0+8] = z;
    }
    __syncthreads();
    if (n0 + c0 < VTW){
        int d = r;
        U4 o0, o1;
        #pragma unroll
        for (int j = 0; j < 8; j++){ o0.s[j] = t[c0+j][d]; o1.s[j] = t[c0+8+j][d]; }
        unsigned short* dp = dst + ((size_t)bh*HD + d)*VTW + n0 + c0;
        *(u16x8_t*)dp       = (u16x8_t)o0.v;
        *(u16x8_t*)(dp + 8) = (u16x8_t)o1.v;
    }
}

#define MFMA12(a0h,a1h,b0h,b1h,a0l,a1l,b0l,b1l) \
    acc[0][0] = __builtin_amdgcn_mfma_f32_32x32x16_bf16(a0h, b0h, acc[0][0], 0,0,0); \
    acc[0][1] = __builtin_amdgcn_mfma_f32_32x32x16_bf16(a0h, b1h, acc[0][1], 0,0,0); \
    acc[1][0] = __builtin_amdgcn_mfma_f32_32x32x16_bf16(a1h, b0h, acc[1][0], 0,0,0); \
    acc[1][1] = __builtin_amdgcn_mfma_f32_32x32x16_bf16(a1h, b1h, acc[1][1], 0,0,0); \
    acc[0][0] = __builtin_amdgcn_mfma_f32_32x32x16_bf16(a0h, b0l, acc[0][0], 0,0,0); \
    acc[0][1] = __builtin_amdgcn_mfma_f32_32x32x16_bf16(a0h, b1l, acc[0][1], 0,0,0); \
    acc[1][0] = __builtin_amdgcn_mfma_f32_32x32x16_bf16(a1h, b0l, acc[1][0], 0,0,0); \
    acc[1][1] = __builtin_amdgcn_mfma_f32_32x32x16_bf16(a1h, b1l, acc[1][1], 0,0,0); \
    acc[0][0] = __builtin_amdgcn_mfma_f32_32x32x16_bf16(a0l, b0h, acc[0][0], 0,0,0); \
    acc[0][1] = __builtin_amdgcn_mfma_f32_32x32x16_bf16(a0l, b1h, acc[0][1], 0,0,0); \
    acc[1][0] = __builtin_amdgcn_mfma_f32_32x32x16_bf16(a1l, b0h, acc[1][0], 0,0,0); \
    acc[1][1] = __builtin_amdgcn_mfma_f32_32x32x16_bf16(a1l, b1h, acc[1][1], 0,0,0);

// ---------------------------------------------------------------------------
// qkv GEMM, LDS-staged (128x128 tile, BK=32, padded LDS rows, 4 waves 2x2).
// ---------------------------------------------------------------------------
__global__ __launch_bounds__(256) void gemm_qkv_mfma(
    const unsigned short* __restrict__ Ah, const unsigned short* __restrict__ Al,
    const unsigned short* __restrict__ Bh, const unsigned short* __restrict__ Bl,
    const float* __restrict__ bias,
    unsigned short* __restrict__ qh, unsigned short* __restrict__ ql,
    unsigned short* __restrict__ kh, unsigned short* __restrict__ kl,
    unsigned short* __restrict__ vh, unsigned short* __restrict__ vl)
{
    __shared__ unsigned short ahs[128][LP], als[128][LP];
    __shared__ unsigned short bhs[128][LP], bls[128][LP];
    int t = threadIdx.x;
    int l = t & 63, w = t >> 6;
    int lq = l & 31, hi = l >> 5;
    int wr = w >> 1, wc = w & 1;
    int col0 = blockIdx.x*128, row0 = blockIdx.y*128;

    int srow[2], scol[2], sa[2];
    #pragma unroll
    for (int i = 0; i < 2; i++){
        int idx = i*256 + t;
        srow[i] = idx >> 2;
        scol[i] = (idx & 3) * 8;
        int ar = row0 + srow[i]; if (ar >= M_ROWS) ar = M_ROWS-1;
        sa[i] = ar;
    }

    f32x16_t acc[2][2];
    #pragma unroll
    for (int i = 0; i < 16; i++){
        acc[0][0][i]=0.f; acc[0][1][i]=0.f; acc[1][0][i]=0.f; acc[1][1][i]=0.f;
    }

    for (int k0 = 0; k0 < NC; k0 += 32){
        if (k0) __syncthreads();
        #pragma unroll
        for (int i = 0; i < 2; i++){
            size_t ao = (size_t)sa[i]*NC + k0 + scol[i];
            size_t bo = (size_t)(col0 + srow[i])*NC + k0 + scol[i];
            u16x8_t va  = *(const u16x8_t*)(Ah + ao);
            u16x8_t va2 = *(const u16x8_t*)(Al + ao);
            u16x8_t vb  = *(const u16x8_t*)(Bh + bo);
            u16x8_t vb2 = *(const u16x8_t*)(Bl + bo);
            *(u16x8_t*)&ahs[srow[i]][scol[i]] = va;
            *(u16x8_t*)&als[srow[i]][scol[i]] = va2;
            *(u16x8_t*)&bhs[srow[i]][scol[i]] = vb;
            *(u16x8_t*)&bls[srow[i]][scol[i]] = vb2;
        }
        __syncthreads();
        #pragma unroll
        for (int kk = 0; kk < 2; kk++){
            int co = kk*16 + 8*hi;
            bf16x8_t a0h = *(const bf16x8_t*)&ahs[wr*64+lq][co];
            bf16x8_t a1h = *(const bf16x8_t*)&ahs[wr*64+32+lq][co];
            bf16x8_t b0h = *(const bf16x8_t*)&bhs[wc*64+lq][co];
            bf16x8_t b1h = *(const bf16x8_t*)&bhs[wc*64+32+lq][co];
            bf16x8_t a0l = *(const bf16x8_t*)&als[wr*64+lq][co];
            bf16x8_t a1l = *(const bf16x8_t*)&als[wr*64+32+lq][co];
            bf16x8_t b0l = *(const bf16x8_t*)&bls[wc*64+lq][co];
            bf16x8_t b1l = *(const bf16x8_t*)&bls[wc*64+32+lq][co];
            MFMA12(a0h,a1h,b0h,b1h,a0l,a1l,b0l,b1l)
        }
    }

    int colW = col0 + wc*64, rowW = row0 + wr*64;
    #pragma unroll
    for (int fn = 0; fn < 2; fn++){
        int colb = colW + fn*32 + lq;
        float bb = bias[colb];
        int tt = colb >> 10, h = (colb >> 6) & 15, d = colb & 63;
        unsigned short* dsth = (tt == 0) ? qh : (tt == 1 ? kh : vh);
        unsigned short* dstl = (tt == 0) ? ql : (tt == 1 ? kl : vl);
        #pragma unroll
        for (int fm = 0; fm < 2; fm++){
            #pragma unroll
            for (int r = 0; r < 16; r++){
                int orow = rowW + fm*32 + (r&3) + 8*(r>>2) + 4*hi;
                if (orow < M_ROWS){
                    float val = acc[fm][fn][r] + bb;
                    int b = orow / NTOK, n = orow % NTOK;
                    unsigned short hv = f2bf(val);
                    unsigned short lv = f2bf(val - bf2f(hv));
                    size_t idx = ((size_t)(b*NH + h)*NTOK + n)*HD + d;
                    dsth[idx] = hv; dstl[idx] = lv;
                }
            }
        }
    }
}

// ---------------------------------------------------------------------------
// proj GEMM, LDS-staged (64x128 tile, BK=32). A split bf16 in HEAD layout.
// ---------------------------------------------------------------------------
__global__ __launch_bounds__(256) void gemm_proj_mfma(
    const unsigned short* __restrict__ Ah, const unsigned short* __restrict__ Al,
    const unsigned short* __restrict__ Bh, const unsigned short* __restrict__ Bl,
    const float* __restrict__ bias, float alpha, float* __restrict__ out)
{
    __shared__ unsigned short ahs[64][LP], als[64][LP];
    __shared__ unsigned short bhs[128][LP], bls[128][LP];
    int t = threadIdx.x;
    int l = t & 63, w = t >> 6;
    int lq = l & 31, hi = l >> 5;
    int wr = w >> 1, wc = w & 1;
    int col0 = blockIdx.x*128, row0 = blockIdx.y*64;

    int sarow = t >> 2, sacol = (t & 3) * 8;
    int ar = row0 + sarow; if (ar >= M_ROWS) ar = M_ROWS-1;
    size_t abase = (size_t)(ar / NTOK)*NH*HSTR + (size_t)(ar % NTOK)*HD;
    int sbrow[2], sbcol[2];
    #pragma unroll
    for (int i = 0; i < 2; i++){
        int idx = i*256 + t;
        sbrow[i] = idx >> 2;
        sbcol[i] = (idx & 3) * 8;
    }

    f32x16_t acc[2];
    #pragma unroll
    for (int i = 0; i < 16; i++){ acc[0][i]=0.f; acc[1][i]=0.f; }

    for (int k0 = 0; k0 < NC; k0 += 32){
        if (k0) __syncthreads();
        {
            int kk = k0 + sacol;
            size_t ao = abase + (size_t)(kk >> 6)*HSTR + (kk & 63);
            u16x8_t va  = *(const u16x8_t*)(Ah + ao);
            u16x8_t va2 = *(const u16x8_t*)(Al + ao);
            *(u16x8_t*)&ahs[sarow][sacol] = va;
            *(u16x8_t*)&als[sarow][sacol] = va2;
            #pragma unroll
            for (int i = 0; i < 2; i++){
                size_t bo = (size_t)(col0 + sbrow[i])*NC + k0 + sbcol[i];
                u16x8_t vb  = *(const u16x8_t*)(Bh + bo);
                u16x8_t vb2 = *(const u16x8_t*)(Bl + bo);
                *(u16x8_t*)&bhs[sbrow[i]][sbcol[i]] = vb;
                *(u16x8_t*)&bls[sbrow[i]][sbcol[i]] = vb2;
            }
        }
        __syncthreads();
        #pragma unroll
        for (int kk = 0; kk < 2; kk++){
            int co = kk*16 + 8*hi;
            bf16x8_t a0h = *(const bf16x8_t*)&ahs[wr*32+lq][co];
            bf16x8_t a0l = *(const bf16x8_t*)&als[wr*32+lq][co];
            bf16x8_t b0h = *(const bf16x8_t*)&bhs[wc*64+lq][co];
            bf16x8_t b1h = *(const bf16x8_t*)&bhs[wc*64+32+lq][co];
            bf16x8_t b0l = *(const bf16x8_t*)&bls[wc*64+lq][co];
            bf16x8_t b1l = *(const bf16x8_t*)&bls[wc*64+32+lq][co];
            acc[0] = __builtin_amdgcn_mfma_f32_32x32x16_bf16(a0h, b0h, acc[0], 0,0,0);
            acc[1] = __builtin_amdgcn_mfma_f32_32x32x16_bf16(a0h, b1h, acc[1], 0,0,0);
            acc[0] = __builtin_amdgcn_mfma_f32_32x32x16_bf16(a0h, b0l, acc[0], 0,0,0);
            acc[1] = __builtin_amdgcn_mfma_f32_32x32x16_bf16(a0h, b1l, acc[1], 0,0,0);
            acc[0] = __builtin_amdgcn_mfma_f32_32x32x16_bf16(a0l, b0h, acc[0], 0,0,0);
            acc[1] = __builtin_amdgcn_mfma_f32_32x32x16_bf16(a0l, b1h, acc[1], 0,0,0);
        }
    }

    #pragma unroll
    for (int fn = 0; fn < 2; fn++){
        int colb = col0 + wc*64 + fn*32 + lq;
        float bb = bias[colb];
        #pragma unroll
        for (int r = 0; r < 16; r++){
            int orow = row0 + wr*32 + (r&3) + 8*(r>>2) + 4*hi;
            if (orow < M_ROWS){
                int b = orow / NTOK, n = orow % NTOK;
                out[((size_t)n*NB + b)*NC + colb] = alpha*acc[fn][r] + bb;
            }
        }
    }
}

// ---------------------------------------------------------------------------
// Flash inner body, no LDS (R11-proven). VAR=0: online softmax + 1/l (x_ori).
// VAR=1: static max (=scale, exact for l2n'd Q=K) + fused output-l2n.
// VAR=2: static max + 1/l.
// ---------------------------------------------------------------------------
template<int VAR>
__device__ __forceinline__ void flash_body(
    const unsigned short* Qh, const unsigned short* Ql,
    const unsigned short* Kh, const unsigned short* Kl,
    const unsigned short* VT,
    unsigned short* Ohi, unsigned short* Olo,
    float scale, int acc, int bh, int qt, int lane)
{
    int hi = lane >> 5, lq = lane & 31;
    const size_t base = (size_t)bh * NTOK * HD;
    const size_t vtb  = (size_t)bh * HD * VTW;

    int qrow = qt*32 + lq;
    int qr = qrow < NTOK ? qrow : NTOK-1;
    const size_t qoff = base + (size_t)qr*HD + 8*hi;
    bf16x8_t qfh[4], qfl[4];
    #pragma unroll
    for (int c = 0; c < 4; c++){
        qfh[c] = *(const bf16x8_t*)(Qh + qoff + 16*c);
        qfl[c] = *(const bf16x8_t*)(Ql + qoff + 16*c);
    }

    f32x16_t od0, od1;
    #pragma unroll
    for (int r = 0; r < 16; r++){ od0[r]=0.f; od1[r]=0.f; }
    float m_ = -1e30f, l_ = 0.f;

    for (int kt = 0; kt < 19; kt++){
        int krow = kt*32 + lq;
        int kr = krow < NTOK ? krow : NTOK-1;
        const size_t koff = base + (size_t)kr*HD + 8*hi;
        bf16x8_t kfh[4], kfl[4];
        #pragma unroll
        for (int c = 0; c < 4; c++){
            kfh[c] = *(const bf16x8_t*)(Kh + koff + 16*c);
            kfl[c] = *(const bf16x8_t*)(Kl + koff + 16*c);
        }
        f32x16_t sf;
        #pragma unroll
        for (int r = 0; r < 16; r++) sf[r] = 0.f;
        __builtin_amdgcn_s_setprio(1);
        #pragma unroll
        for (int c = 0; c < 4; c++){
            sf = __builtin_amdgcn_mfma_f32_32x32x16_bf16(kfh[c], qfh[c], sf, 0,0,0);
            sf = __builtin_amdgcn_mfma_f32_32x32x16_bf16(kfh[c], qfl[c], sf, 0,0,0);
            sf = __builtin_amdgcn_mfma_f32_32x32x16_bf16(kfl[c], qfh[c], sf, 0,0,0);
        }
        __builtin_amdgcn_s_setprio(0);

        float p[16];
        if (VAR == 0){
            float tm = -1e30f;
            if (kt == 18){
                #pragma unroll
                for (int r = 0; r < 16; r++){
                    int key = 576 + (r&3) + 8*(r>>2) + 4*hi;
                    p[r] = (key < NTOK) ? sf[r]*scale : -1e30f;
                    tm = fmaxf(tm, p[r]);
                }
            } else {
                #pragma unroll
                for (int r = 0; r < 16; r++){ p[r] = sf[r]*scale; tm = fmaxf(tm, p[r]); }
            }
            tm = fmaxf(tm, __shfl_xor(tm, 32));
            float mn = fmaxf(m_, tm);
            float corr = __expf(m_ - mn);
            float ps = 0.f;
            #pragma unroll
            for (int r = 0; r < 16; r++){ p[r] = __expf(p[r] - mn); ps += p[r]; }
            ps += __shfl_xor(ps, 32);
            l_ = l_*corr + ps;
            m_ = mn;
            #pragma unroll
            for (int r = 0; r < 16; r++){
                int crow = (r&3) + 8*(r>>2) + 4*hi;
                float cR = __shfl(corr, crow);
                od0[r] *= cR; od1[r] *= cR;
            }
        } else {
            // static max == scale (row max is the diagonal, exactly scale)
            if (kt == 18){
                #pragma unroll
                for (int r = 0; r < 16; r++){
                    int key = 576 + (r&3) + 8*(r>>2) + 4*hi;
                    p[r] = (key < NTOK) ? __expf(sf[r]*scale - scale) : 0.f;
                }
            } else {
                #pragma unroll
                for (int r = 0; r < 16; r++) p[r] = __expf(sf[r]*scale - scale);
            }
            if (VAR == 2){
                #pragma unroll
                for (int r = 0; r < 16; r++) l_ += p[r];
            }
        }

        U4 pa[2];
        #pragma unroll
        for (int ks = 0; ks < 2; ks++){
            unsigned int X0 = cvt_pk(p[8*ks+0], p[8*ks+1]);
            unsigned int X1 = cvt_pk(p[8*ks+2], p[8*ks+3]);
            unsigned int X2 = cvt_pk(p[8*ks+4], p[8*ks+5]);
            unsigned int X3 = cvt_pk(p[8*ks+6], p[8*ks+7]);
            unsigned int Y0 = (unsigned int)__shfl_xor((int)X2, 32);
            unsigned int Y1 = (unsigned int)__shfl_xor((int)X3, 32);
            unsigned int Y2 = (unsigned int)__shfl_xor((int)X0, 32);
            unsigned int Y3 = (unsigned int)__shfl_xor((int)X1, 32);
            pa[ks].u[0] = hi ? Y0 : X0;
            pa[ks].u[1] = hi ? Y1 : X1;
            pa[ks].u[2] = hi ? X2 : Y2;
            pa[ks].u[3] = hi ? X3 : Y3;
        }
        const size_t v0 = vtb + (size_t)lq*VTW      + kt*32 + 8*hi;
        const size_t v1 = vtb + (size_t)(32+lq)*VTW + kt*32 + 8*hi;
        bf16x8_t vf00 = *(const bf16x8_t*)(VT + v0);
        bf16x8_t vf01 = *(const bf16x8_t*)(VT + v0 + 16);
        bf16x8_t vf10 = *(const bf16x8_t*)(VT + v1);
        bf16x8_t vf11 = *(const bf16x8_t*)(VT + v1 + 16);
        __builtin_amdgcn_s_setprio(1);
        od0 = __builtin_amdgcn_mfma_f32_32x32x16_bf16(pa[0].v, vf00, od0, 0,0,0);
        od0 = __builtin_amdgcn_mfma_f32_32x32x16_bf16(pa[1].v, vf01, od0, 0,0,0);
        od1 = __builtin_amdgcn_mfma_f32_32x32x16_bf16(pa[0].v, vf10, od1, 0,0,0);
        od1 = __builtin_amdgcn_mfma_f32_32x32x16_bf16(pa[1].v, vf11, od1, 0,0,0);
        __builtin_amdgcn_s_setprio(0);
    }

    if (VAR == 1){
        #pragma unroll
        for (int r = 0; r < 16; r++){
            float s = od0[r]*od0[r] + od1[r]*od1[r];
            #pragma unroll
            for (int o = 1; o < 32; o <<= 1) s += __shfl_xor(s, o);
            int crow = (r&3) + 8*(r>>2) + 4*hi;
            int qg = qt*32 + crow;
            if (qg < NTOK){
                float inv = 1.f / fmaxf(sqrtf(s), 1e-12f);
                size_t o0 = base + (size_t)qg*HD + lq;
                float a0 = od0[r]*inv, a1 = od1[r]*inv;
                unsigned short h0 = f2bf(a0), h1 = f2bf(a1);
                Ohi[o0] = h0;    Olo[o0]    = f2bf(a0 - bf2f(h0));
                Ohi[o0+32] = h1; Olo[o0+32] = f2bf(a1 - bf2f(h1));
            }
        }
        return;
    }

    if (VAR == 2) l_ = l_ + __shfl_xor(l_, 32);
    float linv = 1.f / l_;
    #pragma unroll
    for (int r = 0; r < 16; r++){
        int crow = (r&3) + 8*(r>>2) + 4*hi;
        int qg = qt*32 + crow;
        float li = __shfl(linv, crow);
        if (qg < NTOK){
            size_t o0 = base + (size_t)qg*HD + lq;
            float a0 = od0[r]*li, a1 = od1[r]*li;
            if (acc){
                a0 += bf2f(Ohi[o0])    + bf2f(Olo[o0]);
                a1 += bf2f(Ohi[o0+32]) + bf2f(Olo[o0+32]);
            }
            unsigned short h0 = f2bf(a0), h1 = f2bf(a1);
            Ohi[o0] = h0;    Olo[o0]    = f2bf(a0 - bf2f(h0));
            Ohi[o0+32] = h1; Olo[o0+32] = f2bf(a1 - bf2f(h1));
        }
    }
}

__global__ __launch_bounds__(256) void flash2(
    const unsigned short* __restrict__ Qh, const unsigned short* __restrict__ Ql,
    const unsigned short* __restrict__ Kh, const unsigned short* __restrict__ Kl,
    const unsigned short* __restrict__ VT,
    unsigned short* __restrict__ Ohi, unsigned short* __restrict__ Olo,
    const float* __restrict__ itemp, float cscale, int acc)
{
    int w = threadIdx.x >> 6, lane = threadIdx.x & 63;
    int bid = blockIdx.x;
    int bh = (bid & 7) * 16 + (bid >> 3) / 5;
    int qt = ((bid >> 3) % 5) * 4 + w;
    if (qt >= 19) return;
    float scale = itemp ? itemp[bh >> 4] : cscale;
    flash_body<0>(Qh, Ql, Kh, Kl, VT, Ohi, Olo, scale, acc, bh, qt, lane);
}

// Batched: 3 independent self-attentions (Q=K), slice = blockIdx.y.
template<int VAR>
__global__ __launch_bounds__(256) void flash2b(
    const unsigned short* __restrict__ q0h, const unsigned short* __restrict__ q0l,
    const unsigned short* __restrict__ q1h, const unsigned short* __restrict__ q1l,
    const unsigned short* __restrict__ q2h, const unsigned short* __restrict__ q2l,
    const unsigned short* __restrict__ vt0, const unsigned short* __restrict__ vt1,
    const unsigned short* __restrict__ vt2,
    unsigned short* __restrict__ o0h, unsigned short* __restrict__ o0l,
    unsigned short* __restrict__ o1h, unsigned short* __restrict__ o1l,
    unsigned short* __restrict__ o2h, unsigned short* __restrict__ o2l,
    const float* __restrict__ itemp)
{
    int w = threadIdx.x >> 6, lane = threadIdx.x & 63;
    int bid = blockIdx.x;
    int bh = (bid & 7) * 16 + (bid >> 3) / 5;
    int qt = ((bid >> 3) % 5) * 4 + w;
    if (qt >= 19) return;
    int i = blockIdx.y;
    const unsigned short *Qh, *Ql, *VT;
    unsigned short *Oh, *Ol;
    if (i == 0){ Qh=q0h; Ql=q0l; VT=vt0; Oh=o0h; Ol=o0l; }
    else if (i == 1){ Qh=q1h; Ql=q1l; VT=vt1; Oh=o1h; Ol=o1l; }
    else { Qh=q2h; Ql=q2l; VT=vt2; Oh=o2h; Ol=o2l; }
    flash_body<VAR>(Qh, Ql, Qh, Ql, VT, Oh, Ol, itemp[bh >> 4], 0, bh, qt, lane);
}

// 4-wide merged: slices 0-2 = ys_i (VAR=1, fused l2n -> z_i); slice 3 = x_ori
// attention (VAR=0, Q=q, K=k, scale=0.125) -> o_ori.
__global__ __launch_bounds__(256) void flash4(
    const unsigned short* __restrict__ x1h, const unsigned short* __restrict__ x1l,
    const unsigned short* __restrict__ x2h, const unsigned short* __restrict__ x2l,
    const unsigned short* __restrict__ x3h, const unsigned short* __restrict__ x3l,
    const unsigned short* __restrict__ qh_, const unsigned short* __restrict__ ql_,
    const unsigned short* __restrict__ kh_, const unsigned short* __restrict__ kl_,
    const unsigned short* __restrict__ vt1, const unsigned short* __restrict__ vt2,
    const unsigned short* __restrict__ vt3, const unsigned short* __restrict__ vtv,
    unsigned short* __restrict__ z1h, unsigned short* __restrict__ z1l,
    unsigned short* __restrict__ z2h, unsigned short* __restrict__ z2l,
    unsigned short* __restrict__ z3h, unsigned short* __restrict__ z3l,
    unsigned short* __restrict__ ooh, unsigned short* __restrict__ ool,
    const float* __restrict__ itemp)
{
    int w = threadIdx.x >> 6, lane = threadIdx.x & 63;
    int bid = blockIdx.x;
    int bh = (bid & 7) * 16 + (bid >> 3) / 5;
    int qt = ((bid >> 3) % 5) * 4 + w;
    if (qt >= 19) return;
    int i = blockIdx.y;
    if (i == 3){
        flash_body<0>(qh_, ql_, kh_, kl_, vtv, ooh, ool, 0.125f, 0, bh, qt, lane);
    } else {
        const unsigned short *Qh, *Ql, *VT;
        unsigned short *Oh, *Ol;
        if (i == 0){ Qh=x1h; Ql=x1l; VT=vt1; Oh=z1h; Ol=z1l; }
        else if (i == 1){ Qh=x2h; Ql=x2l; VT=vt2; Oh=z2h; Ol=z2l; }
        else { Qh=x3h; Ql=x3l; VT=vt3; Oh=z3h; Ol=z3l; }
        flash_body<1>(Qh, Ql, Qh, Ql, VT, Oh, Ol, itemp[bh >> 4], 0, bh, qt, lane);
    }
}

// ---------------------------------------------------------------------------
// sum of 3 split-bf16 buffers -> split-bf16 (fp32 adds, fixed order)
// ---------------------------------------------------------------------------
__global__ __launch_bounds__(256) void sum3(
    const unsigned short* __restrict__ ah, const unsigned short* __restrict__ al,
    const unsigned short* __restrict__ bh, const unsigned short* __restrict__ bl,
    const unsigned short* __restrict__ ch, const unsigned short* __restrict__ cl,
    unsigned short* __restrict__ oh, unsigned short* __restrict__ ol)
{
    size_t idx = ((size_t)blockIdx.x*256 + threadIdx.x)*4;
    ushort4 vah = *(const ushort4*)(ah+idx), val = *(const ushort4*)(al+idx);
    ushort4 vbh = *(const ushort4*)(bh+idx), vbl = *(const ushort4*)(bl+idx);
    ushort4 vch = *(const ushort4*)(ch+idx), vcl = *(const ushort4*)(cl+idx);
    ushort4 rh, rl;
    #define S3(f) { \
        float s = bf2f(vah.f)+bf2f(val.f)+bf2f(vbh.f)+bf2f(vbl.f)+bf2f(vch.f)+bf2f(vcl.f); \
        rh.f = f2bf(s); rl.f = f2bf(s - bf2f(rh.f)); }
    S3(x) S3(y) S3(z) S3(w)
    #undef S3
    *(ushort4*)(oh+idx) = rh;
    *(ushort4*)(ol+idx) = rl;
}

// ---------------------------------------------------------------------------
__global__ __launch_bounds__(256) void row_norm(const float* __restrict__ X,
                                                float* __restrict__ rn)
{
    int id = blockIdx.x;
    int b = id / NTOK, n = id % NTOK;
    const float* src = X + ((size_t)n*NB + b)*NC;
    int tid = threadIdx.x;
    float s = 0.f;
    for (int i = tid; i < NC; i += 256) { float t = src[i]; s += t*t; }
    #pragma unroll
    for (int o = 1; o < 64; o <<= 1) s += __shfl_xor(s, o);
    __shared__ float red[4];
    if ((tid & 63) == 0) red[tid >> 6] = s;
    __syncthreads();
    if (tid == 0) rn[id] = sqrtf(red[0] + red[1] + red[2] + red[3]);
}

__global__ __launch_bounds__(256) void calc_invtemp(const float* __restrict__ rn,
                                                    float* __restrict__ it)
{
    int b = blockIdx.x;
    int tid = threadIdx.x;
    float s = 0.f;
    for (int i = tid; i < NTOK; i += 256) s += rn[b*NTOK + i];
    #pragma unroll
    for (int o = 1; o < 64; o <<= 1) s += __shfl_xor(s, o);
    __shared__ float red[4];
    if ((tid & 63) == 0) red[tid >> 6] = s;
    __syncthreads();
    if (tid == 0) it[b] = (red[0]+red[1]+red[2]+red[3]) / (float)NTOK * 0.125f;
}

// ---------------------------------------------------------------------------
__global__ __launch_bounds__(256) void l2n_s2s(const unsigned short* __restrict__ ih,
        const unsigned short* __restrict__ il,
        unsigned short* __restrict__ oh, unsigned short* __restrict__ ol)
{
    size_t row = (size_t)blockIdx.x*4 + (threadIdx.x >> 6);
    int lane = threadIdx.x & 63;
    size_t ii = row*HD + lane;
    float x = bf2f(ih[ii]) + bf2f(il[ii]);
    float s = x*x;
    #pragma unroll
    for (int o = 1; o < 64; o <<= 1) s += __shfl_xor(s, o);
    float xn = x / fmaxf(sqrtf(s), 1e-12f);
    unsigned short hv = f2bf(xn);
    oh[ii] = hv;
    ol[ii] = f2bf(xn - bf2f(hv));
}

// ---------------------------------------------------------------------------
extern "C" void kernel_launch(void* const* d_in, const int* in_sizes, int n_in,
                              void* d_out, int out_size, void* d_ws, size_t ws_size,
                              hipStream_t stream)
{
    const float* x      = (const float*)d_in[0];
    const float* qkv_w  = (const float*)d_in[1];
    const float* qkv_b  = (const float*)d_in[2];
    const float* proj_w = (const float*)d_in[3];
    const float* proj_b = (const float*)d_in[4];
    float* out = (float*)d_out;            // [0,SZ)=x_gem, [SZ,2SZ)=x_ori

    unsigned short* w16 = (unsigned short*)d_ws;
    #define SL(i) (w16 + (size_t)(i)*SZ)          // 8 bf16 slots
    unsigned short* WQh = w16 + 8*SZ;             // WQ, dead after qkv
    unsigned short* WQl = WQh + WSZ;
    unsigned short* VT1 = WQh;                    // aliases WQ
    size_t p = 8*SZ + 2*WSZ;
    unsigned short* VTv = w16 + p;  p += VTSZ;
    unsigned short* VT2 = w16 + p;  p += VTSZ;
    unsigned short* VT3 = w16 + p;  p += VTSZ;
    unsigned short* WPh = w16 + p;  p += PSZ;
    unsigned short* WPl = w16 + p;  p += PSZ;
    unsigned short* E0  = w16 + p;  p += SZ;
    unsigned short* E1  = w16 + p;  p += SZ;
    float* rn = (float*)(w16 + p);  p += 2*(M_ROWS + 8);
    float* it = rn + M_ROWS;
    size_t need3 = p * sizeof(unsigned short);    // 3-wide batched layout
    unsigned short* F0 = w16 + p;  p += SZ;       // merged4-only
    unsigned short* F1 = w16 + p;  p += SZ;
    unsigned short* G0 = w16 + p;  p += SZ;
    unsigned short* G1 = w16 + p;  p += SZ;
    size_t need4 = p * sizeof(unsigned short);    // 4-wide merged layout
    int merged4  = (ws_size >= need4);
    int batched3 = (ws_size >= need3);

    unsigned short* S0 = (unsigned short*)d_out;  // x_gem bytes (scratch pair)
    unsigned short* S1 = S0 + SZ;
    unsigned short* T0 = S0 + 2*SZ;               // x_ori bytes (scratch pair)
    unsigned short* T1 = S0 + 3*SZ;

    dim3 blk(256);
    dim3 gq(24,37), gp(8,73), gfl(640), gflb(640,3), gfl4(640,4), gt(10,128);

    // common prologue: inv_temp, splits, qkv gemm, VTv
    row_norm<<<dim3(M_ROWS), blk, 0, stream>>>(x, rn);
    calc_invtemp<<<dim3(NB), blk, 0, stream>>>(rn, it);
    split_rows<<<dim3(M_ROWS), blk, 0, stream>>>(x, SL(6), SL(7), 1);
    split_rows<<<dim3(3*NC),  blk, 0, stream>>>(qkv_w, WQh, WQl, 0);
    gemm_qkv_mfma<<<gq, blk, 0, stream>>>(SL(6), SL(7), WQh, WQl, qkv_b,
        SL(0), SL(1), SL(2), SL(3), SL(4), SL(5));
    transp64<<<gt, blk, 0, stream>>>(SL(4), VTv);

    if (merged4){
        // xs1 = l2n(v) in-place (4,5); xs2 = l2n(k) -> (6,7); xs3 = l2n(q) -> E
        l2n_s2s<<<dim3(18464), blk, 0, stream>>>(SL(4),SL(5), SL(4),SL(5));
        l2n_s2s<<<dim3(18464), blk, 0, stream>>>(SL(2),SL(3), SL(6),SL(7));
        l2n_s2s<<<dim3(18464), blk, 0, stream>>>(SL(0),SL(1), E0,E1);
        transp64<<<gt, blk, 0, stream>>>(SL(4), VT1);
        transp64<<<gt, blk, 0, stream>>>(SL(6), VT2);
        transp64<<<gt, blk, 0, stream>>>(E0,  VT3);
        split_rows<<<dim3(NC), blk, 0, stream>>>(proj_w, WPh, WPl, 0);
        // merged: z1->T, z2->F, z3->G, o_ori->S
        flash4<<<gfl4, blk, 0, stream>>>(
            SL(4),SL(5), SL(6),SL(7), E0,E1,
            SL(0),SL(1), SL(2),SL(3),
            VT1, VT2, VT3, VTv,
            T0,T1, F0,F1, G0,G1, S0,S1, it);
        // finals: read z (T,F,G) x VTv -> (4,5),(6,7),E   (q,k,xs dead)
        flash2b<2><<<gflb, blk, 0, stream>>>(
            T0,T1, F0,F1, G0,G1,
            VTv, VTv, VTv,
            SL(4),SL(5), SL(6),SL(7), E0,E1, it);
        sum3<<<dim3(4616), blk, 0, stream>>>(
            SL(4),SL(5), SL(6),SL(7), E0,E1, SL(4),SL(5));
        // proj_ori first (reads S=o_ori, writes T region; z1 dead)
        gemm_proj_mfma<<<gp, blk, 0, stream>>>(S0,S1, WPh,WPl, proj_b, 1.f,
            out + SZ);
        // proj_gem (reads (4,5), writes S region; o_ori dead)
        gemm_proj_mfma<<<gp, blk, 0, stream>>>(SL(4),SL(5), WPh,WPl, proj_b,
            1.f/3.f, out);
    } else if (batched3){
        // proven R10-13 path: x_ori first, then 3-wide ys + finals
        flash2<<<gfl, blk, 0, stream>>>(SL(0),SL(1),SL(2),SL(3), VTv,
            SL(6),SL(7), nullptr, 0.125f, 0);
        split_rows<<<dim3(NC), blk, 0, stream>>>(proj_w, WPh, WPl, 0);
        gemm_proj_mfma<<<gp, blk, 0, stream>>>(SL(6),SL(7), WPh,WPl, proj_b,
            1.f, out + SZ);
        l2n_s2s<<<dim3(18464), blk, 0, stream>>>(SL(4),SL(5), SL(4),SL(5));
        l2n_s2s<<<dim3(18464), blk, 0, stream>>>(SL(2),SL(3), SL(2),SL(3));
        l2n_s2s<<<dim3(18464), blk, 0, stream>>>(SL(0),SL(1), SL(0),SL(1));
        transp64<<<gt, blk, 0, stream>>>(SL(4), VT1);
        transp64<<<gt, blk, 0, stream>>>(SL(2), VT2);
        transp64<<<gt, blk, 0, stream>>>(SL(0), VT3);
        flash2b<1><<<gflb, blk, 0, stream>>>(
            SL(4),SL(5), SL(2),SL(3), SL(0),SL(1),
            VT1, VT2, VT3,
            SL(6),SL(7), S0,S1, E0,E1, it);
        flash2b<2><<<gflb, blk, 0, stream>>>(
            SL(6),SL(7), S0,S1, E0,E1,
            VTv, VTv, VTv,
            SL(4),SL(5), SL(2),SL(3), SL(0),SL(1), it);
        sum3<<<dim3(4616), blk, 0, stream>>>(
            SL(4),SL(5), SL(2),SL(3), SL(0),SL(1), SL(4),SL(5));
        gemm_proj_mfma<<<gp, blk, 0, stream>>>(SL(4),SL(5), WPh,WPl, proj_b,
            1.f/3.f, out);
    } else {
        // serial fallback (online softmax throughout)
        unsigned short* VTx = WQh;
        flash2<<<gfl, blk, 0, stream>>>(SL(0),SL(1),SL(2),SL(3), VTv,
            SL(6),SL(7), nullptr, 0.125f, 0);
        split_rows<<<dim3(NC), blk, 0, stream>>>(proj_w, WPh, WPl, 0);
        gemm_proj_mfma<<<gp, blk, 0, stream>>>(SL(6),SL(7), WPh,WPl, proj_b,
            1.f, out + SZ);
        l2n_s2s<<<dim3(18464), blk, 0, stream>>>(SL(4),SL(5), SL(6),SL(7));
        transp64<<<gt, blk, 0, stream>>>(SL(6), VTx);
        flash2<<<gfl, blk, 0, stream>>>(SL(6),SL(7),SL(6),SL(7), VTx,
            SL(4),SL(5), it, 0.f, 0);
        l2n_s2s<<<dim3(18464), blk, 0, stream>>>(SL(4),SL(5), SL(6),SL(7));
        l2n_s2s<<<dim3(18464), blk, 0, stream>>>(SL(2),SL(3), SL(2),SL(3));
        transp64<<<gt, blk, 0, stream>>>(SL(2), VTx);
        flash2<<<gfl, blk, 0, stream>>>(SL(2),SL(3),SL(2),SL(3), VTx,
            SL(4),SL(5), it, 0.f, 0);
        l2n_s2s<<<dim3(18464), blk, 0, stream>>>(SL(4),SL(5), SL(2),SL(3));
        l2n_s2s<<<dim3(18464), blk, 0, stream>>>(SL(0),SL(1), SL(0),SL(1));
        transp64<<<gt, blk, 0, stream>>>(SL(0), VTx);
        flash2<<<gfl, blk, 0, stream>>>(SL(0),SL(1),SL(0),SL(1), VTx,
            SL(4),SL(5), it, 0.f, 0);
        l2n_s2s<<<dim3(18464), blk, 0, stream>>>(SL(4),SL(5), SL(0),SL(1));
        flash2<<<gfl, blk, 0, stream>>>(SL(6),SL(7),SL(6),SL(7), VTv,
            SL(4),SL(5), it, 0.f, 0);
        flash2<<<gfl, blk, 0, stream>>>(SL(2),SL(3),SL(2),SL(3), VTv,
            SL(4),SL(5), it, 0.f, 1);
        flash2<<<gfl, blk, 0, stream>>>(SL(0),SL(1),SL(0),SL(1), VTv,
            SL(4),SL(5), it, 0.f, 1);
        gemm_proj_mfma<<<gp, blk, 0, stream>>>(SL(4),SL(5), WPh,WPl, proj_b,
            1.f/3.f, out);
    }
    #undef SL
}

// Round 15
// 615.900 us; speedup vs baseline: 1.6001x; 1.1845x over previous
//
#include <hip/hip_runtime.h>
#include <math.h>

#define NTOK 577
#define NB 8
#define NC 1024
#define NH 16
#define HD 64
#define M_ROWS (NB*NTOK)               // 4616
#define SZ ((size_t)NB*NH*NTOK*HD)     // 4726784 elements
#define WSZ ((size_t)3*NC*NC)          // 3145728
#define PSZ ((size_t)NC*NC)            // 1048576
#define VTW 608                        // padded key width for VT (19*32)
#define VTSZ ((size_t)NB*NH*HD*VTW)    // 4980736
#define HSTR ((size_t)NTOK*HD)         // 36928 head stride in A-layout
#define LP 36                          // padded LDS row (32 data + 4 pad)

typedef __attribute__((ext_vector_type(8)))  short bf16x8_t;
typedef __attribute__((ext_vector_type(8)))  unsigned short u16x8_t;
typedef __attribute__((ext_vector_type(16))) float f32x16_t;

union U4 { unsigned short s[8]; unsigned int u[4]; bf16x8_t v; };

__device__ inline unsigned short f2bf(float x){
    unsigned int u = __float_as_uint(x);
    u = (u + 0x7FFFu + ((u>>16)&1u)) >> 16;
    return (unsigned short)u;
}
__device__ inline float bf2f(unsigned short h){
    return __uint_as_float(((unsigned int)h)<<16);
}
__device__ inline unsigned int cvt_pk(float a, float b){
    unsigned int r;
    asm volatile("v_cvt_pk_bf16_f32 %0, %1, %2" : "=v"(r) : "v"(a), "v"(b));
    return r;
}

// ---------------------------------------------------------------------------
// split fp32 rows -> bf16 hi/lo [nrows][1024]. mode 0: row-major src.
// mode 1: X [N,B,C] gather (row m=b*577+n -> src row n*8+b).
// ---------------------------------------------------------------------------
__global__ __launch_bounds__(256) void split_rows(const float* __restrict__ src,
        unsigned short* __restrict__ dh, unsigned short* __restrict__ dl, int mode)
{
    int row = blockIdx.x, t = threadIdx.x;
    const float* s;
    if (mode == 0) s = src + (size_t)row*NC + 4*t;
    else {
        int b = row / NTOK, n = row % NTOK;
        s = src + ((size_t)n*NB + b)*NC + 4*t;
    }
    float4 v = *(const float4*)s;
    ushort4 hv, lv;
    hv.x = f2bf(v.x); lv.x = f2bf(v.x - bf2f(hv.x));
    hv.y = f2bf(v.y); lv.y = f2bf(v.y - bf2f(hv.y));
    hv.z = f2bf(v.z); lv.z = f2bf(v.z - bf2f(hv.z));
    hv.w = f2bf(v.w); lv.w = f2bf(v.w - bf2f(hv.w));
    *(ushort4*)(dh + (size_t)row*NC + 4*t) = hv;
    *(ushort4*)(dl + (size_t)row*NC + 4*t) = lv;
}

// ---------------------------------------------------------------------------
// Coalesced transpose: src hi-bf16 [BH][577][64] -> dst [BH][64][608], pads=0.
// ---------------------------------------------------------------------------
__global__ __launch_bounds__(256) void transp64(const unsigned short* __restrict__ src,
                                                unsigned short* __restrict__ dst)
{
    __shared__ unsigned short t[64][72];
    int bh = blockIdx.y;
    int n0 = blockIdx.x * 64;
    int tid = threadIdx.x;
    int r  = tid >> 2;
    int c0 = (tid & 3) * 16;
    int n = n0 + r;
    if (n < NTOK){
        const unsigned short* s = src + ((size_t)bh*NTOK + n)*HD + c0;
        *(u16x8_t*)&t[r][c0]   = *(const u16x8_t*)s;
        *(u16x8_t*)&t[r][c0+8] = *(const u16x8_t*)(s + 8);
    } else {
        u16x8_t z = (u16x8_t)0;
        *(u16x8_t*)&t[r][c0]   = z;
        *(u16x8_t*)&t[r][c0+8] = z;
    }
    __syncthreads();
    if (n0 + c0 < VTW){
        int d = r;
        U4 o0, o1;
        #pragma unroll
        for (int j = 0; j < 8; j++){ o0.s[j] = t[c0+j][d]; o1.s[j] = t[c0+8+j][d]; }
        unsigned short* dp = dst + ((size_t)bh*HD + d)*VTW + n0 + c0;
        *(u16x8_t*)dp       = (u16x8_t)o0.v;
        *(u16x8_t*)(dp + 8) = (u16x8_t)o1.v;
    }
}

#define MFMA12(a0h,a1h,b0h,b1h,a0l,a1l,b0l,b1l) \
    acc[0][0] = __builtin_amdgcn_mfma_f32_32x32x16_bf16(a0h, b0h, acc[0][0], 0,0,0); \
    acc[0][1] = __builtin_amdgcn_mfma_f32_32x32x16_bf16(a0h, b1h, acc[0][1], 0,0,0); \
    acc[1][0] = __builtin_amdgcn_mfma_f32_32x32x16_bf16(a1h, b0h, acc[1][0], 0,0,0); \
    acc[1][1] = __builtin_amdgcn_mfma_f32_32x32x16_bf16(a1h, b1h, acc[1][1], 0,0,0); \
    acc[0][0] = __builtin_amdgcn_mfma_f32_32x32x16_bf16(a0h, b0l, acc[0][0], 0,0,0); \
    acc[0][1] = __builtin_amdgcn_mfma_f32_32x32x16_bf16(a0h, b1l, acc[0][1], 0,0,0); \
    acc[1][0] = __builtin_amdgcn_mfma_f32_32x32x16_bf16(a1h, b0l, acc[1][0], 0,0,0); \
    acc[1][1] = __builtin_amdgcn_mfma_f32_32x32x16_bf16(a1h, b1l, acc[1][1], 0,0,0); \
    acc[0][0] = __builtin_amdgcn_mfma_f32_32x32x16_bf16(a0l, b0h, acc[0][0], 0,0,0); \
    acc[0][1] = __builtin_amdgcn_mfma_f32_32x32x16_bf16(a0l, b1h, acc[0][1], 0,0,0); \
    acc[1][0] = __builtin_amdgcn_mfma_f32_32x32x16_bf16(a1l, b0h, acc[1][0], 0,0,0); \
    acc[1][1] = __builtin_amdgcn_mfma_f32_32x32x16_bf16(a1l, b1h, acc[1][1], 0,0,0);

// ---------------------------------------------------------------------------
// qkv GEMM, LDS-staged (128x128 tile, BK=32, padded LDS rows, 4 waves 2x2).
// ---------------------------------------------------------------------------
__global__ __launch_bounds__(256) void gemm_qkv_mfma(
    const unsigned short* __restrict__ Ah, const unsigned short* __restrict__ Al,
    const unsigned short* __restrict__ Bh, const unsigned short* __restrict__ Bl,
    const float* __restrict__ bias,
    unsigned short* __restrict__ qh, unsigned short* __restrict__ ql,
    unsigned short* __restrict__ kh, unsigned short* __restrict__ kl,
    unsigned short* __restrict__ vh, unsigned short* __restrict__ vl)
{
    __shared__ unsigned short ahs[128][LP], als[128][LP];
    __shared__ unsigned short bhs[128][LP], bls[128][LP];
    int t = threadIdx.x;
    int l = t & 63, w = t >> 6;
    int lq = l & 31, hi = l >> 5;
    int wr = w >> 1, wc = w & 1;
    int col0 = blockIdx.x*128, row0 = blockIdx.y*128;

    int srow[2], scol[2], sa[2];
    #pragma unroll
    for (int i = 0; i < 2; i++){
        int idx = i*256 + t;
        srow[i] = idx >> 2;
        scol[i] = (idx & 3) * 8;
        int ar = row0 + srow[i]; if (ar >= M_ROWS) ar = M_ROWS-1;
        sa[i] = ar;
    }

    f32x16_t acc[2][2];
    #pragma unroll
    for (int i = 0; i < 16; i++){
        acc[0][0][i]=0.f; acc[0][1][i]=0.f; acc[1][0][i]=0.f; acc[1][1][i]=0.f;
    }

    for (int k0 = 0; k0 < NC; k0 += 32){
        if (k0) __syncthreads();
        #pragma unroll
        for (int i = 0; i < 2; i++){
            size_t ao = (size_t)sa[i]*NC + k0 + scol[i];
            size_t bo = (size_t)(col0 + srow[i])*NC + k0 + scol[i];
            u16x8_t va  = *(const u16x8_t*)(Ah + ao);
            u16x8_t va2 = *(const u16x8_t*)(Al + ao);
            u16x8_t vb  = *(const u16x8_t*)(Bh + bo);
            u16x8_t vb2 = *(const u16x8_t*)(Bl + bo);
            *(u16x8_t*)&ahs[srow[i]][scol[i]] = va;
            *(u16x8_t*)&als[srow[i]][scol[i]] = va2;
            *(u16x8_t*)&bhs[srow[i]][scol[i]] = vb;
            *(u16x8_t*)&bls[srow[i]][scol[i]] = vb2;
        }
        __syncthreads();
        #pragma unroll
        for (int kk = 0; kk < 2; kk++){
            int co = kk*16 + 8*hi;
            bf16x8_t a0h = *(const bf16x8_t*)&ahs[wr*64+lq][co];
            bf16x8_t a1h = *(const bf16x8_t*)&ahs[wr*64+32+lq][co];
            bf16x8_t b0h = *(const bf16x8_t*)&bhs[wc*64+lq][co];
            bf16x8_t b1h = *(const bf16x8_t*)&bhs[wc*64+32+lq][co];
            bf16x8_t a0l = *(const bf16x8_t*)&als[wr*64+lq][co];
            bf16x8_t a1l = *(const bf16x8_t*)&als[wr*64+32+lq][co];
            bf16x8_t b0l = *(const bf16x8_t*)&bls[wc*64+lq][co];
            bf16x8_t b1l = *(const bf16x8_t*)&bls[wc*64+32+lq][co];
            MFMA12(a0h,a1h,b0h,b1h,a0l,a1l,b0l,b1l)
        }
    }

    int colW = col0 + wc*64, rowW = row0 + wr*64;
    #pragma unroll
    for (int fn = 0; fn < 2; fn++){
        int colb = colW + fn*32 + lq;
        float bb = bias[colb];
        int tt = colb >> 10, h = (colb >> 6) & 15, d = colb & 63;
        unsigned short* dsth = (tt == 0) ? qh : (tt == 1 ? kh : vh);
        unsigned short* dstl = (tt == 0) ? ql : (tt == 1 ? kl : vl);
        #pragma unroll
        for (int fm = 0; fm < 2; fm++){
            #pragma unroll
            for (int r = 0; r < 16; r++){
                int orow = rowW + fm*32 + (r&3) + 8*(r>>2) + 4*hi;
                if (orow < M_ROWS){
                    float val = acc[fm][fn][r] + bb;
                    int b = orow / NTOK, n = orow % NTOK;
                    unsigned short hv = f2bf(val);
                    unsigned short lv = f2bf(val - bf2f(hv));
                    size_t idx = ((size_t)(b*NH + h)*NTOK + n)*HD + d;
                    dsth[idx] = hv; dstl[idx] = lv;
                }
            }
        }
    }
}

// ---------------------------------------------------------------------------
// proj GEMM, LDS-staged (64x128 tile, BK=32). A split bf16 in HEAD layout.
// ---------------------------------------------------------------------------
__global__ __launch_bounds__(256) void gemm_proj_mfma(
    const unsigned short* __restrict__ Ah, const unsigned short* __restrict__ Al,
    const unsigned short* __restrict__ Bh, const unsigned short* __restrict__ Bl,
    const float* __restrict__ bias, float alpha, float* __restrict__ out)
{
    __shared__ unsigned short ahs[64][LP], als[64][LP];
    __shared__ unsigned short bhs[128][LP], bls[128][LP];
    int t = threadIdx.x;
    int l = t & 63, w = t >> 6;
    int lq = l & 31, hi = l >> 5;
    int wr = w >> 1, wc = w & 1;
    int col0 = blockIdx.x*128, row0 = blockIdx.y*64;

    int sarow = t >> 2, sacol = (t & 3) * 8;
    int ar = row0 + sarow; if (ar >= M_ROWS) ar = M_ROWS-1;
    size_t abase = (size_t)(ar / NTOK)*NH*HSTR + (size_t)(ar % NTOK)*HD;
    int sbrow[2], sbcol[2];
    #pragma unroll
    for (int i = 0; i < 2; i++){
        int idx = i*256 + t;
        sbrow[i] = idx >> 2;
        sbcol[i] = (idx & 3) * 8;
    }

    f32x16_t acc[2];
    #pragma unroll
    for (int i = 0; i < 16; i++){ acc[0][i]=0.f; acc[1][i]=0.f; }

    for (int k0 = 0; k0 < NC; k0 += 32){
        if (k0) __syncthreads();
        {
            int kk = k0 + sacol;
            size_t ao = abase + (size_t)(kk >> 6)*HSTR + (kk & 63);
            u16x8_t va  = *(const u16x8_t*)(Ah + ao);
            u16x8_t va2 = *(const u16x8_t*)(Al + ao);
            *(u16x8_t*)&ahs[sarow][sacol] = va;
            *(u16x8_t*)&als[sarow][sacol] = va2;
            #pragma unroll
            for (int i = 0; i < 2; i++){
                size_t bo = (size_t)(col0 + sbrow[i])*NC + k0 + sbcol[i];
                u16x8_t vb  = *(const u16x8_t*)(Bh + bo);
                u16x8_t vb2 = *(const u16x8_t*)(Bl + bo);
                *(u16x8_t*)&bhs[sbrow[i]][sbcol[i]] = vb;
                *(u16x8_t*)&bls[sbrow[i]][sbcol[i]] = vb2;
            }
        }
        __syncthreads();
        #pragma unroll
        for (int kk = 0; kk < 2; kk++){
            int co = kk*16 + 8*hi;
            bf16x8_t a0h = *(const bf16x8_t*)&ahs[wr*32+lq][co];
            bf16x8_t a0l = *(const bf16x8_t*)&als[wr*32+lq][co];
            bf16x8_t b0h = *(const bf16x8_t*)&bhs[wc*64+lq][co];
            bf16x8_t b1h = *(const bf16x8_t*)&bhs[wc*64+32+lq][co];
            bf16x8_t b0l = *(const bf16x8_t*)&bls[wc*64+lq][co];
            bf16x8_t b1l = *(const bf16x8_t*)&bls[wc*64+32+lq][co];
            acc[0] = __builtin_amdgcn_mfma_f32_32x32x16_bf16(a0h, b0h, acc[0], 0,0,0);
            acc[1] = __builtin_amdgcn_mfma_f32_32x32x16_bf16(a0h, b1h, acc[1], 0,0,0);
            acc[0] = __builtin_amdgcn_mfma_f32_32x32x16_bf16(a0h, b0l, acc[0], 0,0,0);
            acc[1] = __builtin_amdgcn_mfma_f32_32x32x16_bf16(a0h, b1l, acc[1], 0,0,0);
            acc[0] = __builtin_amdgcn_mfma_f32_32x32x16_bf16(a0l, b0h, acc[0], 0,0,0);
            acc[1] = __builtin_amdgcn_mfma_f32_32x32x16_bf16(a0l, b1h, acc[1], 0,0,0);
        }
    }

    #pragma unroll
    for (int fn = 0; fn < 2; fn++){
        int colb = col0 + wc*64 + fn*32 + lq;
        float bb = bias[colb];
        #pragma unroll
        for (int r = 0; r < 16; r++){
            int orow = row0 + wr*32 + (r&3) + 8*(r>>2) + 4*hi;
            if (orow < M_ROWS){
                int b = orow / NTOK, n = orow % NTOK;
                out[((size_t)n*NB + b)*NC + colb] = alpha*acc[fn][r] + bb;
            }
        }
    }
}

// ---------------------------------------------------------------------------
// Flash inner body, no LDS. VAR=0: online softmax + 1/l (x_ori).
// VAR=1: static max (=scale, exact for l2n'd Q=K) + fused output-l2n.
// VAR=2: static max + 1/l.
// LO=1: bf16x3 scores (hi/lo of Q,K). LO=0: hi-only scores (inputs are
// l2-normalized; per-score abs err ~5e-4 -> within error budget).
// ---------------------------------------------------------------------------
template<int VAR, int LO>
__device__ __forceinline__ void flash_body(
    const unsigned short* Qh, const unsigned short* Ql,
    const unsigned short* Kh, const unsigned short* Kl,
    const unsigned short* VT,
    unsigned short* Ohi, unsigned short* Olo,
    float scale, int acc, int bh, int qt, int lane)
{
    int hi = lane >> 5, lq = lane & 31;
    const size_t base = (size_t)bh * NTOK * HD;
    const size_t vtb  = (size_t)bh * HD * VTW;

    int qrow = qt*32 + lq;
    int qr = qrow < NTOK ? qrow : NTOK-1;
    const size_t qoff = base + (size_t)qr*HD + 8*hi;
    bf16x8_t qfh[4], qfl[4];
    #pragma unroll
    for (int c = 0; c < 4; c++){
        qfh[c] = *(const bf16x8_t*)(Qh + qoff + 16*c);
        if (LO) qfl[c] = *(const bf16x8_t*)(Ql + qoff + 16*c);
    }

    f32x16_t od0, od1;
    #pragma unroll
    for (int r = 0; r < 16; r++){ od0[r]=0.f; od1[r]=0.f; }
    float m_ = -1e30f, l_ = 0.f;

    for (int kt = 0; kt < 19; kt++){
        int krow = kt*32 + lq;
        int kr = krow < NTOK ? krow : NTOK-1;
        const size_t koff = base + (size_t)kr*HD + 8*hi;
        bf16x8_t kfh[4], kfl[4];
        #pragma unroll
        for (int c = 0; c < 4; c++){
            kfh[c] = *(const bf16x8_t*)(Kh + koff + 16*c);
            if (LO) kfl[c] = *(const bf16x8_t*)(Kl + koff + 16*c);
        }
        f32x16_t sf;
        #pragma unroll
        for (int r = 0; r < 16; r++) sf[r] = 0.f;
        __builtin_amdgcn_s_setprio(1);
        #pragma unroll
        for (int c = 0; c < 4; c++){
            sf = __builtin_amdgcn_mfma_f32_32x32x16_bf16(kfh[c], qfh[c], sf, 0,0,0);
            if (LO){
                sf = __builtin_amdgcn_mfma_f32_32x32x16_bf16(kfh[c], qfl[c], sf, 0,0,0);
                sf = __builtin_amdgcn_mfma_f32_32x32x16_bf16(kfl[c], qfh[c], sf, 0,0,0);
            }
        }
        __builtin_amdgcn_s_setprio(0);

        float p[16];
        if (VAR == 0){
            float tm = -1e30f;
            if (kt == 18){
                #pragma unroll
                for (int r = 0; r < 16; r++){
                    int key = 576 + (r&3) + 8*(r>>2) + 4*hi;
                    p[r] = (key < NTOK) ? sf[r]*scale : -1e30f;
                    tm = fmaxf(tm, p[r]);
                }
            } else {
                #pragma unroll
                for (int r = 0; r < 16; r++){ p[r] = sf[r]*scale; tm = fmaxf(tm, p[r]); }
            }
            tm = fmaxf(tm, __shfl_xor(tm, 32));
            float mn = fmaxf(m_, tm);
            float corr = __expf(m_ - mn);
            float ps = 0.f;
            #pragma unroll
            for (int r = 0; r < 16; r++){ p[r] = __expf(p[r] - mn); ps += p[r]; }
            ps += __shfl_xor(ps, 32);
            l_ = l_*corr + ps;
            m_ = mn;
            #pragma unroll
            for (int r = 0; r < 16; r++){
                int crow = (r&3) + 8*(r>>2) + 4*hi;
                float cR = __shfl(corr, crow);
                od0[r] *= cR; od1[r] *= cR;
            }
        } else {
            // static max == scale (row max is the diagonal, exactly scale)
            if (kt == 18){
                #pragma unroll
                for (int r = 0; r < 16; r++){
                    int key = 576 + (r&3) + 8*(r>>2) + 4*hi;
                    p[r] = (key < NTOK) ? __expf(sf[r]*scale - scale) : 0.f;
                }
            } else {
                #pragma unroll
                for (int r = 0; r < 16; r++) p[r] = __expf(sf[r]*scale - scale);
            }
            if (VAR == 2){
                #pragma unroll
                for (int r = 0; r < 16; r++) l_ += p[r];
            }
        }

        U4 pa[2];
        #pragma unroll
        for (int ks = 0; ks < 2; ks++){
            unsigned int X0 = cvt_pk(p[8*ks+0], p[8*ks+1]);
            unsigned int X1 = cvt_pk(p[8*ks+2], p[8*ks+3]);
            unsigned int X2 = cvt_pk(p[8*ks+4], p[8*ks+5]);
            unsigned int X3 = cvt_pk(p[8*ks+6], p[8*ks+7]);
            unsigned int Y0 = (unsigned int)__shfl_xor((int)X2, 32);
            unsigned int Y1 = (unsigned int)__shfl_xor((int)X3, 32);
            unsigned int Y2 = (unsigned int)__shfl_xor((int)X0, 32);
            unsigned int Y3 = (unsigned int)__shfl_xor((int)X1, 32);
            pa[ks].u[0] = hi ? Y0 : X0;
            pa[ks].u[1] = hi ? Y1 : X1;
            pa[ks].u[2] = hi ? X2 : Y2;
            pa[ks].u[3] = hi ? X3 : Y3;
        }
        const size_t v0 = vtb + (size_t)lq*VTW      + kt*32 + 8*hi;
        const size_t v1 = vtb + (size_t)(32+lq)*VTW + kt*32 + 8*hi;
        bf16x8_t vf00 = *(const bf16x8_t*)(VT + v0);
        bf16x8_t vf01 = *(const bf16x8_t*)(VT + v0 + 16);
        bf16x8_t vf10 = *(const bf16x8_t*)(VT + v1);
        bf16x8_t vf11 = *(const bf16x8_t*)(VT + v1 + 16);
        __builtin_amdgcn_s_setprio(1);
        od0 = __builtin_amdgcn_mfma_f32_32x32x16_bf16(pa[0].v, vf00, od0, 0,0,0);
        od0 = __builtin_amdgcn_mfma_f32_32x32x16_bf16(pa[1].v, vf01, od0, 0,0,0);
        od1 = __builtin_amdgcn_mfma_f32_32x32x16_bf16(pa[0].v, vf10, od1, 0,0,0);
        od1 = __builtin_amdgcn_mfma_f32_32x32x16_bf16(pa[1].v, vf11, od1, 0,0,0);
        __builtin_amdgcn_s_setprio(0);
    }

    if (VAR == 1){
        #pragma unroll
        for (int r = 0; r < 16; r++){
            float s = od0[r]*od0[r] + od1[r]*od1[r];
            #pragma unroll
            for (int o = 1; o < 32; o <<= 1) s += __shfl_xor(s, o);
            int crow = (r&3) + 8*(r>>2) + 4*hi;
            int qg = qt*32 + crow;
            if (qg < NTOK){
                float inv = 1.f / fmaxf(sqrtf(s), 1e-12f);
                size_t o0 = base + (size_t)qg*HD + lq;
                float a0 = od0[r]*inv, a1 = od1[r]*inv;
                unsigned short h0 = f2bf(a0), h1 = f2bf(a1);
                Ohi[o0] = h0;    Olo[o0]    = f2bf(a0 - bf2f(h0));
                Ohi[o0+32] = h1; Olo[o0+32] = f2bf(a1 - bf2f(h1));
            }
        }
        return;
    }

    if (VAR == 2) l_ = l_ + __shfl_xor(l_, 32);
    float linv = 1.f / l_;
    #pragma unroll
    for (int r = 0; r < 16; r++){
        int crow = (r&3) + 8*(r>>2) + 4*hi;
        int qg = qt*32 + crow;
        float li = __shfl(linv, crow);
        if (qg < NTOK){
            size_t o0 = base + (size_t)qg*HD + lq;
            float a0 = od0[r]*li, a1 = od1[r]*li;
            if (acc){
                a0 += bf2f(Ohi[o0])    + bf2f(Olo[o0]);
                a1 += bf2f(Ohi[o0+32]) + bf2f(Olo[o0+32]);
            }
            unsigned short h0 = f2bf(a0), h1 = f2bf(a1);
            Ohi[o0] = h0;    Olo[o0]    = f2bf(a0 - bf2f(h0));
            Ohi[o0+32] = h1; Olo[o0+32] = f2bf(a1 - bf2f(h1));
        }
    }
}

__global__ __launch_bounds__(256) void flash2(
    const unsigned short* __restrict__ Qh, const unsigned short* __restrict__ Ql,
    const unsigned short* __restrict__ Kh, const unsigned short* __restrict__ Kl,
    const unsigned short* __restrict__ VT,
    unsigned short* __restrict__ Ohi, unsigned short* __restrict__ Olo,
    const float* __restrict__ itemp, float cscale, int acc)
{
    int w = threadIdx.x >> 6, lane = threadIdx.x & 63;
    int bid = blockIdx.x;
    int bh = (bid & 7) * 16 + (bid >> 3) / 5;
    int qt = ((bid >> 3) % 5) * 4 + w;
    if (qt >= 19) return;
    float scale = itemp ? itemp[bh >> 4] : cscale;
    flash_body<0,1>(Qh, Ql, Kh, Kl, VT, Ohi, Olo, scale, acc, bh, qt, lane);
}

// Batched: 3 independent self-attentions (Q=K), slice = blockIdx.y. Hi-only.
template<int VAR>
__global__ __launch_bounds__(256) void flash2b(
    const unsigned short* __restrict__ q0h, const unsigned short* __restrict__ q0l,
    const unsigned short* __restrict__ q1h, const unsigned short* __restrict__ q1l,
    const unsigned short* __restrict__ q2h, const unsigned short* __restrict__ q2l,
    const unsigned short* __restrict__ vt0, const unsigned short* __restrict__ vt1,
    const unsigned short* __restrict__ vt2,
    unsigned short* __restrict__ o0h, unsigned short* __restrict__ o0l,
    unsigned short* __restrict__ o1h, unsigned short* __restrict__ o1l,
    unsigned short* __restrict__ o2h, unsigned short* __restrict__ o2l,
    const float* __restrict__ itemp)
{
    int w = threadIdx.x >> 6, lane = threadIdx.x & 63;
    int bid = blockIdx.x;
    int bh = (bid & 7) * 16 + (bid >> 3) / 5;
    int qt = ((bid >> 3) % 5) * 4 + w;
    if (qt >= 19) return;
    int i = blockIdx.y;
    const unsigned short *Qh, *Ql, *VT;
    unsigned short *Oh, *Ol;
    if (i == 0){ Qh=q0h; Ql=q0l; VT=vt0; Oh=o0h; Ol=o0l; }
    else if (i == 1){ Qh=q1h; Ql=q1l; VT=vt1; Oh=o1h; Ol=o1l; }
    else { Qh=q2h; Ql=q2l; VT=vt2; Oh=o2h; Ol=o2l; }
    flash_body<VAR,0>(Qh, Ql, Qh, Ql, VT, Oh, Ol, itemp[bh >> 4], 0, bh, qt, lane);
}

// 4-wide merged: slices 0-2 = ys_i (VAR=1 hi-only, fused l2n -> z_i);
// slice 3 = x_ori attention (VAR=0 bf16x3) -> o_ori.
__global__ __launch_bounds__(256) void flash4(
    const unsigned short* __restrict__ x1h, const unsigned short* __restrict__ x1l,
    const unsigned short* __restrict__ x2h, const unsigned short* __restrict__ x2l,
    const unsigned short* __restrict__ x3h, const unsigned short* __restrict__ x3l,
    const unsigned short* __restrict__ qh_, const unsigned short* __restrict__ ql_,
    const unsigned short* __restrict__ kh_, const unsigned short* __restrict__ kl_,
    const unsigned short* __restrict__ vt1, const unsigned short* __restrict__ vt2,
    const unsigned short* __restrict__ vt3, const unsigned short* __restrict__ vtv,
    unsigned short* __restrict__ z1h, unsigned short* __restrict__ z1l,
    unsigned short* __restrict__ z2h, unsigned short* __restrict__ z2l,
    unsigned short* __restrict__ z3h, unsigned short* __restrict__ z3l,
    unsigned short* __restrict__ ooh, unsigned short* __restrict__ ool,
    const float* __restrict__ itemp)
{
    int w = threadIdx.x >> 6, lane = threadIdx.x & 63;
    int bid = blockIdx.x;
    int bh = (bid & 7) * 16 + (bid >> 3) / 5;
    int qt = ((bid >> 3) % 5) * 4 + w;
    if (qt >= 19) return;
    int i = blockIdx.y;
    if (i == 3){
        flash_body<0,1>(qh_, ql_, kh_, kl_, vtv, ooh, ool, 0.125f, 0, bh, qt, lane);
    } else {
        const unsigned short *Qh, *Ql, *VT;
        unsigned short *Oh, *Ol;
        if (i == 0){ Qh=x1h; Ql=x1l; VT=vt1; Oh=z1h; Ol=z1l; }
        else if (i == 1){ Qh=x2h; Ql=x2l; VT=vt2; Oh=z2h; Ol=z2l; }
        else { Qh=x3h; Ql=x3l; VT=vt3; Oh=z3h; Ol=z3l; }
        flash_body<1,0>(Qh, Ql, Qh, Ql, VT, Oh, Ol, itemp[bh >> 4], 0, bh, qt, lane);
    }
}

// ---------------------------------------------------------------------------
// sum of 3 split-bf16 buffers -> split-bf16 (fp32 adds, fixed order)
// ---------------------------------------------------------------------------
__global__ __launch_bounds__(256) void sum3(
    const unsigned short* __restrict__ ah, const unsigned short* __restrict__ al,
    const unsigned short* __restrict__ bh, const unsigned short* __restrict__ bl,
    const unsigned short* __restrict__ ch, const unsigned short* __restrict__ cl,
    unsigned short* __restrict__ oh, unsigned short* __restrict__ ol)
{
    size_t idx = ((size_t)blockIdx.x*256 + threadIdx.x)*4;
    ushort4 vah = *(const ushort4*)(ah+idx), val = *(const ushort4*)(al+idx);
    ushort4 vbh = *(const ushort4*)(bh+idx), vbl = *(const ushort4*)(bl+idx);
    ushort4 vch = *(const ushort4*)(ch+idx), vcl = *(const ushort4*)(cl+idx);
    ushort4 rh, rl;
    #define S3(f) { \
        float s = bf2f(vah.f)+bf2f(val.f)+bf2f(vbh.f)+bf2f(vbl.f)+bf2f(vch.f)+bf2f(vcl.f); \
        rh.f = f2bf(s); rl.f = f2bf(s - bf2f(rh.f)); }
    S3(x) S3(y) S3(z) S3(w)
    #undef S3
    *(ushort4*)(oh+idx) = rh;
    *(ushort4*)(ol+idx) = rl;
}

// ---------------------------------------------------------------------------
__global__ __launch_bounds__(256) void row_norm(const float* __restrict__ X,
                                                float* __restrict__ rn)
{
    int id = blockIdx.x;
    int b = id / NTOK, n = id % NTOK;
    const float* src = X + ((size_t)n*NB + b)*NC;
    int tid = threadIdx.x;
    float s = 0.f;
    for (int i = tid; i < NC; i += 256) { float t = src[i]; s += t*t; }
    #pragma unroll
    for (int o = 1; o < 64; o <<= 1) s += __shfl_xor(s, o);
    __shared__ float red[4];
    if ((tid & 63) == 0) red[tid >> 6] = s;
    __syncthreads();
    if (tid == 0) rn[id] = sqrtf(red[0] + red[1] + red[2] + red[3]);
}

__global__ __launch_bounds__(256) void calc_invtemp(const float* __restrict__ rn,
                                                    float* __restrict__ it)
{
    int b = blockIdx.x;
    int tid = threadIdx.x;
    float s = 0.f;
    for (int i = tid; i < NTOK; i += 256) s += rn[b*NTOK + i];
    #pragma unroll
    for (int o = 1; o < 64; o <<= 1) s += __shfl_xor(s, o);
    __shared__ float red[4];
    if ((tid & 63) == 0) red[tid >> 6] = s;
    __syncthreads();
    if (tid == 0) it[b] = (red[0]+red[1]+red[2]+red[3]) / (float)NTOK * 0.125f;
}

// ---------------------------------------------------------------------------
__global__ __launch_bounds__(256) void l2n_s2s(const unsigned short* __restrict__ ih,
        const unsigned short* __restrict__ il,
        unsigned short* __restrict__ oh, unsigned short* __restrict__ ol)
{
    size_t row = (size_t)blockIdx.x*4 + (threadIdx.x >> 6);
    int lane = threadIdx.x & 63;
    size_t ii = row*HD + lane;
    float x = bf2f(ih[ii]) + bf2f(il[ii]);
    float s = x*x;
    #pragma unroll
    for (int o = 1; o < 64; o <<= 1) s += __shfl_xor(s, o);
    float xn = x / fmaxf(sqrtf(s), 1e-12f);
    unsigned short hv = f2bf(xn);
    oh[ii] = hv;
    ol[ii] = f2bf(xn - bf2f(hv));
}

// ---------------------------------------------------------------------------
extern "C" void kernel_launch(void* const* d_in, const int* in_sizes, int n_in,
                              void* d_out, int out_size, void* d_ws, size_t ws_size,
                              hipStream_t stream)
{
    const float* x      = (const float*)d_in[0];
    const float* qkv_w  = (const float*)d_in[1];
    const float* qkv_b  = (const float*)d_in[2];
    const float* proj_w = (const float*)d_in[3];
    const float* proj_b = (const float*)d_in[4];
    float* out = (float*)d_out;            // [0,SZ)=x_gem, [SZ,2SZ)=x_ori

    unsigned short* w16 = (unsigned short*)d_ws;
    #define SL(i) (w16 + (size_t)(i)*SZ)          // 8 bf16 slots
    unsigned short* WQh = w16 + 8*SZ;             // WQ, dead after qkv
    unsigned short* WQl = WQh + WSZ;
    unsigned short* VT1 = WQh;                    // aliases WQ
    size_t p = 8*SZ + 2*WSZ;
    unsigned short* VTv = w16 + p;  p += VTSZ;
    unsigned short* VT2 = w16 + p;  p += VTSZ;
    unsigned short* VT3 = w16 + p;  p += VTSZ;
    unsigned short* WPh = w16 + p;  p += PSZ;
    unsigned short* WPl = w16 + p;  p += PSZ;
    unsigned short* E0  = w16 + p;  p += SZ;
    unsigned short* E1  = w16 + p;  p += SZ;
    float* rn = (float*)(w16 + p);  p += 2*(M_ROWS + 8);
    float* it = rn + M_ROWS;
    size_t need3 = p * sizeof(unsigned short);    // 3-wide batched layout
    unsigned short* F0 = w16 + p;  p += SZ;       // merged4-only
    unsigned short* F1 = w16 + p;  p += SZ;
    unsigned short* G0 = w16 + p;  p += SZ;
    unsigned short* G1 = w16 + p;  p += SZ;
    size_t need4 = p * sizeof(unsigned short);    // 4-wide merged layout
    int merged4  = (ws_size >= need4);
    int batched3 = (ws_size >= need3);

    unsigned short* S0 = (unsigned short*)d_out;  // x_gem bytes (scratch pair)
    unsigned short* S1 = S0 + SZ;
    unsigned short* T0 = S0 + 2*SZ;               // x_ori bytes (scratch pair)
    unsigned short* T1 = S0 + 3*SZ;

    dim3 blk(256);
    dim3 gq(24,37), gp(8,73), gfl(640), gflb(640,3), gfl4(640,4), gt(10,128);

    // common prologue: inv_temp, splits, qkv gemm, VTv
    row_norm<<<dim3(M_ROWS), blk, 0, stream>>>(x, rn);
    calc_invtemp<<<dim3(NB), blk, 0, stream>>>(rn, it);
    split_rows<<<dim3(M_ROWS), blk, 0, stream>>>(x, SL(6), SL(7), 1);
    split_rows<<<dim3(3*NC),  blk, 0, stream>>>(qkv_w, WQh, WQl, 0);
    gemm_qkv_mfma<<<gq, blk, 0, stream>>>(SL(6), SL(7), WQh, WQl, qkv_b,
        SL(0), SL(1), SL(2), SL(3), SL(4), SL(5));
    transp64<<<gt, blk, 0, stream>>>(SL(4), VTv);

    if (merged4){
        // xs1 = l2n(v) in-place (4,5); xs2 = l2n(k) -> (6,7); xs3 = l2n(q) -> E
        l2n_s2s<<<dim3(18464), blk, 0, stream>>>(SL(4),SL(5), SL(4),SL(5));
        l2n_s2s<<<dim3(18464), blk, 0, stream>>>(SL(2),SL(3), SL(6),SL(7));
        l2n_s2s<<<dim3(18464), blk, 0, stream>>>(SL(0),SL(1), E0,E1);
        transp64<<<gt, blk, 0, stream>>>(SL(4), VT1);
        transp64<<<gt, blk, 0, stream>>>(SL(6), VT2);
        transp64<<<gt, blk, 0, stream>>>(E0,  VT3);
        split_rows<<<dim3(NC), blk, 0, stream>>>(proj_w, WPh, WPl, 0);
        // merged: z1->T, z2->F, z3->G, o_ori->S
        flash4<<<gfl4, blk, 0, stream>>>(
            SL(4),SL(5), SL(6),SL(7), E0,E1,
            SL(0),SL(1), SL(2),SL(3),
            VT1, VT2, VT3, VTv,
            T0,T1, F0,F1, G0,G1, S0,S1, it);
        // finals: read z (T,F,G) x VTv -> (4,5),(6,7),E   (q,k,xs dead)
        flash2b<2><<<gflb, blk, 0, stream>>>(
            T0,T1, F0,F1, G0,G1,
            VTv, VTv, VTv,
            SL(4),SL(5), SL(6),SL(7), E0,E1, it);
        sum3<<<dim3(4616), blk, 0, stream>>>(
            SL(4),SL(5), SL(6),SL(7), E0,E1, SL(4),SL(5));
        // proj_ori first (reads S=o_ori, writes T region; z1 dead)
        gemm_proj_mfma<<<gp, blk, 0, stream>>>(S0,S1, WPh,WPl, proj_b, 1.f,
            out + SZ);
        // proj_gem (reads (4,5), writes S region; o_ori dead)
        gemm_proj_mfma<<<gp, blk, 0, stream>>>(SL(4),SL(5), WPh,WPl, proj_b,
            1.f/3.f, out);
    } else if (batched3){
        // R10-13 path: x_ori first, then 3-wide ys + finals
        flash2<<<gfl, blk, 0, stream>>>(SL(0),SL(1),SL(2),SL(3), VTv,
            SL(6),SL(7), nullptr, 0.125f, 0);
        split_rows<<<dim3(NC), blk, 0, stream>>>(proj_w, WPh, WPl, 0);
        gemm_proj_mfma<<<gp, blk, 0, stream>>>(SL(6),SL(7), WPh,WPl, proj_b,
            1.f, out + SZ);
        l2n_s2s<<<dim3(18464), blk, 0, stream>>>(SL(4),SL(5), SL(4),SL(5));
        l2n_s2s<<<dim3(18464), blk, 0, stream>>>(SL(2),SL(3), SL(2),SL(3));
        l2n_s2s<<<dim3(18464), blk, 0, stream>>>(SL(0),SL(1), SL(0),SL(1));
        transp64<<<gt, blk, 0, stream>>>(SL(4), VT1);
        transp64<<<gt, blk, 0, stream>>>(SL(2), VT2);
        transp64<<<gt, blk, 0, stream>>>(SL(0), VT3);
        flash2b<1><<<gflb, blk, 0, stream>>>(
            SL(4),SL(5), SL(2),SL(3), SL(0),SL(1),
            VT1, VT2, VT3,
            SL(6),SL(7), S0,S1, E0,E1, it);
        flash2b<2><<<gflb, blk, 0, stream>>>(
            SL(6),SL(7), S0,S1, E0,E1,
            VTv, VTv, VTv,
            SL(4),SL(5), SL(2),SL(3), SL(0),SL(1), it);
        sum3<<<dim3(4616), blk, 0, stream>>>(
            SL(4),SL(5), SL(2),SL(3), SL(0),SL(1), SL(4),SL(5));
        gemm_proj_mfma<<<gp, blk, 0, stream>>>(SL(4),SL(5), WPh,WPl, proj_b,
            1.f/3.f, out);
    } else {
        // serial fallback (online softmax, full precision throughout)
        unsigned short* VTx = WQh;
        flash2<<<gfl, blk, 0, stream>>>(SL(0),SL(1),SL(2),SL(3), VTv,
            SL(6),SL(7), nullptr, 0.125f, 0);
        split_rows<<<dim3(NC), blk, 0, stream>>>(proj_w, WPh, WPl, 0);
        gemm_proj_mfma<<<gp, blk, 0, stream>>>(SL(6),SL(7), WPh,WPl, proj_b,
            1.f, out + SZ);
        l2n_s2s<<<dim3(18464), blk, 0, stream>>>(SL(4),SL(5), SL(6),SL(7));
        transp64<<<gt, blk, 0, stream>>>(SL(6), VTx);
        flash2<<<gfl, blk, 0, stream>>>(SL(6),SL(7),SL(6),SL(7), VTx,
            SL(4),SL(5), it, 0.f, 0);
        l2n_s2s<<<dim3(18464), blk, 0, stream>>>(SL(4),SL(5), SL(6),SL(7));
        l2n_s2s<<<dim3(18464), blk, 0, stream>>>(SL(2),SL(3), SL(2),SL(3));
        transp64<<<gt, blk, 0, stream>>>(SL(2), VTx);
        flash2<<<gfl, blk, 0, stream>>>(SL(2),SL(3),SL(2),SL(3), VTx,
            SL(4),SL(5), it, 0.f, 0);
        l2n_s2s<<<dim3(18464), blk, 0, stream>>>(SL(4),SL(5), SL(2),SL(3));
        l2n_s2s<<<dim3(18464), blk, 0, stream>>>(SL(0),SL(1), SL(0),SL(1));
        transp64<<<gt, blk, 0, stream>>>(SL(0), VTx);
        flash2<<<gfl, blk, 0, stream>>>(SL(0),SL(1),SL(0),SL(1), VTx,
            SL(4),SL(5), it, 0.f, 0);
        l2n_s2s<<<dim3(18464), blk, 0, stream>>>(SL(4),SL(5), SL(0),SL(1));
        flash2<<<gfl, blk, 0, stream>>>(SL(6),SL(7),SL(6),SL(7), VTv,
            SL(4),SL(5), it, 0.f, 0);
        flash2<<<gfl, blk, 0, stream>>>(SL(2),SL(3),SL(2),SL(3), VTv,
            SL(4),SL(5), it, 0.f, 1);
        flash2<<<gfl, blk, 0, stream>>>(SL(0),SL(1),SL(0),SL(1), VTv,
            SL(4),SL(5), it, 0.f, 1);
        gemm_proj_mfma<<<gp, blk, 0, stream>>>(SL(4),SL(5), WPh,WPl, proj_b,
            1.f/3.f, out);
    }
    #undef SL
}

// Round 16
// 614.762 us; speedup vs baseline: 1.6030x; 1.0019x over previous
//
#include <hip/hip_runtime.h>
#include <math.h>

#define NTOK 577
#define NB 8
#define NC 1024
#define NH 16
#define HD 64
#define M_ROWS (NB*NTOK)               // 4616
#define SZ ((size_t)NB*NH*NTOK*HD)     // 4726784 elements
#define WSZ ((size_t)3*NC*NC)          // 3145728
#define PSZ ((size_t)NC*NC)            // 1048576
#define VTW 608                        // padded key width for VT (19*32)
#define VTSZ ((size_t)NB*NH*HD*VTW)    // 4980736
#define HSTR ((size_t)NTOK*HD)         // 36928 head stride in A-layout
#define LP 36                          // padded LDS row (32 data + 4 pad)

typedef __attribute__((ext_vector_type(8)))  short bf16x8_t;
typedef __attribute__((ext_vector_type(8)))  unsigned short u16x8_t;
typedef __attribute__((ext_vector_type(16))) float f32x16_t;

union U4 { unsigned short s[8]; unsigned int u[4]; bf16x8_t v; };

__device__ inline unsigned short f2bf(float x){
    unsigned int u = __float_as_uint(x);
    u = (u + 0x7FFFu + ((u>>16)&1u)) >> 16;
    return (unsigned short)u;
}
__device__ inline float bf2f(unsigned short h){
    return __uint_as_float(((unsigned int)h)<<16);
}
__device__ inline unsigned int cvt_pk(float a, float b){
    unsigned int r;
    asm volatile("v_cvt_pk_bf16_f32 %0, %1, %2" : "=v"(r) : "v"(a), "v"(b));
    return r;
}

// ---------------------------------------------------------------------------
// merged split: rows 0..4615 = X [N,B,C] gather -> (xh,xl);
// rows 4616..7687 = qkv_w row-major -> (wh,wl)
// ---------------------------------------------------------------------------
__global__ __launch_bounds__(256) void split_x_w(const float* __restrict__ X,
        const float* __restrict__ W,
        unsigned short* __restrict__ xh, unsigned short* __restrict__ xl,
        unsigned short* __restrict__ wh, unsigned short* __restrict__ wl)
{
    int row = blockIdx.x, t = threadIdx.x;
    const float* s;
    unsigned short *dh, *dl;
    size_t drow;
    if (row < M_ROWS){
        int b = row / NTOK, n = row % NTOK;
        s = X + ((size_t)n*NB + b)*NC + 4*t;
        dh = xh; dl = xl; drow = row;
    } else {
        drow = row - M_ROWS;
        s = W + drow*NC + 4*t;
        dh = wh; dl = wl;
    }
    float4 v = *(const float4*)s;
    ushort4 hv, lv;
    hv.x = f2bf(v.x); lv.x = f2bf(v.x - bf2f(hv.x));
    hv.y = f2bf(v.y); lv.y = f2bf(v.y - bf2f(hv.y));
    hv.z = f2bf(v.z); lv.z = f2bf(v.z - bf2f(hv.z));
    hv.w = f2bf(v.w); lv.w = f2bf(v.w - bf2f(hv.w));
    *(ushort4*)(dh + drow*NC + 4*t) = hv;
    *(ushort4*)(dl + drow*NC + 4*t) = lv;
}

__global__ __launch_bounds__(256) void split_rows(const float* __restrict__ src,
        unsigned short* __restrict__ dh, unsigned short* __restrict__ dl)
{
    int row = blockIdx.x, t = threadIdx.x;
    const float* s = src + (size_t)row*NC + 4*t;
    float4 v = *(const float4*)s;
    ushort4 hv, lv;
    hv.x = f2bf(v.x); lv.x = f2bf(v.x - bf2f(hv.x));
    hv.y = f2bf(v.y); lv.y = f2bf(v.y - bf2f(hv.y));
    hv.z = f2bf(v.z); lv.z = f2bf(v.z - bf2f(hv.z));
    hv.w = f2bf(v.w); lv.w = f2bf(v.w - bf2f(hv.w));
    *(ushort4*)(dh + (size_t)row*NC + 4*t) = hv;
    *(ushort4*)(dl + (size_t)row*NC + 4*t) = lv;
}

// ---------------------------------------------------------------------------
// Coalesced transpose: src hi-bf16 [BH][577][64] -> dst [BH][64][608], pads=0.
// Single and 3-slice variants.
// ---------------------------------------------------------------------------
__device__ __forceinline__ void transp_body(const unsigned short* src,
                                            unsigned short* dst)
{
    __shared__ unsigned short t[64][72];
    int bh = blockIdx.y;
    int n0 = blockIdx.x * 64;
    int tid = threadIdx.x;
    int r  = tid >> 2;
    int c0 = (tid & 3) * 16;
    int n = n0 + r;
    if (n < NTOK){
        const unsigned short* s = src + ((size_t)bh*NTOK + n)*HD + c0;
        *(u16x8_t*)&t[r][c0]   = *(const u16x8_t*)s;
        *(u16x8_t*)&t[r][c0+8] = *(const u16x8_t*)(s + 8);
    } else {
        u16x8_t z = (u16x8_t)0;
        *(u16x8_t*)&t[r][c0]   = z;
        *(u16x8_t*)&t[r][c0+8] = z;
    }
    __syncthreads();
    if (n0 + c0 < VTW){
        int d = r;
        U4 o0, o1;
        #pragma unroll
        for (int j = 0; j < 8; j++){ o0.s[j] = t[c0+j][d]; o1.s[j] = t[c0+8+j][d]; }
        unsigned short* dp = dst + ((size_t)bh*HD + d)*VTW + n0 + c0;
        *(u16x8_t*)dp       = (u16x8_t)o0.v;
        *(u16x8_t*)(dp + 8) = (u16x8_t)o1.v;
    }
}

__global__ __launch_bounds__(256) void transp64(const unsigned short* __restrict__ src,
                                                unsigned short* __restrict__ dst)
{
    transp_body(src, dst);
}

__global__ __launch_bounds__(256) void transp64x3(
    const unsigned short* __restrict__ s0, unsigned short* __restrict__ d0,
    const unsigned short* __restrict__ s1, unsigned short* __restrict__ d1,
    const unsigned short* __restrict__ s2, unsigned short* __restrict__ d2)
{
    int i = blockIdx.z;
    const unsigned short* s = (i == 0) ? s0 : (i == 1 ? s1 : s2);
    unsigned short* d = (i == 0) ? d0 : (i == 1 ? d1 : d2);
    transp_body(s, d);
}

#define MFMA12(a0h,a1h,b0h,b1h,a0l,a1l,b0l,b1l) \
    acc[0][0] = __builtin_amdgcn_mfma_f32_32x32x16_bf16(a0h, b0h, acc[0][0], 0,0,0); \
    acc[0][1] = __builtin_amdgcn_mfma_f32_32x32x16_bf16(a0h, b1h, acc[0][1], 0,0,0); \
    acc[1][0] = __builtin_amdgcn_mfma_f32_32x32x16_bf16(a1h, b0h, acc[1][0], 0,0,0); \
    acc[1][1] = __builtin_amdgcn_mfma_f32_32x32x16_bf16(a1h, b1h, acc[1][1], 0,0,0); \
    acc[0][0] = __builtin_amdgcn_mfma_f32_32x32x16_bf16(a0h, b0l, acc[0][0], 0,0,0); \
    acc[0][1] = __builtin_amdgcn_mfma_f32_32x32x16_bf16(a0h, b1l, acc[0][1], 0,0,0); \
    acc[1][0] = __builtin_amdgcn_mfma_f32_32x32x16_bf16(a1h, b0l, acc[1][0], 0,0,0); \
    acc[1][1] = __builtin_amdgcn_mfma_f32_32x32x16_bf16(a1h, b1l, acc[1][1], 0,0,0); \
    acc[0][0] = __builtin_amdgcn_mfma_f32_32x32x16_bf16(a0l, b0h, acc[0][0], 0,0,0); \
    acc[0][1] = __builtin_amdgcn_mfma_f32_32x32x16_bf16(a0l, b1h, acc[0][1], 0,0,0); \
    acc[1][0] = __builtin_amdgcn_mfma_f32_32x32x16_bf16(a1l, b0h, acc[1][0], 0,0,0); \
    acc[1][1] = __builtin_amdgcn_mfma_f32_32x32x16_bf16(a1l, b1h, acc[1][1], 0,0,0);

// ---------------------------------------------------------------------------
// qkv GEMM, LDS-staged (128x128 tile, BK=32, padded LDS rows, 4 waves 2x2).
// ---------------------------------------------------------------------------
__global__ __launch_bounds__(256) void gemm_qkv_mfma(
    const unsigned short* __restrict__ Ah, const unsigned short* __restrict__ Al,
    const unsigned short* __restrict__ Bh, const unsigned short* __restrict__ Bl,
    const float* __restrict__ bias,
    unsigned short* __restrict__ qh, unsigned short* __restrict__ ql,
    unsigned short* __restrict__ kh, unsigned short* __restrict__ kl,
    unsigned short* __restrict__ vh, unsigned short* __restrict__ vl)
{
    __shared__ unsigned short ahs[128][LP], als[128][LP];
    __shared__ unsigned short bhs[128][LP], bls[128][LP];
    int t = threadIdx.x;
    int l = t & 63, w = t >> 6;
    int lq = l & 31, hi = l >> 5;
    int wr = w >> 1, wc = w & 1;
    int col0 = blockIdx.x*128, row0 = blockIdx.y*128;

    int srow[2], scol[2], sa[2];
    #pragma unroll
    for (int i = 0; i < 2; i++){
        int idx = i*256 + t;
        srow[i] = idx >> 2;
        scol[i] = (idx & 3) * 8;
        int ar = row0 + srow[i]; if (ar >= M_ROWS) ar = M_ROWS-1;
        sa[i] = ar;
    }

    f32x16_t acc[2][2];
    #pragma unroll
    for (int i = 0; i < 16; i++){
        acc[0][0][i]=0.f; acc[0][1][i]=0.f; acc[1][0][i]=0.f; acc[1][1][i]=0.f;
    }

    for (int k0 = 0; k0 < NC; k0 += 32){
        if (k0) __syncthreads();
        #pragma unroll
        for (int i = 0; i < 2; i++){
            size_t ao = (size_t)sa[i]*NC + k0 + scol[i];
            size_t bo = (size_t)(col0 + srow[i])*NC + k0 + scol[i];
            u16x8_t va  = *(const u16x8_t*)(Ah + ao);
            u16x8_t va2 = *(const u16x8_t*)(Al + ao);
            u16x8_t vb  = *(const u16x8_t*)(Bh + bo);
            u16x8_t vb2 = *(const u16x8_t*)(Bl + bo);
            *(u16x8_t*)&ahs[srow[i]][scol[i]] = va;
            *(u16x8_t*)&als[srow[i]][scol[i]] = va2;
            *(u16x8_t*)&bhs[srow[i]][scol[i]] = vb;
            *(u16x8_t*)&bls[srow[i]][scol[i]] = vb2;
        }
        __syncthreads();
        #pragma unroll
        for (int kk = 0; kk < 2; kk++){
            int co = kk*16 + 8*hi;
            bf16x8_t a0h = *(const bf16x8_t*)&ahs[wr*64+lq][co];
            bf16x8_t a1h = *(const bf16x8_t*)&ahs[wr*64+32+lq][co];
            bf16x8_t b0h = *(const bf16x8_t*)&bhs[wc*64+lq][co];
            bf16x8_t b1h = *(const bf16x8_t*)&bhs[wc*64+32+lq][co];
            bf16x8_t a0l = *(const bf16x8_t*)&als[wr*64+lq][co];
            bf16x8_t a1l = *(const bf16x8_t*)&als[wr*64+32+lq][co];
            bf16x8_t b0l = *(const bf16x8_t*)&bls[wc*64+lq][co];
            bf16x8_t b1l = *(const bf16x8_t*)&bls[wc*64+32+lq][co];
            MFMA12(a0h,a1h,b0h,b1h,a0l,a1l,b0l,b1l)
        }
    }

    int colW = col0 + wc*64, rowW = row0 + wr*64;
    #pragma unroll
    for (int fn = 0; fn < 2; fn++){
        int colb = colW + fn*32 + lq;
        float bb = bias[colb];
        int tt = colb >> 10, h = (colb >> 6) & 15, d = colb & 63;
        unsigned short* dsth = (tt == 0) ? qh : (tt == 1 ? kh : vh);
        unsigned short* dstl = (tt == 0) ? ql : (tt == 1 ? kl : vl);
        #pragma unroll
        for (int fm = 0; fm < 2; fm++){
            #pragma unroll
            for (int r = 0; r < 16; r++){
                int orow = rowW + fm*32 + (r&3) + 8*(r>>2) + 4*hi;
                if (orow < M_ROWS){
                    float val = acc[fm][fn][r] + bb;
                    int b = orow / NTOK, n = orow % NTOK;
                    unsigned short hv = f2bf(val);
                    unsigned short lv = f2bf(val - bf2f(hv));
                    size_t idx = ((size_t)(b*NH + h)*NTOK + n)*HD + d;
                    dsth[idx] = hv; dstl[idx] = lv;
                }
            }
        }
    }
}

// ---------------------------------------------------------------------------
// proj GEMM, LDS-staged (64x128 tile, BK=32). A split bf16 in HEAD layout.
// NA=1: single A pair. NA=3: A = A0+A1+A2 (fp32 sum in staging) - fused sum3.
// ---------------------------------------------------------------------------
template<int NA>
__global__ __launch_bounds__(256) void gemm_proj_mfma(
    const unsigned short* __restrict__ A0h, const unsigned short* __restrict__ A0l,
    const unsigned short* __restrict__ A1h, const unsigned short* __restrict__ A1l,
    const unsigned short* __restrict__ A2h, const unsigned short* __restrict__ A2l,
    const unsigned short* __restrict__ Bh, const unsigned short* __restrict__ Bl,
    const float* __restrict__ bias, float alpha, float* __restrict__ out)
{
    __shared__ unsigned short ahs[64][LP], als[64][LP];
    __shared__ unsigned short bhs[128][LP], bls[128][LP];
    int t = threadIdx.x;
    int l = t & 63, w = t >> 6;
    int lq = l & 31, hi = l >> 5;
    int wr = w >> 1, wc = w & 1;
    int col0 = blockIdx.x*128, row0 = blockIdx.y*64;

    int sarow = t >> 2, sacol = (t & 3) * 8;
    int ar = row0 + sarow; if (ar >= M_ROWS) ar = M_ROWS-1;
    size_t abase = (size_t)(ar / NTOK)*NH*HSTR + (size_t)(ar % NTOK)*HD;
    int sbrow[2], sbcol[2];
    #pragma unroll
    for (int i = 0; i < 2; i++){
        int idx = i*256 + t;
        sbrow[i] = idx >> 2;
        sbcol[i] = (idx & 3) * 8;
    }

    f32x16_t acc[2];
    #pragma unroll
    for (int i = 0; i < 16; i++){ acc[0][i]=0.f; acc[1][i]=0.f; }

    for (int k0 = 0; k0 < NC; k0 += 32){
        if (k0) __syncthreads();
        {
            int kk = k0 + sacol;
            size_t ao = abase + (size_t)(kk >> 6)*HSTR + (kk & 63);
            U4 h0, l0;
            u16x8_t va  = *(const u16x8_t*)(A0h + ao);
            u16x8_t va2 = *(const u16x8_t*)(A0l + ao);
            if (NA == 3){
                u16x8_t vb  = *(const u16x8_t*)(A1h + ao);
                u16x8_t vb2 = *(const u16x8_t*)(A1l + ao);
                u16x8_t vc  = *(const u16x8_t*)(A2h + ao);
                u16x8_t vc2 = *(const u16x8_t*)(A2l + ao);
                #pragma unroll
                for (int j = 0; j < 8; j++){
                    float s = bf2f(va[j]) + bf2f(va2[j]) + bf2f(vb[j])
                            + bf2f(vb2[j]) + bf2f(vc[j]) + bf2f(vc2[j]);
                    unsigned short hv = f2bf(s);
                    h0.s[j] = hv; l0.s[j] = f2bf(s - bf2f(hv));
                }
                *(u16x8_t*)&ahs[sarow][sacol] = (u16x8_t)h0.v;
                *(u16x8_t*)&als[sarow][sacol] = (u16x8_t)l0.v;
            } else {
                *(u16x8_t*)&ahs[sarow][sacol] = va;
                *(u16x8_t*)&als[sarow][sacol] = va2;
            }
            #pragma unroll
            for (int i = 0; i < 2; i++){
                size_t bo = (size_t)(col0 + sbrow[i])*NC + k0 + sbcol[i];
                u16x8_t vb  = *(const u16x8_t*)(Bh + bo);
                u16x8_t vb2 = *(const u16x8_t*)(Bl + bo);
                *(u16x8_t*)&bhs[sbrow[i]][sbcol[i]] = vb;
                *(u16x8_t*)&bls[sbrow[i]][sbcol[i]] = vb2;
            }
        }
        __syncthreads();
        #pragma unroll
        for (int kk = 0; kk < 2; kk++){
            int co = kk*16 + 8*hi;
            bf16x8_t a0h = *(const bf16x8_t*)&ahs[wr*32+lq][co];
            bf16x8_t a0l = *(const bf16x8_t*)&als[wr*32+lq][co];
            bf16x8_t b0h = *(const bf16x8_t*)&bhs[wc*64+lq][co];
            bf16x8_t b1h = *(const bf16x8_t*)&bhs[wc*64+32+lq][co];
            bf16x8_t b0l = *(const bf16x8_t*)&bls[wc*64+lq][co];
            bf16x8_t b1l = *(const bf16x8_t*)&bls[wc*64+32+lq][co];
            acc[0] = __builtin_amdgcn_mfma_f32_32x32x16_bf16(a0h, b0h, acc[0], 0,0,0);
            acc[1] = __builtin_amdgcn_mfma_f32_32x32x16_bf16(a0h, b1h, acc[1], 0,0,0);
            acc[0] = __builtin_amdgcn_mfma_f32_32x32x16_bf16(a0h, b0l, acc[0], 0,0,0);
            acc[1] = __builtin_amdgcn_mfma_f32_32x32x16_bf16(a0h, b1l, acc[1], 0,0,0);
            acc[0] = __builtin_amdgcn_mfma_f32_32x32x16_bf16(a0l, b0h, acc[0], 0,0,0);
            acc[1] = __builtin_amdgcn_mfma_f32_32x32x16_bf16(a0l, b1h, acc[1], 0,0,0);
        }
    }

    #pragma unroll
    for (int fn = 0; fn < 2; fn++){
        int colb = col0 + wc*64 + fn*32 + lq;
        float bb = bias[colb];
        #pragma unroll
        for (int r = 0; r < 16; r++){
            int orow = row0 + wr*32 + (r&3) + 8*(r>>2) + 4*hi;
            if (orow < M_ROWS){
                int b = orow / NTOK, n = orow % NTOK;
                out[((size_t)n*NB + b)*NC + colb] = alpha*acc[fn][r] + bb;
            }
        }
    }
}

// ---------------------------------------------------------------------------
// Flash inner body, no LDS, hi-only scores everywhere (inputs either
// l2-normalized or within error budget). VAR=0: online softmax + 1/l (x_ori).
// VAR=1: static max (=scale) + fused output-l2n, hi-only output.
// VAR=2: static max + 1/l, split output.
// ---------------------------------------------------------------------------
template<int VAR>
__device__ __forceinline__ void flash_body(
    const unsigned short* Qh, const unsigned short* Kh,
    const unsigned short* VT,
    unsigned short* Ohi, unsigned short* Olo,
    float scale, int bh, int qt, int lane)
{
    int hi = lane >> 5, lq = lane & 31;
    const size_t base = (size_t)bh * NTOK * HD;
    const size_t vtb  = (size_t)bh * HD * VTW;

    int qrow = qt*32 + lq;
    int qr = qrow < NTOK ? qrow : NTOK-1;
    const size_t qoff = base + (size_t)qr*HD + 8*hi;
    bf16x8_t qfh[4];
    #pragma unroll
    for (int c = 0; c < 4; c++)
        qfh[c] = *(const bf16x8_t*)(Qh + qoff + 16*c);

    f32x16_t od0, od1;
    #pragma unroll
    for (int r = 0; r < 16; r++){ od0[r]=0.f; od1[r]=0.f; }
    float m_ = -1e30f, l_ = 0.f;

    for (int kt = 0; kt < 19; kt++){
        int krow = kt*32 + lq;
        int kr = krow < NTOK ? krow : NTOK-1;
        const size_t koff = base + (size_t)kr*HD + 8*hi;
        bf16x8_t kfh[4];
        #pragma unroll
        for (int c = 0; c < 4; c++)
            kfh[c] = *(const bf16x8_t*)(Kh + koff + 16*c);
        f32x16_t sf;
        #pragma unroll
        for (int r = 0; r < 16; r++) sf[r] = 0.f;
        __builtin_amdgcn_s_setprio(1);
        #pragma unroll
        for (int c = 0; c < 4; c++)
            sf = __builtin_amdgcn_mfma_f32_32x32x16_bf16(kfh[c], qfh[c], sf, 0,0,0);
        __builtin_amdgcn_s_setprio(0);

        float p[16];
        if (VAR == 0){
            float tm = -1e30f;
            if (kt == 18){
                #pragma unroll
                for (int r = 0; r < 16; r++){
                    int key = 576 + (r&3) + 8*(r>>2) + 4*hi;
                    p[r] = (key < NTOK) ? sf[r]*scale : -1e30f;
                    tm = fmaxf(tm, p[r]);
                }
            } else {
                #pragma unroll
                for (int r = 0; r < 16; r++){ p[r] = sf[r]*scale; tm = fmaxf(tm, p[r]); }
            }
            tm = fmaxf(tm, __shfl_xor(tm, 32));
            float mn = fmaxf(m_, tm);
            float corr = __expf(m_ - mn);
            float ps = 0.f;
            #pragma unroll
            for (int r = 0; r < 16; r++){ p[r] = __expf(p[r] - mn); ps += p[r]; }
            ps += __shfl_xor(ps, 32);
            l_ = l_*corr + ps;
            m_ = mn;
            #pragma unroll
            for (int r = 0; r < 16; r++){
                int crow = (r&3) + 8*(r>>2) + 4*hi;
                float cR = __shfl(corr, crow);
                od0[r] *= cR; od1[r] *= cR;
            }
        } else {
            // static max == scale (row max is the diagonal, exactly scale)
            if (kt == 18){
                #pragma unroll
                for (int r = 0; r < 16; r++){
                    int key = 576 + (r&3) + 8*(r>>2) + 4*hi;
                    p[r] = (key < NTOK) ? __expf(sf[r]*scale - scale) : 0.f;
                }
            } else {
                #pragma unroll
                for (int r = 0; r < 16; r++) p[r] = __expf(sf[r]*scale - scale);
            }
            if (VAR == 2){
                #pragma unroll
                for (int r = 0; r < 16; r++) l_ += p[r];
            }
        }

        U4 pa[2];
        #pragma unroll
        for (int ks = 0; ks < 2; ks++){
            unsigned int X0 = cvt_pk(p[8*ks+0], p[8*ks+1]);
            unsigned int X1 = cvt_pk(p[8*ks+2], p[8*ks+3]);
            unsigned int X2 = cvt_pk(p[8*ks+4], p[8*ks+5]);
            unsigned int X3 = cvt_pk(p[8*ks+6], p[8*ks+7]);
            unsigned int Y0 = (unsigned int)__shfl_xor((int)X2, 32);
            unsigned int Y1 = (unsigned int)__shfl_xor((int)X3, 32);
            unsigned int Y2 = (unsigned int)__shfl_xor((int)X0, 32);
            unsigned int Y3 = (unsigned int)__shfl_xor((int)X1, 32);
            pa[ks].u[0] = hi ? Y0 : X0;
            pa[ks].u[1] = hi ? Y1 : X1;
            pa[ks].u[2] = hi ? X2 : Y2;
            pa[ks].u[3] = hi ? X3 : Y3;
        }
        const size_t v0 = vtb + (size_t)lq*VTW      + kt*32 + 8*hi;
        const size_t v1 = vtb + (size_t)(32+lq)*VTW + kt*32 + 8*hi;
        bf16x8_t vf00 = *(const bf16x8_t*)(VT + v0);
        bf16x8_t vf01 = *(const bf16x8_t*)(VT + v0 + 16);
        bf16x8_t vf10 = *(const bf16x8_t*)(VT + v1);
        bf16x8_t vf11 = *(const bf16x8_t*)(VT + v1 + 16);
        __builtin_amdgcn_s_setprio(1);
        od0 = __builtin_amdgcn_mfma_f32_32x32x16_bf16(pa[0].v, vf00, od0, 0,0,0);
        od0 = __builtin_amdgcn_mfma_f32_32x32x16_bf16(pa[1].v, vf01, od0, 0,0,0);
        od1 = __builtin_amdgcn_mfma_f32_32x32x16_bf16(pa[0].v, vf10, od1, 0,0,0);
        od1 = __builtin_amdgcn_mfma_f32_32x32x16_bf16(pa[1].v, vf11, od1, 0,0,0);
        __builtin_amdgcn_s_setprio(0);
    }

    if (VAR == 1){
        // fused l2n: z = od/||od|| per row (1/l cancels); hi-only output
        #pragma unroll
        for (int r = 0; r < 16; r++){
            float s = od0[r]*od0[r] + od1[r]*od1[r];
            #pragma unroll
            for (int o = 1; o < 32; o <<= 1) s += __shfl_xor(s, o);
            int crow = (r&3) + 8*(r>>2) + 4*hi;
            int qg = qt*32 + crow;
            if (qg < NTOK){
                float inv = 1.f / fmaxf(sqrtf(s), 1e-12f);
                size_t o0 = base + (size_t)qg*HD + lq;
                Ohi[o0]    = f2bf(od0[r]*inv);
                Ohi[o0+32] = f2bf(od1[r]*inv);
            }
        }
        return;
    }

    if (VAR == 2) l_ = l_ + __shfl_xor(l_, 32);
    float linv = 1.f / l_;
    #pragma unroll
    for (int r = 0; r < 16; r++){
        int crow = (r&3) + 8*(r>>2) + 4*hi;
        int qg = qt*32 + crow;
        float li = __shfl(linv, crow);
        if (qg < NTOK){
            size_t o0 = base + (size_t)qg*HD + lq;
            float a0 = od0[r]*li, a1 = od1[r]*li;
            unsigned short h0 = f2bf(a0), h1 = f2bf(a1);
            Ohi[o0] = h0;    Olo[o0]    = f2bf(a0 - bf2f(h0));
            Ohi[o0+32] = h1; Olo[o0+32] = f2bf(a1 - bf2f(h1));
        }
    }
}

// Batched: 3 independent self-attentions (Q=K), slice = blockIdx.y.
template<int VAR>
__global__ __launch_bounds__(256) void flash2b(
    const unsigned short* __restrict__ q0h,
    const unsigned short* __restrict__ q1h,
    const unsigned short* __restrict__ q2h,
    const unsigned short* __restrict__ vt0, const unsigned short* __restrict__ vt1,
    const unsigned short* __restrict__ vt2,
    unsigned short* __restrict__ o0h, unsigned short* __restrict__ o0l,
    unsigned short* __restrict__ o1h, unsigned short* __restrict__ o1l,
    unsigned short* __restrict__ o2h, unsigned short* __restrict__ o2l,
    const float* __restrict__ itemp)
{
    int w = threadIdx.x >> 6, lane = threadIdx.x & 63;
    int bid = blockIdx.x;
    int bh = (bid & 7) * 16 + (bid >> 3) / 5;
    int qt = ((bid >> 3) % 5) * 4 + w;
    if (qt >= 19) return;
    int i = blockIdx.y;
    const unsigned short *Qh, *VT;
    unsigned short *Oh, *Ol;
    if (i == 0){ Qh=q0h; VT=vt0; Oh=o0h; Ol=o0l; }
    else if (i == 1){ Qh=q1h; VT=vt1; Oh=o1h; Ol=o1l; }
    else { Qh=q2h; VT=vt2; Oh=o2h; Ol=o2l; }
    flash_body<VAR>(Qh, Qh, VT, Oh, Ol, itemp[bh >> 4], bh, qt, lane);
}

// 4-wide merged: slices 0-2 = ys_i (VAR=1, fused l2n -> z_i, hi-only out);
// slice 3 = x_ori attention (VAR=0) -> o_ori (split out).
__global__ __launch_bounds__(256) void flash4(
    const unsigned short* __restrict__ x1h,
    const unsigned short* __restrict__ x2h,
    const unsigned short* __restrict__ x3h,
    const unsigned short* __restrict__ qh_,
    const unsigned short* __restrict__ kh_,
    const unsigned short* __restrict__ vt1, const unsigned short* __restrict__ vt2,
    const unsigned short* __restrict__ vt3, const unsigned short* __restrict__ vtv,
    unsigned short* __restrict__ z1h,
    unsigned short* __restrict__ z2h,
    unsigned short* __restrict__ z3h,
    unsigned short* __restrict__ ooh, unsigned short* __restrict__ ool,
    const float* __restrict__ itemp)
{
    int w = threadIdx.x >> 6, lane = threadIdx.x & 63;
    int bid = blockIdx.x;
    int bh = (bid & 7) * 16 + (bid >> 3) / 5;
    int qt = ((bid >> 3) % 5) * 4 + w;
    if (qt >= 19) return;
    int i = blockIdx.y;
    if (i == 3){
        flash_body<0>(qh_, kh_, vtv, ooh, ool, 0.125f, bh, qt, lane);
    } else {
        const unsigned short *Qh, *VT;
        unsigned short *Oh;
        if (i == 0){ Qh=x1h; VT=vt1; Oh=z1h; }
        else if (i == 1){ Qh=x2h; VT=vt2; Oh=z2h; }
        else { Qh=x3h; VT=vt3; Oh=z3h; }
        flash_body<1>(Qh, Qh, VT, Oh, nullptr, itemp[bh >> 4], bh, qt, lane);
    }
}

// ---------------------------------------------------------------------------
__global__ __launch_bounds__(256) void row_norm(const float* __restrict__ X,
                                                float* __restrict__ rn)
{
    int id = blockIdx.x;
    int b = id / NTOK, n = id % NTOK;
    const float* src = X + ((size_t)n*NB + b)*NC;
    int tid = threadIdx.x;
    float s = 0.f;
    for (int i = tid; i < NC; i += 256) { float t = src[i]; s += t*t; }
    #pragma unroll
    for (int o = 1; o < 64; o <<= 1) s += __shfl_xor(s, o);
    __shared__ float red[4];
    if ((tid & 63) == 0) red[tid >> 6] = s;
    __syncthreads();
    if (tid == 0) rn[id] = sqrtf(red[0] + red[1] + red[2] + red[3]);
}

__global__ __launch_bounds__(256) void calc_invtemp(const float* __restrict__ rn,
                                                    float* __restrict__ it)
{
    int b = blockIdx.x;
    int tid = threadIdx.x;
    float s = 0.f;
    for (int i = tid; i < NTOK; i += 256) s += rn[b*NTOK + i];
    #pragma unroll
    for (int o = 1; o < 64; o <<= 1) s += __shfl_xor(s, o);
    __shared__ float red[4];
    if ((tid & 63) == 0) red[tid >> 6] = s;
    __syncthreads();
    if (tid == 0) it[b] = (red[0]+red[1]+red[2]+red[3]) / (float)NTOK * 0.125f;
}

// ---------------------------------------------------------------------------
// 3-slice L2-normalize (rows of 64, split in -> split out). In-place safe.
// ---------------------------------------------------------------------------
__device__ __forceinline__ void l2n_body(const unsigned short* ih,
        const unsigned short* il, unsigned short* oh, unsigned short* ol)
{
    size_t row = (size_t)blockIdx.x*4 + (threadIdx.x >> 6);
    int lane = threadIdx.x & 63;
    size_t ii = row*HD + lane;
    float x = bf2f(ih[ii]) + bf2f(il[ii]);
    float s = x*x;
    #pragma unroll
    for (int o = 1; o < 64; o <<= 1) s += __shfl_xor(s, o);
    float xn = x / fmaxf(sqrtf(s), 1e-12f);
    unsigned short hv = f2bf(xn);
    oh[ii] = hv;
    ol[ii] = f2bf(xn - bf2f(hv));
}

__global__ __launch_bounds__(256) void l2n_s2s(const unsigned short* __restrict__ ih,
        const unsigned short* __restrict__ il,
        unsigned short* __restrict__ oh, unsigned short* __restrict__ ol)
{
    l2n_body(ih, il, oh, ol);
}

__global__ __launch_bounds__(256) void l2n3(
    const unsigned short* __restrict__ i0h, const unsigned short* __restrict__ i0l,
    unsigned short* __restrict__ o0h, unsigned short* __restrict__ o0l,
    const unsigned short* __restrict__ i1h, const unsigned short* __restrict__ i1l,
    unsigned short* __restrict__ o1h, unsigned short* __restrict__ o1l,
    const unsigned short* __restrict__ i2h, const unsigned short* __restrict__ i2l,
    unsigned short* __restrict__ o2h, unsigned short* __restrict__ o2l)
{
    int i = blockIdx.y;
    if (i == 0) l2n_body(i0h, i0l, o0h, o0l);
    else if (i == 1) l2n_body(i1h, i1l, o1h, o1l);
    else l2n_body(i2h, i2l, o2h, o2l);
}

// ---------------------------------------------------------------------------
extern "C" void kernel_launch(void* const* d_in, const int* in_sizes, int n_in,
                              void* d_out, int out_size, void* d_ws, size_t ws_size,
                              hipStream_t stream)
{
    const float* x      = (const float*)d_in[0];
    const float* qkv_w  = (const float*)d_in[1];
    const float* qkv_b  = (const float*)d_in[2];
    const float* proj_w = (const float*)d_in[3];
    const float* proj_b = (const float*)d_in[4];
    float* out = (float*)d_out;            // [0,SZ)=x_gem, [SZ,2SZ)=x_ori

    unsigned short* w16 = (unsigned short*)d_ws;
    #define SL(i) (w16 + (size_t)(i)*SZ)          // 8 bf16 slots
    unsigned short* WQh = w16 + 8*SZ;             // WQ, dead after qkv
    unsigned short* WQl = WQh + WSZ;
    unsigned short* VT1 = WQh;                    // aliases WQ
    size_t p = 8*SZ + 2*WSZ;
    unsigned short* VTv = w16 + p;  p += VTSZ;
    unsigned short* VT2 = w16 + p;  p += VTSZ;
    unsigned short* VT3 = w16 + p;  p += VTSZ;
    unsigned short* WPh = w16 + p;  p += PSZ;
    unsigned short* WPl = w16 + p;  p += PSZ;
    unsigned short* E0  = w16 + p;  p += SZ;
    unsigned short* E1  = w16 + p;  p += SZ;
    float* rn = (float*)(w16 + p);  p += 2*(M_ROWS + 8);
    float* it = rn + M_ROWS;
    size_t need3 = p * sizeof(unsigned short);    // 3-wide batched layout
    unsigned short* F0 = w16 + p;  p += SZ;       // merged4-only
    unsigned short* F1 = w16 + p;  p += SZ;
    unsigned short* G0 = w16 + p;  p += SZ;
    unsigned short* G1 = w16 + p;  p += SZ;
    size_t need4 = p * sizeof(unsigned short);    // 4-wide merged layout
    int merged4  = (ws_size >= need4);
    int batched3 = (ws_size >= need3);

    unsigned short* S0 = (unsigned short*)d_out;  // x_gem bytes (scratch pair)
    unsigned short* S1 = S0 + SZ;
    unsigned short* T0 = S0 + 2*SZ;               // x_ori bytes (scratch pair)
    unsigned short* T1 = S0 + 3*SZ;

    dim3 blk(256);
    dim3 gq(24,37), gp(8,73), gflb(640,3), gfl4(640,4), gt(10,128);
    dim3 gt3(10,128,3), gl3(18464,3);

    // prologue: inv_temp, merged splits, qkv gemm, VTv
    row_norm<<<dim3(M_ROWS), blk, 0, stream>>>(x, rn);
    calc_invtemp<<<dim3(NB), blk, 0, stream>>>(rn, it);
    split_x_w<<<dim3(M_ROWS + 3*NC), blk, 0, stream>>>(x, qkv_w,
        SL(6), SL(7), WQh, WQl);
    gemm_qkv_mfma<<<gq, blk, 0, stream>>>(SL(6), SL(7), WQh, WQl, qkv_b,
        SL(0), SL(1), SL(2), SL(3), SL(4), SL(5));
    transp64<<<gt, blk, 0, stream>>>(SL(4), VTv);

    if (merged4){
        // xs1 = l2n(v) in-place (4,5); xs2 = l2n(k)->(6,7); xs3 = l2n(q)->E
        l2n3<<<gl3, blk, 0, stream>>>(
            SL(4),SL(5), SL(4),SL(5),
            SL(2),SL(3), SL(6),SL(7),
            SL(0),SL(1), E0,E1);
        transp64x3<<<gt3, blk, 0, stream>>>(SL(4), VT1, SL(6), VT2, E0, VT3);
        split_rows<<<dim3(NC), blk, 0, stream>>>(proj_w, WPh, WPl);
        // merged: z1->T0, z2->F0, z3->G0 (hi only), o_ori->S pair
        flash4<<<gfl4, blk, 0, stream>>>(
            SL(4), SL(6), E0,
            SL(0), SL(2),
            VT1, VT2, VT3, VTv,
            T0, F0, G0, S0,S1, it);
        // finals: z (hi) x VTv -> (4,5),(6,7),E split
        flash2b<2><<<gflb, blk, 0, stream>>>(
            T0, F0, G0,
            VTv, VTv, VTv,
            SL(4),SL(5), SL(6),SL(7), E0,E1, it);
        // proj_ori (reads S=o_ori, writes out x_ori region = T bytes)
        gemm_proj_mfma<1><<<gp, blk, 0, stream>>>(S0,S1, S0,S1, S0,S1,
            WPh,WPl, proj_b, 1.f, out + SZ);
        // proj_gem with fused sum3 (reads 3 pairs, writes S region)
        gemm_proj_mfma<3><<<gp, blk, 0, stream>>>(SL(4),SL(5), SL(6),SL(7),
            E0,E1, WPh,WPl, proj_b, 1.f/3.f, out);
    } else if (batched3){
        // 3-wide path (no F/G): x_ori via flash2b slice trick not possible;
        // use flash4-less sequence with flash2b<1> then finals.
        // x_ori first: single-slice via flash2b<0>? keep a dedicated launch:
        flash4<<<dim3(640,1,1), blk, 0, stream>>>(   // only slice 3 semantics
            SL(4), SL(6), E0, SL(0), SL(2),
            VTv, VTv, VTv, VTv,
            T0, F0, G0, SL(6),SL(7), it);            // unused slices see valid ptrs
        // NOTE: grid y=1 -> only slice 0 runs (VAR=1 on xs1 not yet built),
        // so instead fall through to safe serial-ish path below.
        // To stay safe, run the proven 3-wide schedule:
        split_rows<<<dim3(NC), blk, 0, stream>>>(proj_w, WPh, WPl);
        // x_ori with online softmax: use flash2b<0>-style via flash4 slice 3:
        // (launch with y offset not available; use dedicated flash4 grid (640,4)
        //  would need F/G. Use serial flash: reuse flash2b<2> on q? Not exact.)
        // Simplest correct: full serial fallback below.
        batched3 = 0;
    }
    if (!merged4 && !batched3){
        // serial fallback: x_ori then sequential ys/z/finals (hi-only scores)
        unsigned short* VTx = WQh;
        split_rows<<<dim3(NC), blk, 0, stream>>>(proj_w, WPh, WPl);
        // x_ori: flash4 slice-3 behavior via 1-slice launch trick is not
        // available; emulate with flash2b<2>? scores unbounded -> need VAR=0.
        // Launch flash4 with full 4-slice grid but dummy-but-valid slice ptrs:
        // xs slices read SL(4)/SL(6)/E0 BEFORE l2n (contents = raw v/k-copy),
        // outputs T0,F0,G0 are scratch; slice 3 computes o_ori correctly.
        l2n_s2s<<<dim3(18464), blk, 0, stream>>>(SL(4),SL(5), SL(6),SL(7));
        transp64<<<gt, blk, 0, stream>>>(SL(6), VTx);
        flash4<<<gfl4, blk, 0, stream>>>(
            SL(6), SL(6), SL(6), SL(0), SL(2),
            VTx, VTx, VTx, VTv,
            T0, F0, G0, S0,S1, it);   // T/F/G scratch; S = o_ori
        gemm_proj_mfma<1><<<gp, blk, 0, stream>>>(S0,S1, S0,S1, S0,S1,
            WPh,WPl, proj_b, 1.f, out + SZ);
        // ys1 on xs1=(6,7): reuse T0 as z1 (hi)
        flash2b<1><<<dim3(640,1), blk, 0, stream>>>(
            SL(6), SL(6), SL(6), VTx, VTx, VTx,
            T0, T1, T0, T1, T0, T1, it);
        // xs2 = l2n(k) in place, ys2 -> F0; xs3 = l2n(q), ys3 -> G0
        l2n_s2s<<<dim3(18464), blk, 0, stream>>>(SL(2),SL(3), SL(2),SL(3));
        transp64<<<gt, blk, 0, stream>>>(SL(2), VTx);
        flash2b<1><<<dim3(640,1), blk, 0, stream>>>(
            SL(2), SL(2), SL(2), VTx, VTx, VTx,
            F0, F1, F0, F1, F0, F1, it);
        l2n_s2s<<<dim3(18464), blk, 0, stream>>>(SL(0),SL(1), SL(0),SL(1));
        transp64<<<gt, blk, 0, stream>>>(SL(0), VTx);
        flash2b<1><<<dim3(640,1), blk, 0, stream>>>(
            SL(0), SL(0), SL(0), VTx, VTx, VTx,
            G0, G1, G0, G1, G0, G1, it);
        // finals 3-wide + fused-sum3 proj
        flash2b<2><<<gflb, blk, 0, stream>>>(
            T0, F0, G0, VTv, VTv, VTv,
            SL(4),SL(5), SL(6),SL(7), E0,E1, it);
        gemm_proj_mfma<3><<<gp, blk, 0, stream>>>(SL(4),SL(5), SL(6),SL(7),
            E0,E1, WPh,WPl, proj_b, 1.f/3.f, out);
    }
    #undef SL
}

// Round 17
// 564.291 us; speedup vs baseline: 1.7464x; 1.0894x over previous
//
#include <hip/hip_runtime.h>
#include <math.h>

#define NTOK 577
#define NB 8
#define NC 1024
#define NH 16
#define HD 64
#define M_ROWS (NB*NTOK)               // 4616
#define SZ ((size_t)NB*NH*NTOK*HD)     // 4726784 elements
#define WSZ ((size_t)3*NC*NC)          // 3145728
#define PSZ ((size_t)NC*NC)            // 1048576
#define VTW 608                        // padded key width for VT (19*32)
#define VTSZ ((size_t)NB*NH*HD*VTW)    // 4980736
#define HSTR ((size_t)NTOK*HD)         // 36928 head stride in A-layout
#define LP 36                          // padded LDS row (32 data + 4 pad)

typedef __attribute__((ext_vector_type(8)))  short bf16x8_t;
typedef __attribute__((ext_vector_type(8)))  unsigned short u16x8_t;
typedef __attribute__((ext_vector_type(16))) float f32x16_t;

union U4 { unsigned short s[8]; unsigned int u[4]; bf16x8_t v; };

__device__ inline unsigned short f2bf(float x){
    unsigned int u = __float_as_uint(x);
    u = (u + 0x7FFFu + ((u>>16)&1u)) >> 16;
    return (unsigned short)u;
}
__device__ inline float bf2f(unsigned short h){
    return __uint_as_float(((unsigned int)h)<<16);
}
__device__ inline unsigned int cvt_pk(float a, float b){
    unsigned int r;
    asm volatile("v_cvt_pk_bf16_f32 %0, %1, %2" : "=v"(r) : "v"(a), "v"(b));
    return r;
}

// ---------------------------------------------------------------------------
// merged split + fused row-norm:
// rows 0..4615: X [N,B,C] gather -> (xh,xl) + rn[row] = ||x_row||
// rows 4616..7687: qkv_w row-major -> wh (hi only)
// ---------------------------------------------------------------------------
__global__ __launch_bounds__(256) void split_x_w(const float* __restrict__ X,
        const float* __restrict__ W,
        unsigned short* __restrict__ xh, unsigned short* __restrict__ xl,
        unsigned short* __restrict__ wh, float* __restrict__ rn)
{
    int row = blockIdx.x, t = threadIdx.x;
    if (row < M_ROWS){
        int b = row / NTOK, n = row % NTOK;
        const float* s = X + ((size_t)n*NB + b)*NC + 4*t;
        float4 v = *(const float4*)s;
        ushort4 hv, lv;
        hv.x = f2bf(v.x); lv.x = f2bf(v.x - bf2f(hv.x));
        hv.y = f2bf(v.y); lv.y = f2bf(v.y - bf2f(hv.y));
        hv.z = f2bf(v.z); lv.z = f2bf(v.z - bf2f(hv.z));
        hv.w = f2bf(v.w); lv.w = f2bf(v.w - bf2f(hv.w));
        *(ushort4*)(xh + (size_t)row*NC + 4*t) = hv;
        *(ushort4*)(xl + (size_t)row*NC + 4*t) = lv;
        float ss = v.x*v.x + v.y*v.y + v.z*v.z + v.w*v.w;
        #pragma unroll
        for (int o = 1; o < 64; o <<= 1) ss += __shfl_xor(ss, o);
        __shared__ float red[4];
        if ((t & 63) == 0) red[t >> 6] = ss;
        __syncthreads();
        if (t == 0) rn[row] = sqrtf(red[0] + red[1] + red[2] + red[3]);
    } else {
        size_t drow = row - M_ROWS;
        const float* s = W + drow*NC + 4*t;
        float4 v = *(const float4*)s;
        ushort4 hv;
        hv.x = f2bf(v.x); hv.y = f2bf(v.y); hv.z = f2bf(v.z); hv.w = f2bf(v.w);
        *(ushort4*)(wh + drow*NC + 4*t) = hv;
    }
}

// hi-only weight split (proj_w)
__global__ __launch_bounds__(256) void split_w(const float* __restrict__ src,
        unsigned short* __restrict__ dh)
{
    int row = blockIdx.x, t = threadIdx.x;
    float4 v = *(const float4*)(src + (size_t)row*NC + 4*t);
    ushort4 hv;
    hv.x = f2bf(v.x); hv.y = f2bf(v.y); hv.z = f2bf(v.z); hv.w = f2bf(v.w);
    *(ushort4*)(dh + (size_t)row*NC + 4*t) = hv;
}

// ---------------------------------------------------------------------------
// Coalesced transpose: src hi-bf16 [BH][577][64] -> dst [BH][64][608], pads=0.
// ---------------------------------------------------------------------------
__device__ __forceinline__ void transp_body(const unsigned short* src,
                                            unsigned short* dst)
{
    __shared__ unsigned short t[64][72];
    int bh = blockIdx.y;
    int n0 = blockIdx.x * 64;
    int tid = threadIdx.x;
    int r  = tid >> 2;
    int c0 = (tid & 3) * 16;
    int n = n0 + r;
    if (n < NTOK){
        const unsigned short* s = src + ((size_t)bh*NTOK + n)*HD + c0;
        *(u16x8_t*)&t[r][c0]   = *(const u16x8_t*)s;
        *(u16x8_t*)&t[r][c0+8] = *(const u16x8_t*)(s + 8);
    } else {
        u16x8_t z = (u16x8_t)0;
        *(u16x8_t*)&t[r][c0]   = z;
        *(u16x8_t*)&t[r][c0+8] = z;
    }
    __syncthreads();
    if (n0 + c0 < VTW){
        int d = r;
        U4 o0, o1;
        #pragma unroll
        for (int j = 0; j < 8; j++){ o0.s[j] = t[c0+j][d]; o1.s[j] = t[c0+8+j][d]; }
        unsigned short* dp = dst + ((size_t)bh*HD + d)*VTW + n0 + c0;
        *(u16x8_t*)dp       = (u16x8_t)o0.v;
        *(u16x8_t*)(dp + 8) = (u16x8_t)o1.v;
    }
}

__global__ __launch_bounds__(256) void transp64(const unsigned short* __restrict__ src,
                                                unsigned short* __restrict__ dst)
{
    transp_body(src, dst);
}

__global__ __launch_bounds__(256) void transp64x3(
    const unsigned short* __restrict__ s0, unsigned short* __restrict__ d0,
    const unsigned short* __restrict__ s1, unsigned short* __restrict__ d1,
    const unsigned short* __restrict__ s2, unsigned short* __restrict__ d2)
{
    int i = blockIdx.z;
    const unsigned short* s = (i == 0) ? s0 : (i == 1 ? s1 : s2);
    unsigned short* d = (i == 0) ? d0 : (i == 1 ? d1 : d2);
    transp_body(s, d);
}

// A split bf16x2, B hi-only: 8 MFMAs per kk (hh + lh)
#define MFMA8(a0h,a1h,b0,b1,a0l,a1l) \
    acc[0][0] = __builtin_amdgcn_mfma_f32_32x32x16_bf16(a0h, b0, acc[0][0], 0,0,0); \
    acc[0][1] = __builtin_amdgcn_mfma_f32_32x32x16_bf16(a0h, b1, acc[0][1], 0,0,0); \
    acc[1][0] = __builtin_amdgcn_mfma_f32_32x32x16_bf16(a1h, b0, acc[1][0], 0,0,0); \
    acc[1][1] = __builtin_amdgcn_mfma_f32_32x32x16_bf16(a1h, b1, acc[1][1], 0,0,0); \
    acc[0][0] = __builtin_amdgcn_mfma_f32_32x32x16_bf16(a0l, b0, acc[0][0], 0,0,0); \
    acc[0][1] = __builtin_amdgcn_mfma_f32_32x32x16_bf16(a0l, b1, acc[0][1], 0,0,0); \
    acc[1][0] = __builtin_amdgcn_mfma_f32_32x32x16_bf16(a1l, b0, acc[1][0], 0,0,0); \
    acc[1][1] = __builtin_amdgcn_mfma_f32_32x32x16_bf16(a1l, b1, acc[1][1], 0,0,0);

// ---------------------------------------------------------------------------
// qkv GEMM, LDS-staged (128x128 tile, BK=32). A = X split bf16x2, B = W hi.
// ---------------------------------------------------------------------------
__global__ __launch_bounds__(256) void gemm_qkv_mfma(
    const unsigned short* __restrict__ Ah, const unsigned short* __restrict__ Al,
    const unsigned short* __restrict__ Bh,
    const float* __restrict__ bias,
    unsigned short* __restrict__ qh, unsigned short* __restrict__ ql,
    unsigned short* __restrict__ kh, unsigned short* __restrict__ kl,
    unsigned short* __restrict__ vh, unsigned short* __restrict__ vl)
{
    __shared__ unsigned short ahs[128][LP], als[128][LP];
    __shared__ unsigned short bhs[128][LP];
    int t = threadIdx.x;
    int l = t & 63, w = t >> 6;
    int lq = l & 31, hi = l >> 5;
    int wr = w >> 1, wc = w & 1;
    int col0 = blockIdx.x*128, row0 = blockIdx.y*128;

    int srow[2], scol[2], sa[2];
    #pragma unroll
    for (int i = 0; i < 2; i++){
        int idx = i*256 + t;
        srow[i] = idx >> 2;
        scol[i] = (idx & 3) * 8;
        int ar = row0 + srow[i]; if (ar >= M_ROWS) ar = M_ROWS-1;
        sa[i] = ar;
    }

    f32x16_t acc[2][2];
    #pragma unroll
    for (int i = 0; i < 16; i++){
        acc[0][0][i]=0.f; acc[0][1][i]=0.f; acc[1][0][i]=0.f; acc[1][1][i]=0.f;
    }

    for (int k0 = 0; k0 < NC; k0 += 32){
        if (k0) __syncthreads();
        #pragma unroll
        for (int i = 0; i < 2; i++){
            size_t ao = (size_t)sa[i]*NC + k0 + scol[i];
            size_t bo = (size_t)(col0 + srow[i])*NC + k0 + scol[i];
            u16x8_t va  = *(const u16x8_t*)(Ah + ao);
            u16x8_t va2 = *(const u16x8_t*)(Al + ao);
            u16x8_t vb  = *(const u16x8_t*)(Bh + bo);
            *(u16x8_t*)&ahs[srow[i]][scol[i]] = va;
            *(u16x8_t*)&als[srow[i]][scol[i]] = va2;
            *(u16x8_t*)&bhs[srow[i]][scol[i]] = vb;
        }
        __syncthreads();
        #pragma unroll
        for (int kk = 0; kk < 2; kk++){
            int co = kk*16 + 8*hi;
            bf16x8_t a0h = *(const bf16x8_t*)&ahs[wr*64+lq][co];
            bf16x8_t a1h = *(const bf16x8_t*)&ahs[wr*64+32+lq][co];
            bf16x8_t b0  = *(const bf16x8_t*)&bhs[wc*64+lq][co];
            bf16x8_t b1  = *(const bf16x8_t*)&bhs[wc*64+32+lq][co];
            bf16x8_t a0l = *(const bf16x8_t*)&als[wr*64+lq][co];
            bf16x8_t a1l = *(const bf16x8_t*)&als[wr*64+32+lq][co];
            MFMA8(a0h,a1h,b0,b1,a0l,a1l)
        }
    }

    int colW = col0 + wc*64, rowW = row0 + wr*64;
    #pragma unroll
    for (int fn = 0; fn < 2; fn++){
        int colb = colW + fn*32 + lq;
        float bb = bias[colb];
        int tt = colb >> 10, h = (colb >> 6) & 15, d = colb & 63;
        unsigned short* dsth = (tt == 0) ? qh : (tt == 1 ? kh : vh);
        unsigned short* dstl = (tt == 0) ? ql : (tt == 1 ? kl : vl);
        #pragma unroll
        for (int fm = 0; fm < 2; fm++){
            #pragma unroll
            for (int r = 0; r < 16; r++){
                int orow = rowW + fm*32 + (r&3) + 8*(r>>2) + 4*hi;
                if (orow < M_ROWS){
                    float val = acc[fm][fn][r] + bb;
                    int b = orow / NTOK, n = orow % NTOK;
                    unsigned short hv = f2bf(val);
                    unsigned short lv = f2bf(val - bf2f(hv));
                    size_t idx = ((size_t)(b*NH + h)*NTOK + n)*HD + d;
                    dsth[idx] = hv; dstl[idx] = lv;
                }
            }
        }
    }
}

// ---------------------------------------------------------------------------
// proj GEMM, LDS-staged (64x128 tile, BK=32). A split bf16x2 HEAD layout,
// B = proj_w hi-only. NA=1 single A pair; NA=3 fused sum of 3 pairs.
// ---------------------------------------------------------------------------
template<int NA>
__global__ __launch_bounds__(256) void gemm_proj_mfma(
    const unsigned short* __restrict__ A0h, const unsigned short* __restrict__ A0l,
    const unsigned short* __restrict__ A1h, const unsigned short* __restrict__ A1l,
    const unsigned short* __restrict__ A2h, const unsigned short* __restrict__ A2l,
    const unsigned short* __restrict__ Bh,
    const float* __restrict__ bias, float alpha, float* __restrict__ out)
{
    __shared__ unsigned short ahs[64][LP], als[64][LP];
    __shared__ unsigned short bhs[128][LP];
    int t = threadIdx.x;
    int l = t & 63, w = t >> 6;
    int lq = l & 31, hi = l >> 5;
    int wr = w >> 1, wc = w & 1;
    int col0 = blockIdx.x*128, row0 = blockIdx.y*64;

    int sarow = t >> 2, sacol = (t & 3) * 8;
    int ar = row0 + sarow; if (ar >= M_ROWS) ar = M_ROWS-1;
    size_t abase = (size_t)(ar / NTOK)*NH*HSTR + (size_t)(ar % NTOK)*HD;
    int sbrow[2], sbcol[2];
    #pragma unroll
    for (int i = 0; i < 2; i++){
        int idx = i*256 + t;
        sbrow[i] = idx >> 2;
        sbcol[i] = (idx & 3) * 8;
    }

    f32x16_t acc[2];
    #pragma unroll
    for (int i = 0; i < 16; i++){ acc[0][i]=0.f; acc[1][i]=0.f; }

    for (int k0 = 0; k0 < NC; k0 += 32){
        if (k0) __syncthreads();
        {
            int kk = k0 + sacol;
            size_t ao = abase + (size_t)(kk >> 6)*HSTR + (kk & 63);
            U4 h0, l0;
            u16x8_t va  = *(const u16x8_t*)(A0h + ao);
            u16x8_t va2 = *(const u16x8_t*)(A0l + ao);
            if (NA == 3){
                u16x8_t vb  = *(const u16x8_t*)(A1h + ao);
                u16x8_t vb2 = *(const u16x8_t*)(A1l + ao);
                u16x8_t vc  = *(const u16x8_t*)(A2h + ao);
                u16x8_t vc2 = *(const u16x8_t*)(A2l + ao);
                #pragma unroll
                for (int j = 0; j < 8; j++){
                    float s = bf2f(va[j]) + bf2f(va2[j]) + bf2f(vb[j])
                            + bf2f(vb2[j]) + bf2f(vc[j]) + bf2f(vc2[j]);
                    unsigned short hv = f2bf(s);
                    h0.s[j] = hv; l0.s[j] = f2bf(s - bf2f(hv));
                }
                *(u16x8_t*)&ahs[sarow][sacol] = (u16x8_t)h0.v;
                *(u16x8_t*)&als[sarow][sacol] = (u16x8_t)l0.v;
            } else {
                *(u16x8_t*)&ahs[sarow][sacol] = va;
                *(u16x8_t*)&als[sarow][sacol] = va2;
            }
            #pragma unroll
            for (int i = 0; i < 2; i++){
                size_t bo = (size_t)(col0 + sbrow[i])*NC + k0 + sbcol[i];
                u16x8_t vb = *(const u16x8_t*)(Bh + bo);
                *(u16x8_t*)&bhs[sbrow[i]][sbcol[i]] = vb;
            }
        }
        __syncthreads();
        #pragma unroll
        for (int kk = 0; kk < 2; kk++){
            int co = kk*16 + 8*hi;
            bf16x8_t a0h = *(const bf16x8_t*)&ahs[wr*32+lq][co];
            bf16x8_t a0l = *(const bf16x8_t*)&als[wr*32+lq][co];
            bf16x8_t b0  = *(const bf16x8_t*)&bhs[wc*64+lq][co];
            bf16x8_t b1  = *(const bf16x8_t*)&bhs[wc*64+32+lq][co];
            acc[0] = __builtin_amdgcn_mfma_f32_32x32x16_bf16(a0h, b0, acc[0], 0,0,0);
            acc[1] = __builtin_amdgcn_mfma_f32_32x32x16_bf16(a0h, b1, acc[1], 0,0,0);
            acc[0] = __builtin_amdgcn_mfma_f32_32x32x16_bf16(a0l, b0, acc[0], 0,0,0);
            acc[1] = __builtin_amdgcn_mfma_f32_32x32x16_bf16(a0l, b1, acc[1], 0,0,0);
        }
    }

    #pragma unroll
    for (int fn = 0; fn < 2; fn++){
        int colb = col0 + wc*64 + fn*32 + lq;
        float bb = bias[colb];
        #pragma unroll
        for (int r = 0; r < 16; r++){
            int orow = row0 + wr*32 + (r&3) + 8*(r>>2) + 4*hi;
            if (orow < M_ROWS){
                int b = orow / NTOK, n = orow % NTOK;
                out[((size_t)n*NB + b)*NC + colb] = alpha*acc[fn][r] + bb;
            }
        }
    }
}

// ---------------------------------------------------------------------------
// Flash inner body, no LDS, hi-only scores. VAR=0: online softmax + 1/l.
// VAR=1: static max (=scale) + fused output-l2n, hi-only output.
// VAR=2: static max + 1/l, split output.
// ---------------------------------------------------------------------------
template<int VAR>
__device__ __forceinline__ void flash_body(
    const unsigned short* Qh, const unsigned short* Kh,
    const unsigned short* VT,
    unsigned short* Ohi, unsigned short* Olo,
    float scale, int bh, int qt, int lane)
{
    int hi = lane >> 5, lq = lane & 31;
    const size_t base = (size_t)bh * NTOK * HD;
    const size_t vtb  = (size_t)bh * HD * VTW;

    int qrow = qt*32 + lq;
    int qr = qrow < NTOK ? qrow : NTOK-1;
    const size_t qoff = base + (size_t)qr*HD + 8*hi;
    bf16x8_t qfh[4];
    #pragma unroll
    for (int c = 0; c < 4; c++)
        qfh[c] = *(const bf16x8_t*)(Qh + qoff + 16*c);

    f32x16_t od0, od1;
    #pragma unroll
    for (int r = 0; r < 16; r++){ od0[r]=0.f; od1[r]=0.f; }
    float m_ = -1e30f, l_ = 0.f;

    for (int kt = 0; kt < 19; kt++){
        int krow = kt*32 + lq;
        int kr = krow < NTOK ? krow : NTOK-1;
        const size_t koff = base + (size_t)kr*HD + 8*hi;
        bf16x8_t kfh[4];
        #pragma unroll
        for (int c = 0; c < 4; c++)
            kfh[c] = *(const bf16x8_t*)(Kh + koff + 16*c);
        f32x16_t sf;
        #pragma unroll
        for (int r = 0; r < 16; r++) sf[r] = 0.f;
        __builtin_amdgcn_s_setprio(1);
        #pragma unroll
        for (int c = 0; c < 4; c++)
            sf = __builtin_amdgcn_mfma_f32_32x32x16_bf16(kfh[c], qfh[c], sf, 0,0,0);
        __builtin_amdgcn_s_setprio(0);

        float p[16];
        if (VAR == 0){
            float tm = -1e30f;
            if (kt == 18){
                #pragma unroll
                for (int r = 0; r < 16; r++){
                    int key = 576 + (r&3) + 8*(r>>2) + 4*hi;
                    p[r] = (key < NTOK) ? sf[r]*scale : -1e30f;
                    tm = fmaxf(tm, p[r]);
                }
            } else {
                #pragma unroll
                for (int r = 0; r < 16; r++){ p[r] = sf[r]*scale; tm = fmaxf(tm, p[r]); }
            }
            tm = fmaxf(tm, __shfl_xor(tm, 32));
            float mn = fmaxf(m_, tm);
            float corr = __expf(m_ - mn);
            float ps = 0.f;
            #pragma unroll
            for (int r = 0; r < 16; r++){ p[r] = __expf(p[r] - mn); ps += p[r]; }
            ps += __shfl_xor(ps, 32);
            l_ = l_*corr + ps;
            m_ = mn;
            #pragma unroll
            for (int r = 0; r < 16; r++){
                int crow = (r&3) + 8*(r>>2) + 4*hi;
                float cR = __shfl(corr, crow);
                od0[r] *= cR; od1[r] *= cR;
            }
        } else {
            if (kt == 18){
                #pragma unroll
                for (int r = 0; r < 16; r++){
                    int key = 576 + (r&3) + 8*(r>>2) + 4*hi;
                    p[r] = (key < NTOK) ? __expf(sf[r]*scale - scale) : 0.f;
                }
            } else {
                #pragma unroll
                for (int r = 0; r < 16; r++) p[r] = __expf(sf[r]*scale - scale);
            }
            if (VAR == 2){
                #pragma unroll
                for (int r = 0; r < 16; r++) l_ += p[r];
            }
        }

        U4 pa[2];
        #pragma unroll
        for (int ks = 0; ks < 2; ks++){
            unsigned int X0 = cvt_pk(p[8*ks+0], p[8*ks+1]);
            unsigned int X1 = cvt_pk(p[8*ks+2], p[8*ks+3]);
            unsigned int X2 = cvt_pk(p[8*ks+4], p[8*ks+5]);
            unsigned int X3 = cvt_pk(p[8*ks+6], p[8*ks+7]);
            unsigned int Y0 = (unsigned int)__shfl_xor((int)X2, 32);
            unsigned int Y1 = (unsigned int)__shfl_xor((int)X3, 32);
            unsigned int Y2 = (unsigned int)__shfl_xor((int)X0, 32);
            unsigned int Y3 = (unsigned int)__shfl_xor((int)X1, 32);
            pa[ks].u[0] = hi ? Y0 : X0;
            pa[ks].u[1] = hi ? Y1 : X1;
            pa[ks].u[2] = hi ? X2 : Y2;
            pa[ks].u[3] = hi ? X3 : Y3;
        }
        const size_t v0 = vtb + (size_t)lq*VTW      + kt*32 + 8*hi;
        const size_t v1 = vtb + (size_t)(32+lq)*VTW + kt*32 + 8*hi;
        bf16x8_t vf00 = *(const bf16x8_t*)(VT + v0);
        bf16x8_t vf01 = *(const bf16x8_t*)(VT + v0 + 16);
        bf16x8_t vf10 = *(const bf16x8_t*)(VT + v1);
        bf16x8_t vf11 = *(const bf16x8_t*)(VT + v1 + 16);
        __builtin_amdgcn_s_setprio(1);
        od0 = __builtin_amdgcn_mfma_f32_32x32x16_bf16(pa[0].v, vf00, od0, 0,0,0);
        od0 = __builtin_amdgcn_mfma_f32_32x32x16_bf16(pa[1].v, vf01, od0, 0,0,0);
        od1 = __builtin_amdgcn_mfma_f32_32x32x16_bf16(pa[0].v, vf10, od1, 0,0,0);
        od1 = __builtin_amdgcn_mfma_f32_32x32x16_bf16(pa[1].v, vf11, od1, 0,0,0);
        __builtin_amdgcn_s_setprio(0);
    }

    if (VAR == 1){
        #pragma unroll
        for (int r = 0; r < 16; r++){
            float s = od0[r]*od0[r] + od1[r]*od1[r];
            #pragma unroll
            for (int o = 1; o < 32; o <<= 1) s += __shfl_xor(s, o);
            int crow = (r&3) + 8*(r>>2) + 4*hi;
            int qg = qt*32 + crow;
            if (qg < NTOK){
                float inv = 1.f / fmaxf(sqrtf(s), 1e-12f);
                size_t o0 = base + (size_t)qg*HD + lq;
                Ohi[o0]    = f2bf(od0[r]*inv);
                Ohi[o0+32] = f2bf(od1[r]*inv);
            }
        }
        return;
    }

    if (VAR == 2) l_ = l_ + __shfl_xor(l_, 32);
    float linv = 1.f / l_;
    #pragma unroll
    for (int r = 0; r < 16; r++){
        int crow = (r&3) + 8*(r>>2) + 4*hi;
        int qg = qt*32 + crow;
        float li = __shfl(linv, crow);
        if (qg < NTOK){
            size_t o0 = base + (size_t)qg*HD + lq;
            float a0 = od0[r]*li, a1 = od1[r]*li;
            unsigned short h0 = f2bf(a0), h1 = f2bf(a1);
            Ohi[o0] = h0;    Olo[o0]    = f2bf(a0 - bf2f(h0));
            Ohi[o0+32] = h1; Olo[o0+32] = f2bf(a1 - bf2f(h1));
        }
    }
}

// Batched: 3 independent self-attentions (Q=K), slice = blockIdx.y.
template<int VAR>
__global__ __launch_bounds__(256) void flash2b(
    const unsigned short* __restrict__ q0h,
    const unsigned short* __restrict__ q1h,
    const unsigned short* __restrict__ q2h,
    const unsigned short* __restrict__ vt0, const unsigned short* __restrict__ vt1,
    const unsigned short* __restrict__ vt2,
    unsigned short* __restrict__ o0h, unsigned short* __restrict__ o0l,
    unsigned short* __restrict__ o1h, unsigned short* __restrict__ o1l,
    unsigned short* __restrict__ o2h, unsigned short* __restrict__ o2l,
    const float* __restrict__ itemp)
{
    int w = threadIdx.x >> 6, lane = threadIdx.x & 63;
    int bid = blockIdx.x;
    int bh = (bid & 7) * 16 + (bid >> 3) / 5;
    int qt = ((bid >> 3) % 5) * 4 + w;
    if (qt >= 19) return;
    int i = blockIdx.y;
    const unsigned short *Qh, *VT;
    unsigned short *Oh, *Ol;
    if (i == 0){ Qh=q0h; VT=vt0; Oh=o0h; Ol=o0l; }
    else if (i == 1){ Qh=q1h; VT=vt1; Oh=o1h; Ol=o1l; }
    else { Qh=q2h; VT=vt2; Oh=o2h; Ol=o2l; }
    flash_body<VAR>(Qh, Qh, VT, Oh, Ol, itemp[bh >> 4], bh, qt, lane);
}

// 4-wide merged: slices 0-2 = ys_i (VAR=1, fused l2n -> z_i hi-only);
// slice 3 = x_ori attention (VAR=0) -> o_ori (split out).
__global__ __launch_bounds__(256) void flash4(
    const unsigned short* __restrict__ x1h,
    const unsigned short* __restrict__ x2h,
    const unsigned short* __restrict__ x3h,
    const unsigned short* __restrict__ qh_,
    const unsigned short* __restrict__ kh_,
    const unsigned short* __restrict__ vt1, const unsigned short* __restrict__ vt2,
    const unsigned short* __restrict__ vt3, const unsigned short* __restrict__ vtv,
    unsigned short* __restrict__ z1h,
    unsigned short* __restrict__ z2h,
    unsigned short* __restrict__ z3h,
    unsigned short* __restrict__ ooh, unsigned short* __restrict__ ool,
    const float* __restrict__ itemp)
{
    int w = threadIdx.x >> 6, lane = threadIdx.x & 63;
    int bid = blockIdx.x;
    int bh = (bid & 7) * 16 + (bid >> 3) / 5;
    int qt = ((bid >> 3) % 5) * 4 + w;
    if (qt >= 19) return;
    int i = blockIdx.y;
    if (i == 3){
        flash_body<0>(qh_, kh_, vtv, ooh, ool, 0.125f, bh, qt, lane);
    } else {
        const unsigned short *Qh, *VT;
        unsigned short *Oh;
        if (i == 0){ Qh=x1h; VT=vt1; Oh=z1h; }
        else if (i == 1){ Qh=x2h; VT=vt2; Oh=z2h; }
        else { Qh=x3h; VT=vt3; Oh=z3h; }
        flash_body<1>(Qh, Qh, VT, Oh, nullptr, itemp[bh >> 4], bh, qt, lane);
    }
}

// ---------------------------------------------------------------------------
__global__ __launch_bounds__(256) void calc_invtemp(const float* __restrict__ rn,
                                                    float* __restrict__ it)
{
    int b = blockIdx.x;
    int tid = threadIdx.x;
    float s = 0.f;
    for (int i = tid; i < NTOK; i += 256) s += rn[b*NTOK + i];
    #pragma unroll
    for (int o = 1; o < 64; o <<= 1) s += __shfl_xor(s, o);
    __shared__ float red[4];
    if ((tid & 63) == 0) red[tid >> 6] = s;
    __syncthreads();
    if (tid == 0) it[b] = (red[0]+red[1]+red[2]+red[3]) / (float)NTOK * 0.125f;
}

// ---------------------------------------------------------------------------
// 3-slice L2-normalize (rows of 64, split in -> split out). In-place safe.
// ---------------------------------------------------------------------------
__device__ __forceinline__ void l2n_body(const unsigned short* ih,
        const unsigned short* il, unsigned short* oh, unsigned short* ol)
{
    size_t row = (size_t)blockIdx.x*4 + (threadIdx.x >> 6);
    int lane = threadIdx.x & 63;
    size_t ii = row*HD + lane;
    float x = bf2f(ih[ii]) + bf2f(il[ii]);
    float s = x*x;
    #pragma unroll
    for (int o = 1; o < 64; o <<= 1) s += __shfl_xor(s, o);
    float xn = x / fmaxf(sqrtf(s), 1e-12f);
    unsigned short hv = f2bf(xn);
    oh[ii] = hv;
    ol[ii] = f2bf(xn - bf2f(hv));
}

__global__ __launch_bounds__(256) void l2n_s2s(const unsigned short* __restrict__ ih,
        const unsigned short* __restrict__ il,
        unsigned short* __restrict__ oh, unsigned short* __restrict__ ol)
{
    l2n_body(ih, il, oh, ol);
}

__global__ __launch_bounds__(256) void l2n3(
    const unsigned short* __restrict__ i0h, const unsigned short* __restrict__ i0l,
    unsigned short* __restrict__ o0h, unsigned short* __restrict__ o0l,
    const unsigned short* __restrict__ i1h, const unsigned short* __restrict__ i1l,
    unsigned short* __restrict__ o1h, unsigned short* __restrict__ o1l,
    const unsigned short* __restrict__ i2h, const unsigned short* __restrict__ i2l,
    unsigned short* __restrict__ o2h, unsigned short* __restrict__ o2l)
{
    int i = blockIdx.y;
    if (i == 0) l2n_body(i0h, i0l, o0h, o0l);
    else if (i == 1) l2n_body(i1h, i1l, o1h, o1l);
    else l2n_body(i2h, i2l, o2h, o2l);
}

// ---------------------------------------------------------------------------
extern "C" void kernel_launch(void* const* d_in, const int* in_sizes, int n_in,
                              void* d_out, int out_size, void* d_ws, size_t ws_size,
                              hipStream_t stream)
{
    const float* x      = (const float*)d_in[0];
    const float* qkv_w  = (const float*)d_in[1];
    const float* qkv_b  = (const float*)d_in[2];
    const float* proj_w = (const float*)d_in[3];
    const float* proj_b = (const float*)d_in[4];
    float* out = (float*)d_out;            // [0,SZ)=x_gem, [SZ,2SZ)=x_ori

    unsigned short* w16 = (unsigned short*)d_ws;
    #define SL(i) (w16 + (size_t)(i)*SZ)          // 8 bf16 slots
    unsigned short* WQh = w16 + 8*SZ;             // WQ hi, dead after qkv
    unsigned short* VT1 = WQh;                    // aliases WQ
    size_t p = 8*SZ + 2*WSZ;
    unsigned short* VTv = w16 + p;  p += VTSZ;
    unsigned short* VT2 = w16 + p;  p += VTSZ;
    unsigned short* VT3 = w16 + p;  p += VTSZ;
    unsigned short* WPh = w16 + p;  p += PSZ;
    unsigned short* WPl = w16 + p;  p += PSZ;     // unused (kept for layout)
    unsigned short* E0  = w16 + p;  p += SZ;
    unsigned short* E1  = w16 + p;  p += SZ;
    float* rn = (float*)(w16 + p);  p += 2*(M_ROWS + 8);
    float* it = rn + M_ROWS;
    unsigned short* F0 = w16 + p;  p += SZ;
    unsigned short* F1 = w16 + p;  p += SZ;
    unsigned short* G0 = w16 + p;  p += SZ;
    unsigned short* G1 = w16 + p;  p += SZ;
    size_t need4 = p * sizeof(unsigned short);
    int merged4  = (ws_size >= need4);

    unsigned short* S0 = (unsigned short*)d_out;  // x_gem bytes (scratch pair)
    unsigned short* S1 = S0 + SZ;
    unsigned short* T0 = S0 + 2*SZ;               // x_ori bytes (scratch pair)
    unsigned short* T1 = S0 + 3*SZ;

    dim3 blk(256);
    dim3 gq(24,37), gp(8,73), gflb(640,3), gfl4(640,4), gt(10,128);
    dim3 gt3(10,128,3), gl3(18464,3);

    // prologue: merged split + fused row-norm, inv_temp, qkv gemm, VTv
    split_x_w<<<dim3(M_ROWS + 3*NC), blk, 0, stream>>>(x, qkv_w,
        SL(6), SL(7), WQh, rn);
    calc_invtemp<<<dim3(NB), blk, 0, stream>>>(rn, it);
    gemm_qkv_mfma<<<gq, blk, 0, stream>>>(SL(6), SL(7), WQh, qkv_b,
        SL(0), SL(1), SL(2), SL(3), SL(4), SL(5));
    transp64<<<gt, blk, 0, stream>>>(SL(4), VTv);

    if (merged4){
        // xs1 = l2n(v) in-place (4,5); xs2 = l2n(k)->(6,7); xs3 = l2n(q)->E
        l2n3<<<gl3, blk, 0, stream>>>(
            SL(4),SL(5), SL(4),SL(5),
            SL(2),SL(3), SL(6),SL(7),
            SL(0),SL(1), E0,E1);
        transp64x3<<<gt3, blk, 0, stream>>>(SL(4), VT1, SL(6), VT2, E0, VT3);
        split_w<<<dim3(NC), blk, 0, stream>>>(proj_w, WPh);
        // merged: z1->T0, z2->F0, z3->G0 (hi only), o_ori->S pair
        flash4<<<gfl4, blk, 0, stream>>>(
            SL(4), SL(6), E0,
            SL(0), SL(2),
            VT1, VT2, VT3, VTv,
            T0, F0, G0, S0,S1, it);
        // finals: z (hi) x VTv -> (4,5),(6,7),E split
        flash2b<2><<<gflb, blk, 0, stream>>>(
            T0, F0, G0,
            VTv, VTv, VTv,
            SL(4),SL(5), SL(6),SL(7), E0,E1, it);
        // proj_ori (reads S=o_ori, writes x_ori = T bytes)
        gemm_proj_mfma<1><<<gp, blk, 0, stream>>>(S0,S1, S0,S1, S0,S1,
            WPh, proj_b, 1.f, out + SZ);
        // proj_gem with fused sum3 (reads 3 pairs, writes S region)
        gemm_proj_mfma<3><<<gp, blk, 0, stream>>>(SL(4),SL(5), SL(6),SL(7),
            E0,E1, WPh, proj_b, 1.f/3.f, out);
    } else {
        // serial fallback (hi-only scores; same kernels, sequential)
        unsigned short* VTx = WQh;
        split_w<<<dim3(NC), blk, 0, stream>>>(proj_w, WPh);
        l2n_s2s<<<dim3(18464), blk, 0, stream>>>(SL(4),SL(5), SL(6),SL(7));
        transp64<<<gt, blk, 0, stream>>>(SL(6), VTx);
        flash4<<<gfl4, blk, 0, stream>>>(
            SL(6), SL(6), SL(6), SL(0), SL(2),
            VTx, VTx, VTx, VTv,
            T0, F0, G0, S0,S1, it);   // T/F/G scratch; S = o_ori
        gemm_proj_mfma<1><<<gp, blk, 0, stream>>>(S0,S1, S0,S1, S0,S1,
            WPh, proj_b, 1.f, out + SZ);
        flash2b<1><<<dim3(640,1), blk, 0, stream>>>(
            SL(6), SL(6), SL(6), VTx, VTx, VTx,
            T0, T1, T0, T1, T0, T1, it);
        l2n_s2s<<<dim3(18464), blk, 0, stream>>>(SL(2),SL(3), SL(2),SL(3));
        transp64<<<gt, blk, 0, stream>>>(SL(2), VTx);
        flash2b<1><<<dim3(640,1), blk, 0, stream>>>(
            SL(2), SL(2), SL(2), VTx, VTx, VTx,
            F0, F1, F0, F1, F0, F1, it);
        l2n_s2s<<<dim3(18464), blk, 0, stream>>>(SL(0),SL(1), SL(0),SL(1));
        transp64<<<gt, blk, 0, stream>>>(SL(0), VTx);
        flash2b<1><<<dim3(640,1), blk, 0, stream>>>(
            SL(0), SL(0), SL(0), VTx, VTx, VTx,
            G0, G1, G0, G1, G0, G1, it);
        flash2b<2><<<gflb, blk, 0, stream>>>(
            T0, F0, G0, VTv, VTv, VTv,
            SL(4),SL(5), SL(6),SL(7), E0,E1, it);
        gemm_proj_mfma<3><<<gp, blk, 0, stream>>>(SL(4),SL(5), SL(6),SL(7),
            E0,E1, WPh, proj_b, 1.f/3.f, out);
    }
    #undef SL
}

// Round 18
// 542.857 us; speedup vs baseline: 1.8154x; 1.0395x over previous
//
#include <hip/hip_runtime.h>
#include <math.h>

#define NTOK 577
#define NB 8
#define NC 1024
#define NH 16
#define HD 64
#define M_ROWS (NB*NTOK)               // 4616
#define SZ ((size_t)NB*NH*NTOK*HD)     // 4726784 elements
#define WSZ ((size_t)3*NC*NC)          // 3145728
#define PSZ ((size_t)NC*NC)            // 1048576
#define VTW 608                        // padded key width for VT (19*32)
#define VTSZ ((size_t)NB*NH*HD*VTW)    // 4980736
#define HSTR ((size_t)NTOK*HD)         // 36928 head stride in A-layout
#define LP 36                          // padded LDS row (32 data + 4 pad)
#define LOG2E 1.44269504088896f

typedef __attribute__((ext_vector_type(8)))  short bf16x8_t;
typedef __attribute__((ext_vector_type(8)))  unsigned short u16x8_t;
typedef __attribute__((ext_vector_type(16))) float f32x16_t;

union U4 { unsigned short s[8]; unsigned int u[4]; bf16x8_t v; };

__device__ inline unsigned short f2bf(float x){
    unsigned int u = __float_as_uint(x);
    u = (u + 0x7FFFu + ((u>>16)&1u)) >> 16;
    return (unsigned short)u;
}
__device__ inline float bf2f(unsigned short h){
    return __uint_as_float(((unsigned int)h)<<16);
}
__device__ inline unsigned int cvt_pk(float a, float b){
    unsigned int r;
    asm volatile("v_cvt_pk_bf16_f32 %0, %1, %2" : "=v"(r) : "v"(a), "v"(b));
    return r;
}
__device__ inline float fexp2(float x){
    float r;
    asm("v_exp_f32 %0, %1" : "=v"(r) : "v"(x));
    return r;
}

// ---------------------------------------------------------------------------
// merged split + fused row-norm:
// rows 0..4615: X gather -> (xh,xl) + rn; 4616..7687: qkv_w -> wh (hi);
// rows 7688..8711: proj_w -> ph (hi)
// ---------------------------------------------------------------------------
__global__ __launch_bounds__(256) void split_all(const float* __restrict__ X,
        const float* __restrict__ W, const float* __restrict__ P,
        unsigned short* __restrict__ xh, unsigned short* __restrict__ xl,
        unsigned short* __restrict__ wh, unsigned short* __restrict__ ph,
        float* __restrict__ rn)
{
    int row = blockIdx.x, t = threadIdx.x;
    if (row < M_ROWS){
        int b = row / NTOK, n = row % NTOK;
        const float* s = X + ((size_t)n*NB + b)*NC + 4*t;
        float4 v = *(const float4*)s;
        ushort4 hv, lv;
        hv.x = f2bf(v.x); lv.x = f2bf(v.x - bf2f(hv.x));
        hv.y = f2bf(v.y); lv.y = f2bf(v.y - bf2f(hv.y));
        hv.z = f2bf(v.z); lv.z = f2bf(v.z - bf2f(hv.z));
        hv.w = f2bf(v.w); lv.w = f2bf(v.w - bf2f(hv.w));
        *(ushort4*)(xh + (size_t)row*NC + 4*t) = hv;
        *(ushort4*)(xl + (size_t)row*NC + 4*t) = lv;
        float ss = v.x*v.x + v.y*v.y + v.z*v.z + v.w*v.w;
        #pragma unroll
        for (int o = 1; o < 64; o <<= 1) ss += __shfl_xor(ss, o);
        __shared__ float red[4];
        if ((t & 63) == 0) red[t >> 6] = ss;
        __syncthreads();
        if (t == 0) rn[row] = sqrtf(red[0] + red[1] + red[2] + red[3]);
    } else if (row < M_ROWS + 3*NC){
        size_t drow = row - M_ROWS;
        float4 v = *(const float4*)(W + drow*NC + 4*t);
        ushort4 hv;
        hv.x = f2bf(v.x); hv.y = f2bf(v.y); hv.z = f2bf(v.z); hv.w = f2bf(v.w);
        *(ushort4*)(wh + drow*NC + 4*t) = hv;
    } else {
        size_t drow = row - M_ROWS - 3*NC;
        float4 v = *(const float4*)(P + drow*NC + 4*t);
        ushort4 hv;
        hv.x = f2bf(v.x); hv.y = f2bf(v.y); hv.z = f2bf(v.z); hv.w = f2bf(v.w);
        *(ushort4*)(ph + drow*NC + 4*t) = hv;
    }
}

// ---------------------------------------------------------------------------
// Coalesced transpose: src hi-bf16 [BH][577][64] -> dst [BH][64][608], pads=0.
// ---------------------------------------------------------------------------
__device__ __forceinline__ void transp_body(const unsigned short* src,
                                            unsigned short* dst)
{
    __shared__ unsigned short t[64][72];
    int bh = blockIdx.y;
    int n0 = blockIdx.x * 64;
    int tid = threadIdx.x;
    int r  = tid >> 2;
    int c0 = (tid & 3) * 16;
    int n = n0 + r;
    if (n < NTOK){
        const unsigned short* s = src + ((size_t)bh*NTOK + n)*HD + c0;
        *(u16x8_t*)&t[r][c0]   = *(const u16x8_t*)s;
        *(u16x8_t*)&t[r][c0+8] = *(const u16x8_t*)(s + 8);
    } else {
        u16x8_t z = (u16x8_t)0;
        *(u16x8_t*)&t[r][c0]   = z;
        *(u16x8_t*)&t[r][c0+8] = z;
    }
    __syncthreads();
    if (n0 + c0 < VTW){
        int d = r;
        U4 o0, o1;
        #pragma unroll
        for (int j = 0; j < 8; j++){ o0.s[j] = t[c0+j][d]; o1.s[j] = t[c0+8+j][d]; }
        unsigned short* dp = dst + ((size_t)bh*HD + d)*VTW + n0 + c0;
        *(u16x8_t*)dp       = (u16x8_t)o0.v;
        *(u16x8_t*)(dp + 8) = (u16x8_t)o1.v;
    }
}

__global__ __launch_bounds__(256) void transp64(const unsigned short* __restrict__ src,
                                                unsigned short* __restrict__ dst)
{
    transp_body(src, dst);
}

__global__ __launch_bounds__(256) void transp64x3(
    const unsigned short* __restrict__ s0, unsigned short* __restrict__ d0,
    const unsigned short* __restrict__ s1, unsigned short* __restrict__ d1,
    const unsigned short* __restrict__ s2, unsigned short* __restrict__ d2)
{
    int i = blockIdx.z;
    const unsigned short* s = (i == 0) ? s0 : (i == 1 ? s1 : s2);
    unsigned short* d = (i == 0) ? d0 : (i == 1 ? d1 : d2);
    transp_body(s, d);
}

// A split bf16x2, B hi-only: 8 MFMAs per kk (hh + lh)
#define MFMA8(a0h,a1h,b0,b1,a0l,a1l) \
    acc[0][0] = __builtin_amdgcn_mfma_f32_32x32x16_bf16(a0h, b0, acc[0][0], 0,0,0); \
    acc[0][1] = __builtin_amdgcn_mfma_f32_32x32x16_bf16(a0h, b1, acc[0][1], 0,0,0); \
    acc[1][0] = __builtin_amdgcn_mfma_f32_32x32x16_bf16(a1h, b0, acc[1][0], 0,0,0); \
    acc[1][1] = __builtin_amdgcn_mfma_f32_32x32x16_bf16(a1h, b1, acc[1][1], 0,0,0); \
    acc[0][0] = __builtin_amdgcn_mfma_f32_32x32x16_bf16(a0l, b0, acc[0][0], 0,0,0); \
    acc[0][1] = __builtin_amdgcn_mfma_f32_32x32x16_bf16(a0l, b1, acc[0][1], 0,0,0); \
    acc[1][0] = __builtin_amdgcn_mfma_f32_32x32x16_bf16(a1l, b0, acc[1][0], 0,0,0); \
    acc[1][1] = __builtin_amdgcn_mfma_f32_32x32x16_bf16(a1l, b1, acc[1][1], 0,0,0);

// ---------------------------------------------------------------------------
// qkv GEMM, LDS-staged (128x128 tile, BK=32). A = X split bf16x2, B = W hi.
// ---------------------------------------------------------------------------
__global__ __launch_bounds__(256) void gemm_qkv_mfma(
    const unsigned short* __restrict__ Ah, const unsigned short* __restrict__ Al,
    const unsigned short* __restrict__ Bh,
    const float* __restrict__ bias,
    unsigned short* __restrict__ qh, unsigned short* __restrict__ ql,
    unsigned short* __restrict__ kh, unsigned short* __restrict__ kl,
    unsigned short* __restrict__ vh, unsigned short* __restrict__ vl)
{
    __shared__ unsigned short ahs[128][LP], als[128][LP];
    __shared__ unsigned short bhs[128][LP];
    int t = threadIdx.x;
    int l = t & 63, w = t >> 6;
    int lq = l & 31, hi = l >> 5;
    int wr = w >> 1, wc = w & 1;
    int col0 = blockIdx.x*128, row0 = blockIdx.y*128;

    int srow[2], scol[2], sa[2];
    #pragma unroll
    for (int i = 0; i < 2; i++){
        int idx = i*256 + t;
        srow[i] = idx >> 2;
        scol[i] = (idx & 3) * 8;
        int ar = row0 + srow[i]; if (ar >= M_ROWS) ar = M_ROWS-1;
        sa[i] = ar;
    }

    f32x16_t acc[2][2];
    #pragma unroll
    for (int i = 0; i < 16; i++){
        acc[0][0][i]=0.f; acc[0][1][i]=0.f; acc[1][0][i]=0.f; acc[1][1][i]=0.f;
    }

    for (int k0 = 0; k0 < NC; k0 += 32){
        if (k0) __syncthreads();
        #pragma unroll
        for (int i = 0; i < 2; i++){
            size_t ao = (size_t)sa[i]*NC + k0 + scol[i];
            size_t bo = (size_t)(col0 + srow[i])*NC + k0 + scol[i];
            u16x8_t va  = *(const u16x8_t*)(Ah + ao);
            u16x8_t va2 = *(const u16x8_t*)(Al + ao);
            u16x8_t vb  = *(const u16x8_t*)(Bh + bo);
            *(u16x8_t*)&ahs[srow[i]][scol[i]] = va;
            *(u16x8_t*)&als[srow[i]][scol[i]] = va2;
            *(u16x8_t*)&bhs[srow[i]][scol[i]] = vb;
        }
        __syncthreads();
        #pragma unroll
        for (int kk = 0; kk < 2; kk++){
            int co = kk*16 + 8*hi;
            bf16x8_t a0h = *(const bf16x8_t*)&ahs[wr*64+lq][co];
            bf16x8_t a1h = *(const bf16x8_t*)&ahs[wr*64+32+lq][co];
            bf16x8_t b0  = *(const bf16x8_t*)&bhs[wc*64+lq][co];
            bf16x8_t b1  = *(const bf16x8_t*)&bhs[wc*64+32+lq][co];
            bf16x8_t a0l = *(const bf16x8_t*)&als[wr*64+lq][co];
            bf16x8_t a1l = *(const bf16x8_t*)&als[wr*64+32+lq][co];
            MFMA8(a0h,a1h,b0,b1,a0l,a1l)
        }
    }

    int colW = col0 + wc*64, rowW = row0 + wr*64;
    #pragma unroll
    for (int fn = 0; fn < 2; fn++){
        int colb = colW + fn*32 + lq;
        float bb = bias[colb];
        int tt = colb >> 10, h = (colb >> 6) & 15, d = colb & 63;
        unsigned short* dsth = (tt == 0) ? qh : (tt == 1 ? kh : vh);
        unsigned short* dstl = (tt == 0) ? ql : (tt == 1 ? kl : vl);
        #pragma unroll
        for (int fm = 0; fm < 2; fm++){
            #pragma unroll
            for (int r = 0; r < 16; r++){
                int orow = rowW + fm*32 + (r&3) + 8*(r>>2) + 4*hi;
                if (orow < M_ROWS){
                    float val = acc[fm][fn][r] + bb;
                    int b = orow / NTOK, n = orow % NTOK;
                    unsigned short hv = f2bf(val);
                    unsigned short lv = f2bf(val - bf2f(hv));
                    size_t idx = ((size_t)(b*NH + h)*NTOK + n)*HD + d;
                    dsth[idx] = hv; dstl[idx] = lv;
                }
            }
        }
    }
}

// ---------------------------------------------------------------------------
// proj GEMM body, LDS-staged (64x128 tile, BK=32). A split bf16x2 HEAD
// layout, B hi-only. NA=1 single A pair; NA=3 fused sum of 3 pairs.
// ---------------------------------------------------------------------------
template<int NA>
__device__ __forceinline__ void proj_body(
    const unsigned short* A0h, const unsigned short* A0l,
    const unsigned short* A1h, const unsigned short* A1l,
    const unsigned short* A2h, const unsigned short* A2l,
    const unsigned short* Bh,
    const float* bias, float alpha, float* out, int bx, int by)
{
    __shared__ unsigned short ahs[64][LP], als[64][LP];
    __shared__ unsigned short bhs[128][LP];
    int t = threadIdx.x;
    int l = t & 63, w = t >> 6;
    int lq = l & 31, hi = l >> 5;
    int wr = w >> 1, wc = w & 1;
    int col0 = bx*128, row0 = by*64;

    int sarow = t >> 2, sacol = (t & 3) * 8;
    int ar = row0 + sarow; if (ar >= M_ROWS) ar = M_ROWS-1;
    size_t abase = (size_t)(ar / NTOK)*NH*HSTR + (size_t)(ar % NTOK)*HD;
    int sbrow[2], sbcol[2];
    #pragma unroll
    for (int i = 0; i < 2; i++){
        int idx = i*256 + t;
        sbrow[i] = idx >> 2;
        sbcol[i] = (idx & 3) * 8;
    }

    f32x16_t acc[2];
    #pragma unroll
    for (int i = 0; i < 16; i++){ acc[0][i]=0.f; acc[1][i]=0.f; }

    for (int k0 = 0; k0 < NC; k0 += 32){
        if (k0) __syncthreads();
        {
            int kk = k0 + sacol;
            size_t ao = abase + (size_t)(kk >> 6)*HSTR + (kk & 63);
            U4 h0, l0;
            u16x8_t va  = *(const u16x8_t*)(A0h + ao);
            u16x8_t va2 = *(const u16x8_t*)(A0l + ao);
            if (NA == 3){
                u16x8_t vb  = *(const u16x8_t*)(A1h + ao);
                u16x8_t vb2 = *(const u16x8_t*)(A1l + ao);
                u16x8_t vc  = *(const u16x8_t*)(A2h + ao);
                u16x8_t vc2 = *(const u16x8_t*)(A2l + ao);
                #pragma unroll
                for (int j = 0; j < 8; j++){
                    float s = bf2f(va[j]) + bf2f(va2[j]) + bf2f(vb[j])
                            + bf2f(vb2[j]) + bf2f(vc[j]) + bf2f(vc2[j]);
                    unsigned short hv = f2bf(s);
                    h0.s[j] = hv; l0.s[j] = f2bf(s - bf2f(hv));
                }
                *(u16x8_t*)&ahs[sarow][sacol] = (u16x8_t)h0.v;
                *(u16x8_t*)&als[sarow][sacol] = (u16x8_t)l0.v;
            } else {
                *(u16x8_t*)&ahs[sarow][sacol] = va;
                *(u16x8_t*)&als[sarow][sacol] = va2;
            }
            #pragma unroll
            for (int i = 0; i < 2; i++){
                size_t bo = (size_t)(col0 + sbrow[i])*NC + k0 + sbcol[i];
                u16x8_t vb = *(const u16x8_t*)(Bh + bo);
                *(u16x8_t*)&bhs[sbrow[i]][sbcol[i]] = vb;
            }
        }
        __syncthreads();
        #pragma unroll
        for (int kk = 0; kk < 2; kk++){
            int co = kk*16 + 8*hi;
            bf16x8_t a0h = *(const bf16x8_t*)&ahs[wr*32+lq][co];
            bf16x8_t a0l = *(const bf16x8_t*)&als[wr*32+lq][co];
            bf16x8_t b0  = *(const bf16x8_t*)&bhs[wc*64+lq][co];
            bf16x8_t b1  = *(const bf16x8_t*)&bhs[wc*64+32+lq][co];
            acc[0] = __builtin_amdgcn_mfma_f32_32x32x16_bf16(a0h, b0, acc[0], 0,0,0);
            acc[1] = __builtin_amdgcn_mfma_f32_32x32x16_bf16(a0h, b1, acc[1], 0,0,0);
            acc[0] = __builtin_amdgcn_mfma_f32_32x32x16_bf16(a0l, b0, acc[0], 0,0,0);
            acc[1] = __builtin_amdgcn_mfma_f32_32x32x16_bf16(a0l, b1, acc[1], 0,0,0);
        }
    }

    #pragma unroll
    for (int fn = 0; fn < 2; fn++){
        int colb = col0 + wc*64 + fn*32 + lq;
        float bb = bias[colb];
        #pragma unroll
        for (int r = 0; r < 16; r++){
            int orow = row0 + wr*32 + (r&3) + 8*(r>>2) + 4*hi;
            if (orow < M_ROWS){
                int b = orow / NTOK, n = orow % NTOK;
                out[((size_t)n*NB + b)*NC + colb] = alpha*acc[fn][r] + bb;
            }
        }
    }
}

template<int NA>
__global__ __launch_bounds__(256) void gemm_proj_mfma(
    const unsigned short* __restrict__ A0h, const unsigned short* __restrict__ A0l,
    const unsigned short* __restrict__ A1h, const unsigned short* __restrict__ A1l,
    const unsigned short* __restrict__ A2h, const unsigned short* __restrict__ A2l,
    const unsigned short* __restrict__ Bh,
    const float* __restrict__ bias, float alpha, float* __restrict__ out)
{
    proj_body<NA>(A0h,A0l,A1h,A1l,A2h,A2l,Bh,bias,alpha,out,
                  blockIdx.x, blockIdx.y);
}

// ---------------------------------------------------------------------------
// Flash inner body, no LDS, hi-only scores, exp2-domain softmax.
// VAR=0: online softmax + 1/l. VAR=1: static max + fused output-l2n (hi out).
// VAR=2: static max + 1/l, split output.
// ---------------------------------------------------------------------------
template<int VAR>
__device__ __forceinline__ void flash_body(
    const unsigned short* Qh, const unsigned short* Kh,
    const unsigned short* VT,
    unsigned short* Ohi, unsigned short* Olo,
    float scale, int bh, int qt, int lane)
{
    int hi = lane >> 5, lq = lane & 31;
    const size_t base = (size_t)bh * NTOK * HD;
    const size_t vtb  = (size_t)bh * HD * VTW;
    const float l2s = scale * LOG2E;          // log2-domain scale

    int qrow = qt*32 + lq;
    int qr = qrow < NTOK ? qrow : NTOK-1;
    const size_t qoff = base + (size_t)qr*HD + 8*hi;
    bf16x8_t qfh[4];
    #pragma unroll
    for (int c = 0; c < 4; c++)
        qfh[c] = *(const bf16x8_t*)(Qh + qoff + 16*c);

    f32x16_t od0, od1;
    #pragma unroll
    for (int r = 0; r < 16; r++){ od0[r]=0.f; od1[r]=0.f; }
    float m_ = -1e30f, l_ = 0.f;

    for (int kt = 0; kt < 19; kt++){
        int krow = kt*32 + lq;
        int kr = krow < NTOK ? krow : NTOK-1;
        const size_t koff = base + (size_t)kr*HD + 8*hi;
        bf16x8_t kfh[4];
        #pragma unroll
        for (int c = 0; c < 4; c++)
            kfh[c] = *(const bf16x8_t*)(Kh + koff + 16*c);
        f32x16_t sf;
        #pragma unroll
        for (int r = 0; r < 16; r++) sf[r] = 0.f;
        __builtin_amdgcn_s_setprio(1);
        #pragma unroll
        for (int c = 0; c < 4; c++)
            sf = __builtin_amdgcn_mfma_f32_32x32x16_bf16(kfh[c], qfh[c], sf, 0,0,0);
        __builtin_amdgcn_s_setprio(0);

        float p[16];
        if (VAR == 0){
            // log2-domain online softmax (weights identical to base-e)
            float tm = -1e30f;
            if (kt == 18){
                #pragma unroll
                for (int r = 0; r < 16; r++){
                    int key = 576 + (r&3) + 8*(r>>2) + 4*hi;
                    p[r] = (key < NTOK) ? sf[r]*l2s : -1e30f;
                    tm = fmaxf(tm, p[r]);
                }
            } else {
                #pragma unroll
                for (int r = 0; r < 16; r++){ p[r] = sf[r]*l2s; tm = fmaxf(tm, p[r]); }
            }
            tm = fmaxf(tm, __shfl_xor(tm, 32));
            float mn = fmaxf(m_, tm);
            float corr = fexp2(m_ - mn);
            float ps = 0.f;
            #pragma unroll
            for (int r = 0; r < 16; r++){ p[r] = fexp2(p[r] - mn); ps += p[r]; }
            ps += __shfl_xor(ps, 32);
            l_ = l_*corr + ps;
            m_ = mn;
            #pragma unroll
            for (int r = 0; r < 16; r++){
                int crow = (r&3) + 8*(r>>2) + 4*hi;
                float cR = __shfl(corr, crow);
                od0[r] *= cR; od1[r] *= cR;
            }
        } else {
            // static max == scale (diagonal); p = 2^(S*l2s - l2s)
            if (kt == 18){
                #pragma unroll
                for (int r = 0; r < 16; r++){
                    int key = 576 + (r&3) + 8*(r>>2) + 4*hi;
                    p[r] = (key < NTOK) ? fexp2(sf[r]*l2s - l2s) : 0.f;
                }
            } else {
                #pragma unroll
                for (int r = 0; r < 16; r++) p[r] = fexp2(sf[r]*l2s - l2s);
            }
            if (VAR == 2){
                #pragma unroll
                for (int r = 0; r < 16; r++) l_ += p[r];
            }
        }

        U4 pa[2];
        #pragma unroll
        for (int ks = 0; ks < 2; ks++){
            unsigned int X0 = cvt_pk(p[8*ks+0], p[8*ks+1]);
            unsigned int X1 = cvt_pk(p[8*ks+2], p[8*ks+3]);
            unsigned int X2 = cvt_pk(p[8*ks+4], p[8*ks+5]);
            unsigned int X3 = cvt_pk(p[8*ks+6], p[8*ks+7]);
            unsigned int Y0 = (unsigned int)__shfl_xor((int)X2, 32);
            unsigned int Y1 = (unsigned int)__shfl_xor((int)X3, 32);
            unsigned int Y2 = (unsigned int)__shfl_xor((int)X0, 32);
            unsigned int Y3 = (unsigned int)__shfl_xor((int)X1, 32);
            pa[ks].u[0] = hi ? Y0 : X0;
            pa[ks].u[1] = hi ? Y1 : X1;
            pa[ks].u[2] = hi ? X2 : Y2;
            pa[ks].u[3] = hi ? X3 : Y3;
        }
        const size_t v0 = vtb + (size_t)lq*VTW      + kt*32 + 8*hi;
        const size_t v1 = vtb + (size_t)(32+lq)*VTW + kt*32 + 8*hi;
        bf16x8_t vf00 = *(const bf16x8_t*)(VT + v0);
        bf16x8_t vf01 = *(const bf16x8_t*)(VT + v0 + 16);
        bf16x8_t vf10 = *(const bf16x8_t*)(VT + v1);
        bf16x8_t vf11 = *(const bf16x8_t*)(VT + v1 + 16);
        __builtin_amdgcn_s_setprio(1);
        od0 = __builtin_amdgcn_mfma_f32_32x32x16_bf16(pa[0].v, vf00, od0, 0,0,0);
        od0 = __builtin_amdgcn_mfma_f32_32x32x16_bf16(pa[1].v, vf01, od0, 0,0,0);
        od1 = __builtin_amdgcn_mfma_f32_32x32x16_bf16(pa[0].v, vf10, od1, 0,0,0);
        od1 = __builtin_amdgcn_mfma_f32_32x32x16_bf16(pa[1].v, vf11, od1, 0,0,0);
        __builtin_amdgcn_s_setprio(0);
    }

    if (VAR == 1){
        #pragma unroll
        for (int r = 0; r < 16; r++){
            float s = od0[r]*od0[r] + od1[r]*od1[r];
            #pragma unroll
            for (int o = 1; o < 32; o <<= 1) s += __shfl_xor(s, o);
            int crow = (r&3) + 8*(r>>2) + 4*hi;
            int qg = qt*32 + crow;
            if (qg < NTOK){
                float inv = 1.f / fmaxf(sqrtf(s), 1e-12f);
                size_t o0 = base + (size_t)qg*HD + lq;
                Ohi[o0]    = f2bf(od0[r]*inv);
                Ohi[o0+32] = f2bf(od1[r]*inv);
            }
        }
        return;
    }

    if (VAR == 2) l_ = l_ + __shfl_xor(l_, 32);
    float linv = 1.f / l_;
    #pragma unroll
    for (int r = 0; r < 16; r++){
        int crow = (r&3) + 8*(r>>2) + 4*hi;
        int qg = qt*32 + crow;
        float li = __shfl(linv, crow);
        if (qg < NTOK){
            size_t o0 = base + (size_t)qg*HD + lq;
            float a0 = od0[r]*li, a1 = od1[r]*li;
            unsigned short h0 = f2bf(a0), h1 = f2bf(a1);
            Ohi[o0] = h0;    Olo[o0]    = f2bf(a0 - bf2f(h0));
            Ohi[o0+32] = h1; Olo[o0+32] = f2bf(a1 - bf2f(h1));
        }
    }
}

// Batched: 3 independent self-attentions (Q=K), slice = blockIdx.y.
template<int VAR>
__global__ __launch_bounds__(256) void flash2b(
    const unsigned short* __restrict__ q0h,
    const unsigned short* __restrict__ q1h,
    const unsigned short* __restrict__ q2h,
    const unsigned short* __restrict__ vt0, const unsigned short* __restrict__ vt1,
    const unsigned short* __restrict__ vt2,
    unsigned short* __restrict__ o0h, unsigned short* __restrict__ o0l,
    unsigned short* __restrict__ o1h, unsigned short* __restrict__ o1l,
    unsigned short* __restrict__ o2h, unsigned short* __restrict__ o2l,
    const float* __restrict__ itemp)
{
    int w = threadIdx.x >> 6, lane = threadIdx.x & 63;
    int bid = blockIdx.x;
    int bh = (bid & 7) * 16 + (bid >> 3) / 5;
    int qt = ((bid >> 3) % 5) * 4 + w;
    if (qt >= 19) return;
    int i = blockIdx.y;
    const unsigned short *Qh, *VT;
    unsigned short *Oh, *Ol;
    if (i == 0){ Qh=q0h; VT=vt0; Oh=o0h; Ol=o0l; }
    else if (i == 1){ Qh=q1h; VT=vt1; Oh=o1h; Ol=o1l; }
    else { Qh=q2h; VT=vt2; Oh=o2h; Ol=o2l; }
    flash_body<VAR>(Qh, Qh, VT, Oh, Ol, itemp[bh >> 4], bh, qt, lane);
}

// 4-wide merged ys+ori: slices 0-2 = ys_i (VAR=1, fused l2n, hi out);
// slice 3 = x_ori attention (VAR=0) -> o_ori (split out).
__global__ __launch_bounds__(256) void flash4(
    const unsigned short* __restrict__ x1h,
    const unsigned short* __restrict__ x2h,
    const unsigned short* __restrict__ x3h,
    const unsigned short* __restrict__ qh_,
    const unsigned short* __restrict__ kh_,
    const unsigned short* __restrict__ vt1, const unsigned short* __restrict__ vt2,
    const unsigned short* __restrict__ vt3, const unsigned short* __restrict__ vtv,
    unsigned short* __restrict__ z1h,
    unsigned short* __restrict__ z2h,
    unsigned short* __restrict__ z3h,
    unsigned short* __restrict__ ooh, unsigned short* __restrict__ ool,
    const float* __restrict__ itemp)
{
    int w = threadIdx.x >> 6, lane = threadIdx.x & 63;
    int bid = blockIdx.x;
    int bh = (bid & 7) * 16 + (bid >> 3) / 5;
    int qt = ((bid >> 3) % 5) * 4 + w;
    if (qt >= 19) return;
    int i = blockIdx.y;
    if (i == 3){
        flash_body<0>(qh_, kh_, vtv, ooh, ool, 0.125f, bh, qt, lane);
    } else {
        const unsigned short *Qh, *VT;
        unsigned short *Oh;
        if (i == 0){ Qh=x1h; VT=vt1; Oh=z1h; }
        else if (i == 1){ Qh=x2h; VT=vt2; Oh=z2h; }
        else { Qh=x3h; VT=vt3; Oh=z3h; }
        flash_body<1>(Qh, Qh, VT, Oh, nullptr, itemp[bh >> 4], bh, qt, lane);
    }
}

// Finals + proj_ori merged: slices 0-2 = final attentions (VAR=2);
// slice 3 = proj_ori GEMM (blocks 0..583 map to (8,73) grid).
__global__ __launch_bounds__(256) void flash_fin(
    const unsigned short* __restrict__ z1h,
    const unsigned short* __restrict__ z2h,
    const unsigned short* __restrict__ z3h,
    const unsigned short* __restrict__ vtv,
    unsigned short* __restrict__ o0h, unsigned short* __restrict__ o0l,
    unsigned short* __restrict__ o1h, unsigned short* __restrict__ o1l,
    unsigned short* __restrict__ o2h, unsigned short* __restrict__ o2l,
    const unsigned short* __restrict__ Oh, const unsigned short* __restrict__ Ol,
    const unsigned short* __restrict__ WPh,
    const float* __restrict__ proj_b, float* __restrict__ out_ori,
    const float* __restrict__ itemp)
{
    int i = blockIdx.y;
    if (i == 3){
        int bid = blockIdx.x;
        if (bid >= 584) return;
        proj_body<1>(Oh, Ol, Oh, Ol, Oh, Ol, WPh, proj_b, 1.f, out_ori,
                     bid & 7, bid >> 3);
        return;
    }
    int w = threadIdx.x >> 6, lane = threadIdx.x & 63;
    int bid = blockIdx.x;
    int bh = (bid & 7) * 16 + (bid >> 3) / 5;
    int qt = ((bid >> 3) % 5) * 4 + w;
    if (qt >= 19) return;
    const unsigned short *Qh;
    unsigned short *Ohh, *Oll;
    if (i == 0){ Qh=z1h; Ohh=o0h; Oll=o0l; }
    else if (i == 1){ Qh=z2h; Ohh=o1h; Oll=o1l; }
    else { Qh=z3h; Ohh=o2h; Oll=o2l; }
    flash_body<2>(Qh, Qh, vtv, Ohh, Oll, itemp[bh >> 4], bh, qt, lane);
}

// ---------------------------------------------------------------------------
__global__ __launch_bounds__(256) void calc_invtemp(const float* __restrict__ rn,
                                                    float* __restrict__ it)
{
    int b = blockIdx.x;
    int tid = threadIdx.x;
    float s = 0.f;
    for (int i = tid; i < NTOK; i += 256) s += rn[b*NTOK + i];
    #pragma unroll
    for (int o = 1; o < 64; o <<= 1) s += __shfl_xor(s, o);
    __shared__ float red[4];
    if ((tid & 63) == 0) red[tid >> 6] = s;
    __syncthreads();
    if (tid == 0) it[b] = (red[0]+red[1]+red[2]+red[3]) / (float)NTOK * 0.125f;
}

// ---------------------------------------------------------------------------
// L2-normalize (rows of 64, split in -> split out). In-place safe.
// ---------------------------------------------------------------------------
__device__ __forceinline__ void l2n_body(const unsigned short* ih,
        const unsigned short* il, unsigned short* oh, unsigned short* ol)
{
    size_t row = (size_t)blockIdx.x*4 + (threadIdx.x >> 6);
    int lane = threadIdx.x & 63;
    size_t ii = row*HD + lane;
    float x = bf2f(ih[ii]) + bf2f(il[ii]);
    float s = x*x;
    #pragma unroll
    for (int o = 1; o < 64; o <<= 1) s += __shfl_xor(s, o);
    float xn = x / fmaxf(sqrtf(s), 1e-12f);
    unsigned short hv = f2bf(xn);
    oh[ii] = hv;
    ol[ii] = f2bf(xn - bf2f(hv));
}

__global__ __launch_bounds__(256) void l2n_s2s(const unsigned short* __restrict__ ih,
        const unsigned short* __restrict__ il,
        unsigned short* __restrict__ oh, unsigned short* __restrict__ ol)
{
    l2n_body(ih, il, oh, ol);
}

__global__ __launch_bounds__(256) void l2n3(
    const unsigned short* __restrict__ i0h, const unsigned short* __restrict__ i0l,
    unsigned short* __restrict__ o0h, unsigned short* __restrict__ o0l,
    const unsigned short* __restrict__ i1h, const unsigned short* __restrict__ i1l,
    unsigned short* __restrict__ o1h, unsigned short* __restrict__ o1l,
    const unsigned short* __restrict__ i2h, const unsigned short* __restrict__ i2l,
    unsigned short* __restrict__ o2h, unsigned short* __restrict__ o2l)
{
    int i = blockIdx.y;
    if (i == 0) l2n_body(i0h, i0l, o0h, o0l);
    else if (i == 1) l2n_body(i1h, i1l, o1h, o1l);
    else l2n_body(i2h, i2l, o2h, o2l);
}

// ---------------------------------------------------------------------------
extern "C" void kernel_launch(void* const* d_in, const int* in_sizes, int n_in,
                              void* d_out, int out_size, void* d_ws, size_t ws_size,
                              hipStream_t stream)
{
    const float* x      = (const float*)d_in[0];
    const float* qkv_w  = (const float*)d_in[1];
    const float* qkv_b  = (const float*)d_in[2];
    const float* proj_w = (const float*)d_in[3];
    const float* proj_b = (const float*)d_in[4];
    float* out = (float*)d_out;            // [0,SZ)=x_gem, [SZ,2SZ)=x_ori

    unsigned short* w16 = (unsigned short*)d_ws;
    #define SL(i) (w16 + (size_t)(i)*SZ)          // 8 bf16 slots
    unsigned short* WQh = w16 + 8*SZ;             // WQ hi, dead after qkv
    unsigned short* VT1 = WQh;                    // aliases WQ
    size_t p = 8*SZ + 2*WSZ;
    unsigned short* VTv = w16 + p;  p += VTSZ;
    unsigned short* VT2 = w16 + p;  p += VTSZ;
    unsigned short* VT3 = w16 + p;  p += VTSZ;
    unsigned short* WPh = w16 + p;  p += PSZ;
    unsigned short* WPl = w16 + p;  p += PSZ;     // unused (layout keep)
    unsigned short* E0  = w16 + p;  p += SZ;
    unsigned short* E1  = w16 + p;  p += SZ;
    float* rn = (float*)(w16 + p);  p += 2*(M_ROWS + 8);
    float* it = rn + M_ROWS;
    unsigned short* F0 = w16 + p;  p += SZ;
    unsigned short* F1 = w16 + p;  p += SZ;
    unsigned short* G0 = w16 + p;  p += SZ;
    unsigned short* G1 = w16 + p;  p += SZ;
    size_t need4 = p * sizeof(unsigned short);
    int merged4  = (ws_size >= need4);

    unsigned short* S0 = (unsigned short*)d_out;  // x_gem bytes (scratch pair)
    unsigned short* S1 = S0 + SZ;

    dim3 blk(256);
    dim3 gq(24,37), gp(8,73), gfl4(640,4), gt(10,128);
    dim3 gt3(10,128,3), gl3(18464,3);

    // prologue: merged splits + fused row-norm, inv_temp, qkv gemm, VTv
    split_all<<<dim3(M_ROWS + 4*NC), blk, 0, stream>>>(x, qkv_w, proj_w,
        SL(6), SL(7), WQh, WPh, rn);
    calc_invtemp<<<dim3(NB), blk, 0, stream>>>(rn, it);
    gemm_qkv_mfma<<<gq, blk, 0, stream>>>(SL(6), SL(7), WQh, qkv_b,
        SL(0), SL(1), SL(2), SL(3), SL(4), SL(5));
    transp64<<<gt, blk, 0, stream>>>(SL(4), VTv);

    if (merged4){
        // xs1 = l2n(v) in-place (4,5); xs2 = l2n(k)->(6,7); xs3 = l2n(q)->E
        l2n3<<<gl3, blk, 0, stream>>>(
            SL(4),SL(5), SL(4),SL(5),
            SL(2),SL(3), SL(6),SL(7),
            SL(0),SL(1), E0,E1);
        transp64x3<<<gt3, blk, 0, stream>>>(SL(4), VT1, SL(6), VT2, E0, VT3);
        // merged: z1->F1, z2->F0, z3->G0 (hi only), o_ori->S pair
        flash4<<<gfl4, blk, 0, stream>>>(
            SL(4), SL(6), E0,
            SL(0), SL(2),
            VT1, VT2, VT3, VTv,
            F1, F0, G0, S0,S1, it);
        // finals 3-wide + proj_ori as slice 3 (proj reads S, writes x_ori)
        flash_fin<<<gfl4, blk, 0, stream>>>(
            F1, F0, G0, VTv,
            SL(4),SL(5), SL(6),SL(7), E0,E1,
            S0,S1, WPh, proj_b, out + SZ, it);
        // proj_gem with fused sum3 (reads 3 pairs, writes x_gem = S region)
        gemm_proj_mfma<3><<<gp, blk, 0, stream>>>(SL(4),SL(5), SL(6),SL(7),
            E0,E1, WPh, proj_b, 1.f/3.f, out);
    } else {
        // serial fallback (hi-only scores; same kernels, sequential)
        unsigned short* VTx = WQh;
        l2n_s2s<<<dim3(18464), blk, 0, stream>>>(SL(4),SL(5), SL(6),SL(7));
        transp64<<<gt, blk, 0, stream>>>(SL(6), VTx);
        flash4<<<gfl4, blk, 0, stream>>>(
            SL(6), SL(6), SL(6), SL(0), SL(2),
            VTx, VTx, VTx, VTv,
            F1, F0, G0, S0,S1, it);   // F/G scratch; S = o_ori
        gemm_proj_mfma<1><<<gp, blk, 0, stream>>>(S0,S1, S0,S1, S0,S1,
            WPh, proj_b, 1.f, out + SZ);
        flash2b<1><<<dim3(640,1), blk, 0, stream>>>(
            SL(6), SL(6), SL(6), VTx, VTx, VTx,
            F1, G1, F1, G1, F1, G1, it);
        l2n_s2s<<<dim3(18464), blk, 0, stream>>>(SL(2),SL(3), SL(2),SL(3));
        transp64<<<gt, blk, 0, stream>>>(SL(2), VTx);
        flash2b<1><<<dim3(640,1), blk, 0, stream>>>(
            SL(2), SL(2), SL(2), VTx, VTx, VTx,
            F0, G1, F0, G1, F0, G1, it);
        l2n_s2s<<<dim3(18464), blk, 0, stream>>>(SL(0),SL(1), SL(0),SL(1));
        transp64<<<gt, blk, 0, stream>>>(SL(0), VTx);
        flash2b<1><<<dim3(640,1), blk, 0, stream>>>(
            SL(0), SL(0), SL(0), VTx, VTx, VTx,
            G0, G1, G0, G1, G0, G1, it);
        flash2b<2><<<dim3(640,3), blk, 0, stream>>>(
            F1, F0, G0, VTv, VTv, VTv,
            SL(4),SL(5), SL(6),SL(7), E0,E1, it);
        gemm_proj_mfma<3><<<gp, blk, 0, stream>>>(SL(4),SL(5), SL(6),SL(7),
            E0,E1, WPh, proj_b, 1.f/3.f, out);
    }
    #undef SL
}